// Round 1
// baseline (647.672 us; speedup 1.0000x reference)
//
#include <hip/hip_runtime.h>
#include <math.h>

#define HEADS 3
#define HID 64
#define HOUT 192
#define NEG_SLOPE 0.2f

// ---------------- CSR build ----------------

__global__ void zero_int_kernel(int* __restrict__ p, int n) {
  int i = blockIdx.x * 256 + threadIdx.x;
  if (i < n) p[i] = 0;
}

// edges e in [0,E): src=ei[e], dst=ei[E+e]; e in [E,E+N): self-loop (e-E, e-E)
__global__ void hist_kernel(const int* __restrict__ ei, int E, int N,
                            int* __restrict__ counts) {
  int e = blockIdx.x * 256 + threadIdx.x;
  int E2 = E + N;
  if (e >= E2) return;
  int d = (e < E) ? ei[E + e] : (e - E);
  atomicAdd(&counts[d], 1);
}

// chunk=1024 per block, 256 threads, 4 elems/thread; writes per-chunk exclusive
// prefix into excl[], chunk totals into blocksums[]
__global__ void scan1_kernel(const int* __restrict__ counts, int* __restrict__ excl,
                             int* __restrict__ blocksums, int n) {
  int t = threadIdx.x;
  int base = blockIdx.x * 1024 + t * 4;
  int v[4];
  int s = 0;
#pragma unroll
  for (int j = 0; j < 4; ++j) {
    int i = base + j;
    v[j] = (i < n) ? counts[i] : 0;
    s += v[j];
  }
  int lane = t & 63, wid = t >> 6;
  int x = s;
#pragma unroll
  for (int d = 1; d < 64; d <<= 1) {
    int y = __shfl_up(x, d);
    if (lane >= d) x += y;
  }
  __shared__ int wsum[4];
  if (lane == 63) wsum[wid] = x;
  __syncthreads();
  int wbase = 0;
  for (int w = 0; w < wid; ++w) wbase += wsum[w];
  int run = wbase + x - s;  // exclusive prefix for this thread's 4 elems
#pragma unroll
  for (int j = 0; j < 4; ++j) {
    int i = base + j;
    if (i < n) excl[i] = run;
    run += v[j];
  }
  if (t == 255) blocksums[blockIdx.x] = wbase + x;
}

// single block (64 threads) scans up to many chunks of 64 with a running total
__global__ void scan2_kernel(const int* __restrict__ blocksums, int* __restrict__ blockbase,
                             int nb, int* __restrict__ total_out) {
  int lane = threadIdx.x;
  __shared__ int running_s;
  if (lane == 0) running_s = 0;
  __syncthreads();
  for (int base = 0; base < nb; base += 64) {
    int i = base + lane;
    int v = (i < nb) ? blocksums[i] : 0;
    int x = v;
#pragma unroll
    for (int d = 1; d < 64; d <<= 1) {
      int y = __shfl_up(x, d);
      if (lane >= d) x += y;
    }
    int running = running_s;
    if (i < nb) blockbase[i] = running + x - v;
    __syncthreads();
    if (lane == 63) running_s = running + x;
    __syncthreads();
  }
  if (lane == 0) *total_out = running_s;
}

__global__ void scan3_kernel(int* __restrict__ excl, const int* __restrict__ blockbase,
                             int* __restrict__ cursor, int n) {
  int i = blockIdx.x * 256 + threadIdx.x;
  if (i < n) {
    int v = excl[i] + blockbase[i >> 10];
    excl[i] = v;
    cursor[i] = v;
  }
}

__global__ void scatter_kernel(const int* __restrict__ ei, int E, int N,
                               int* __restrict__ cursor, int* __restrict__ srcs) {
  int e = blockIdx.x * 256 + threadIdx.x;
  int E2 = E + N;
  if (e >= E2) return;
  int s, d;
  if (e < E) { s = ei[e]; d = ei[E + e]; }
  else       { s = e - E; d = e - E; }
  int pos = atomicAdd(&cursor[d], 1);
  srcs[pos] = s;
}

// ---------------- f32 GEMM: C[M,Nc] = A[M,K] @ B[K,Nc] ----------------
// BM=128, BN=64, BK=32; 256 threads; 8x4 microtile
#define BM 128
#define BN 64
#define BK 32

__global__ __launch_bounds__(256) void gemm_f32_kernel(
    const float* __restrict__ A, const float* __restrict__ B, float* __restrict__ C,
    int M, int Nc, int K) {
  __shared__ float As[BK][BM];
  __shared__ float Bs[BK][BN];
  int bm = blockIdx.x * BM;
  int bn = blockIdx.y * BN;
  int tid = threadIdx.x;
  int tx = tid & 15;   // 0..15 -> 4 cols each
  int ty = tid >> 4;   // 0..15 -> 8 rows each
  float acc[8][4];
#pragma unroll
  for (int i = 0; i < 8; ++i)
#pragma unroll
    for (int j = 0; j < 4; ++j) acc[i][j] = 0.f;

  for (int kt = 0; kt < K; kt += BK) {
    // load A tile 128x32 (coalesced along K)
#pragma unroll
    for (int it = 0; it < (BM * BK) / 256; ++it) {
      int i = tid + it * 256;
      int m = i >> 5, k = i & 31;
      int gm = bm + m;
      As[k][m] = (gm < M) ? A[(size_t)gm * K + kt + k] : 0.f;
    }
    // load B tile 32x64 (coalesced along Nc)
#pragma unroll
    for (int it = 0; it < (BK * BN) / 256; ++it) {
      int i = tid + it * 256;
      int kk = i >> 6, n = i & 63;
      Bs[kk][n] = B[(size_t)(kt + kk) * Nc + bn + n];
    }
    __syncthreads();
#pragma unroll
    for (int k = 0; k < BK; ++k) {
      float a[8], b[4];
#pragma unroll
      for (int i = 0; i < 8; ++i) a[i] = As[k][ty * 8 + i];
#pragma unroll
      for (int j = 0; j < 4; ++j) b[j] = Bs[k][tx * 4 + j];
#pragma unroll
      for (int i = 0; i < 8; ++i)
#pragma unroll
        for (int j = 0; j < 4; ++j) acc[i][j] += a[i] * b[j];
    }
    __syncthreads();
  }
#pragma unroll
  for (int i = 0; i < 8; ++i) {
    int gm = bm + ty * 8 + i;
    if (gm < M) {
#pragma unroll
      for (int j = 0; j < 4; ++j)
        C[(size_t)gm * Nc + bn + tx * 4 + j] = acc[i][j];
    }
  }
}

// ---------------- attention coefficients ----------------
// wave per node: al_s[n,h] = dot(h[n,h,:], a_src[h,:]) ; same for dst
__global__ void al_kernel(const float* __restrict__ h, const float* __restrict__ asrc,
                          const float* __restrict__ adst, float* __restrict__ als,
                          float* __restrict__ ald, int n_nodes) {
  int wave = (blockIdx.x * blockDim.x + threadIdx.x) >> 6;
  int lane = threadIdx.x & 63;
  if (wave >= n_nodes) return;
  const float* hr = h + (size_t)wave * HOUT;
  float ps[3], pd[3];
#pragma unroll
  for (int hd = 0; hd < 3; ++hd) {
    float v = hr[hd * 64 + lane];
    ps[hd] = v * asrc[hd * 64 + lane];
    pd[hd] = v * adst[hd * 64 + lane];
  }
#pragma unroll
  for (int d = 32; d > 0; d >>= 1) {
#pragma unroll
    for (int hd = 0; hd < 3; ++hd) {
      ps[hd] += __shfl_xor(ps[hd], d);
      pd[hd] += __shfl_xor(pd[hd], d);
    }
  }
  if (lane == 0) {
#pragma unroll
    for (int hd = 0; hd < 3; ++hd) {
      als[wave * 3 + hd] = ps[hd];
      ald[wave * 3 + hd] = pd[hd];
    }
  }
}

// ---------------- per-dst-node online-softmax aggregation ----------------
// wave per node; lane = dim within head; 3 heads in registers
__global__ void agg_kernel(const float* __restrict__ h, const float* __restrict__ als,
                           const float* __restrict__ ald, const int* __restrict__ offsets,
                           const int* __restrict__ srcs, const float* __restrict__ bias,
                           float* __restrict__ out, int n_nodes) {
  int wave = (blockIdx.x * blockDim.x + threadIdx.x) >> 6;
  int lane = threadIdx.x & 63;
  if (wave >= n_nodes) return;
  int node = wave;
  int beg = offsets[node], end = offsets[node + 1];
  float ad0 = ald[node * 3 + 0], ad1 = ald[node * 3 + 1], ad2 = ald[node * 3 + 2];
  float m0 = -1e30f, m1 = -1e30f, m2 = -1e30f;
  float s0 = 0.f, s1 = 0.f, s2 = 0.f;
  float a0 = 0.f, a1 = 0.f, a2 = 0.f;
  for (int p = beg; p < end; ++p) {
    int s = srcs[p];
    const float* hr = h + (size_t)s * HOUT;
    float l0 = als[s * 3 + 0] + ad0; l0 = (l0 > 0.f) ? l0 : NEG_SLOPE * l0;
    float l1 = als[s * 3 + 1] + ad1; l1 = (l1 > 0.f) ? l1 : NEG_SLOPE * l1;
    float l2 = als[s * 3 + 2] + ad2; l2 = (l2 > 0.f) ? l2 : NEG_SLOPE * l2;
    float v0 = hr[lane], v1 = hr[64 + lane], v2 = hr[128 + lane];
    float nm, sc, w;
    nm = fmaxf(m0, l0); sc = __expf(m0 - nm); w = __expf(l0 - nm);
    s0 = s0 * sc + w; a0 = a0 * sc + w * v0; m0 = nm;
    nm = fmaxf(m1, l1); sc = __expf(m1 - nm); w = __expf(l1 - nm);
    s1 = s1 * sc + w; a1 = a1 * sc + w * v1; m1 = nm;
    nm = fmaxf(m2, l2); sc = __expf(m2 - nm); w = __expf(l2 - nm);
    s2 = s2 * sc + w; a2 = a2 * sc + w * v2; m2 = nm;
  }
  float* o = out + (size_t)node * HOUT;
  o[lane]       = fmaxf(a0 / (s0 + 1e-16f) + bias[lane], 0.f);
  o[64 + lane]  = fmaxf(a1 / (s1 + 1e-16f) + bias[64 + lane], 0.f);
  o[128 + lane] = fmaxf(a2 / (s2 + 1e-16f) + bias[128 + lane], 0.f);
}

// ---------------- mean pool over sorted batch + relu ----------------
__global__ void pool_kernel(const float* __restrict__ h, const int* __restrict__ batch,
                            float* __restrict__ out, int n_nodes) {
  __shared__ int sbe[2];
  int g = blockIdx.x;
  if (threadIdx.x < 2) {
    int key = g + (int)threadIdx.x;
    int lo = 0, hi = n_nodes;
    while (lo < hi) {
      int mid = (lo + hi) >> 1;
      if (batch[mid] < key) lo = mid + 1; else hi = mid;
    }
    sbe[threadIdx.x] = lo;
  }
  __syncthreads();
  int beg = sbe[0], end = sbe[1];
  float sum = 0.f;
  for (int i = beg; i < end; ++i) sum += h[(size_t)i * HOUT + threadIdx.x];
  float cnt = (float)(end - beg);
  float v = (cnt > 0.f) ? sum / cnt : 0.f;
  out[(size_t)g * HOUT + threadIdx.x] = fmaxf(v, 0.f);
}

// ---------------- launcher ----------------

extern "C" void kernel_launch(void* const* d_in, const int* in_sizes, int n_in,
                              void* d_out, int out_size, void* d_ws, size_t ws_size,
                              hipStream_t stream) {
  const float* x   = (const float*)d_in[0];
  const int*   ei  = (const int*)d_in[1];
  const int*   bat = (const int*)d_in[2];
  const float* W1  = (const float*)d_in[3];
  const float* a1s = (const float*)d_in[4];
  const float* a1d = (const float*)d_in[5];
  const float* b1  = (const float*)d_in[6];
  const float* W2  = (const float*)d_in[7];
  const float* a2s = (const float*)d_in[8];
  const float* a2d = (const float*)d_in[9];
  const float* b2  = (const float*)d_in[10];
  float* out = (float*)d_out;

  int N   = in_sizes[2];
  int Fin = in_sizes[0] / N;
  int E   = in_sizes[1] / 2;
  int E2  = E + N;
  int G   = out_size / HOUT;

  char* p = (char*)d_ws;
  auto carve = [&](size_t bytes) -> char* {
    char* r = p;
    p += (bytes + 255) & ~(size_t)255;
    return r;
  };
  int*   counts    = (int*)carve((size_t)N * 4);
  int*   offsets   = (int*)carve((size_t)(N + 1) * 4);
  int*   cursor    = (int*)carve((size_t)N * 4);
  int*   blocksums = (int*)carve(256 * 4);
  int*   blockbase = (int*)carve(256 * 4);
  int*   srcs      = (int*)carve((size_t)E2 * 4);
  float* als       = (float*)carve((size_t)N * 3 * 4);
  float* ald       = (float*)carve((size_t)N * 3 * 4);
  float* bufA      = (float*)carve((size_t)N * HOUT * 4);
  float* bufB      = (float*)carve((size_t)N * HOUT * 4);
  (void)ws_size;

  // --- CSR build (dst-sorted edge list) ---
  zero_int_kernel<<<(N + 255) / 256, 256, 0, stream>>>(counts, N);
  hist_kernel<<<(E2 + 255) / 256, 256, 0, stream>>>(ei, E, N, counts);
  int nb = (N + 1023) / 1024;
  scan1_kernel<<<nb, 256, 0, stream>>>(counts, offsets, blocksums, N);
  scan2_kernel<<<1, 64, 0, stream>>>(blocksums, blockbase, nb, offsets + N);
  scan3_kernel<<<(N + 255) / 256, 256, 0, stream>>>(offsets, blockbase, cursor, N);
  scatter_kernel<<<(E2 + 255) / 256, 256, 0, stream>>>(ei, E, N, cursor, srcs);

  int wave_blocks = (N * 64 + 255) / 256;
  dim3 gemm_grid((N + BM - 1) / BM, HOUT / BN);

  // --- layer 1 ---
  gemm_f32_kernel<<<gemm_grid, 256, 0, stream>>>(x, W1, bufA, N, HOUT, Fin);
  al_kernel<<<wave_blocks, 256, 0, stream>>>(bufA, a1s, a1d, als, ald, N);
  agg_kernel<<<wave_blocks, 256, 0, stream>>>(bufA, als, ald, offsets, srcs, b1, bufB, N);

  // --- layer 2 ---
  gemm_f32_kernel<<<gemm_grid, 256, 0, stream>>>(bufB, W2, bufA, N, HOUT, HOUT);
  al_kernel<<<wave_blocks, 256, 0, stream>>>(bufA, a2s, a2d, als, ald, N);
  agg_kernel<<<wave_blocks, 256, 0, stream>>>(bufA, als, ald, offsets, srcs, b2, bufB, N);

  // --- pool ---
  pool_kernel<<<G, HOUT, 0, stream>>>(bufB, bat, out, N);
}

// Round 2
// 563.484 us; speedup vs baseline: 1.1494x; 1.1494x over previous
//
#include <hip/hip_runtime.h>
#include <math.h>

#define HEADS 3
#define HID 64
#define HOUT 192
#define NEG_SLOPE 0.2f

// ---------------- CSR build ----------------

__global__ void zero_int_kernel(int* __restrict__ p, int n) {
  int i = blockIdx.x * 256 + threadIdx.x;
  if (i < n) p[i] = 0;
}

__global__ void hist_kernel(const int* __restrict__ ei, int E, int N,
                            int* __restrict__ counts) {
  int e = blockIdx.x * 256 + threadIdx.x;
  int E2 = E + N;
  if (e >= E2) return;
  int d = (e < E) ? ei[E + e] : (e - E);
  atomicAdd(&counts[d], 1);
}

__global__ void scan1_kernel(const int* __restrict__ counts, int* __restrict__ excl,
                             int* __restrict__ blocksums, int n) {
  int t = threadIdx.x;
  int base = blockIdx.x * 1024 + t * 4;
  int v[4];
  int s = 0;
#pragma unroll
  for (int j = 0; j < 4; ++j) {
    int i = base + j;
    v[j] = (i < n) ? counts[i] : 0;
    s += v[j];
  }
  int lane = t & 63, wid = t >> 6;
  int x = s;
#pragma unroll
  for (int d = 1; d < 64; d <<= 1) {
    int y = __shfl_up(x, d);
    if (lane >= d) x += y;
  }
  __shared__ int wsum[4];
  if (lane == 63) wsum[wid] = x;
  __syncthreads();
  int wbase = 0;
  for (int w = 0; w < wid; ++w) wbase += wsum[w];
  int run = wbase + x - s;
#pragma unroll
  for (int j = 0; j < 4; ++j) {
    int i = base + j;
    if (i < n) excl[i] = run;
    run += v[j];
  }
  if (t == 255) blocksums[blockIdx.x] = wbase + x;
}

__global__ void scan2_kernel(const int* __restrict__ blocksums, int* __restrict__ blockbase,
                             int nb, int* __restrict__ total_out) {
  int lane = threadIdx.x;
  __shared__ int running_s;
  if (lane == 0) running_s = 0;
  __syncthreads();
  for (int base = 0; base < nb; base += 64) {
    int i = base + lane;
    int v = (i < nb) ? blocksums[i] : 0;
    int x = v;
#pragma unroll
    for (int d = 1; d < 64; d <<= 1) {
      int y = __shfl_up(x, d);
      if (lane >= d) x += y;
    }
    int running = running_s;
    if (i < nb) blockbase[i] = running + x - v;
    __syncthreads();
    if (lane == 63) running_s = running + x;
    __syncthreads();
  }
  if (lane == 0) *total_out = running_s;
}

__global__ void scan3_kernel(int* __restrict__ excl, const int* __restrict__ blockbase,
                             int* __restrict__ cursor, int n) {
  int i = blockIdx.x * 256 + threadIdx.x;
  if (i < n) {
    int v = excl[i] + blockbase[i >> 10];
    excl[i] = v;
    cursor[i] = v;
  }
}

__global__ void scatter_kernel(const int* __restrict__ ei, int E, int N,
                               int* __restrict__ cursor, int* __restrict__ srcs) {
  int e = blockIdx.x * 256 + threadIdx.x;
  int E2 = E + N;
  if (e >= E2) return;
  int s, d;
  if (e < E) { s = ei[e]; d = ei[E + e]; }
  else       { s = e - E; d = e - E; }
  int pos = atomicAdd(&cursor[d], 1);
  srcs[pos] = s;
}

// ---------------- f32 GEMM: C[M,192] = A[M,K] @ B[K,192] ----------------
// BM=128, BN=192 (full width), BK=32; 256 threads; 8x12 microtile.
// Thread (tx=tid&15, ty=tid>>4) computes rows {ty+16*i, i<8}, cols {tx*12..tx*12+11}.
#define GBM 128
#define GBK 32

__global__ __launch_bounds__(256) void gemm_f32_kernel(
    const float* __restrict__ A, const float* __restrict__ B, float* __restrict__ C,
    int M, int K) {
  __shared__ float As[GBM][GBK + 4];   // row stride 36 floats: bank(m,k)=(4m+k)%32
  __shared__ float Bs[GBK][HOUT];
  int bm = blockIdx.x * GBM;
  int tid = threadIdx.x;
  int tx = tid & 15;
  int ty = tid >> 4;
  float acc[8][12];
#pragma unroll
  for (int i = 0; i < 8; ++i)
#pragma unroll
    for (int n = 0; n < 12; ++n) acc[i][n] = 0.f;

  for (int kt = 0; kt < K; kt += GBK) {
    // A tile: 128x32 floats, float4 along K, 4 passes of 32 rows
#pragma unroll
    for (int it = 0; it < 4; ++it) {
      int m = it * 32 + (tid >> 3);
      int k4 = (tid & 7) * 4;
      int gm = bm + m;
      float4 av;
      if (gm < M) av = *(const float4*)&A[(size_t)gm * K + kt + k4];
      else av = make_float4(0.f, 0.f, 0.f, 0.f);
      *(float4*)&As[m][k4] = av;
    }
    // B tile: 32x192 floats = 1536 float4, 6 passes
#pragma unroll
    for (int it = 0; it < 6; ++it) {
      int f = tid + it * 256;
      int kk = f / 48;
      int c4 = (f % 48) * 4;
      *(float4*)&Bs[kk][c4] = *(const float4*)&B[(size_t)(kt + kk) * HOUT + c4];
    }
    __syncthreads();

    for (int k4 = 0; k4 < GBK; k4 += 4) {
      float4 a4[8];
#pragma unroll
      for (int i = 0; i < 8; ++i)
        a4[i] = *(const float4*)&As[ty + 16 * i][k4];
#pragma unroll
      for (int j = 0; j < 4; ++j) {
        float4 b0 = *(const float4*)&Bs[k4 + j][tx * 12];
        float4 b1 = *(const float4*)&Bs[k4 + j][tx * 12 + 4];
        float4 b2 = *(const float4*)&Bs[k4 + j][tx * 12 + 8];
        float bv[12] = {b0.x, b0.y, b0.z, b0.w, b1.x, b1.y, b1.z, b1.w,
                        b2.x, b2.y, b2.z, b2.w};
#pragma unroll
        for (int i = 0; i < 8; ++i) {
          float av = (j == 0) ? a4[i].x : (j == 1) ? a4[i].y : (j == 2) ? a4[i].z : a4[i].w;
#pragma unroll
          for (int n = 0; n < 12; ++n) acc[i][n] += av * bv[n];
        }
      }
    }
    __syncthreads();
  }
#pragma unroll
  for (int i = 0; i < 8; ++i) {
    int gm = bm + ty + 16 * i;
    if (gm < M) {
      float* cr = &C[(size_t)gm * HOUT + tx * 12];
      *(float4*)&cr[0] = make_float4(acc[i][0], acc[i][1], acc[i][2], acc[i][3]);
      *(float4*)&cr[4] = make_float4(acc[i][4], acc[i][5], acc[i][6], acc[i][7]);
      *(float4*)&cr[8] = make_float4(acc[i][8], acc[i][9], acc[i][10], acc[i][11]);
    }
  }
}

// ---------------- attention coefficients ----------------
__global__ void al_kernel(const float* __restrict__ h, const float* __restrict__ asrc,
                          const float* __restrict__ adst, float* __restrict__ als,
                          float* __restrict__ ald, int n_nodes) {
  int wave = (blockIdx.x * blockDim.x + threadIdx.x) >> 6;
  int lane = threadIdx.x & 63;
  if (wave >= n_nodes) return;
  const float* hr = h + (size_t)wave * HOUT;
  float ps[3], pd[3];
#pragma unroll
  for (int hd = 0; hd < 3; ++hd) {
    float v = hr[hd * 64 + lane];
    ps[hd] = v * asrc[hd * 64 + lane];
    pd[hd] = v * adst[hd * 64 + lane];
  }
#pragma unroll
  for (int d = 32; d > 0; d >>= 1) {
#pragma unroll
    for (int hd = 0; hd < 3; ++hd) {
      ps[hd] += __shfl_xor(ps[hd], d);
      pd[hd] += __shfl_xor(pd[hd], d);
    }
  }
  if (lane == 0) {
#pragma unroll
    for (int hd = 0; hd < 3; ++hd) {
      als[wave * 3 + hd] = ps[hd];
      ald[wave * 3 + hd] = pd[hd];
    }
  }
}

// ---------------- per-dst-node aggregation (direct exp, no max) ----------------
// Logits are leaky_relu of O(1) dot products -> exp() overflow-safe; max-subtract
// cancels in a/s so result is mathematically identical to reference.
__global__ void agg_kernel(const float* __restrict__ h, const float* __restrict__ als,
                           const float* __restrict__ ald, const int* __restrict__ offsets,
                           const int* __restrict__ srcs, const float* __restrict__ bias,
                           float* __restrict__ out, int n_nodes) {
  int wave = (blockIdx.x * blockDim.x + threadIdx.x) >> 6;
  int lane = threadIdx.x & 63;
  if (wave >= n_nodes) return;
  int node = wave;
  int beg = offsets[node], end = offsets[node + 1];
  float ad0 = ald[node * 3 + 0], ad1 = ald[node * 3 + 1], ad2 = ald[node * 3 + 2];
  float sA0 = 0.f, sA1 = 0.f, sA2 = 0.f, aA0 = 0.f, aA1 = 0.f, aA2 = 0.f;
  float sB0 = 0.f, sB1 = 0.f, sB2 = 0.f, aB0 = 0.f, aB1 = 0.f, aB2 = 0.f;
  int p = beg;
  for (; p + 1 < end; p += 2) {
    int sa = srcs[p];
    int sb = srcs[p + 1];
    const float* ha = h + (size_t)sa * HOUT;
    const float* hb = h + (size_t)sb * HOUT;
    float la0 = als[sa * 3 + 0] + ad0;
    float la1 = als[sa * 3 + 1] + ad1;
    float la2 = als[sa * 3 + 2] + ad2;
    float lb0 = als[sb * 3 + 0] + ad0;
    float lb1 = als[sb * 3 + 1] + ad1;
    float lb2 = als[sb * 3 + 2] + ad2;
    float va0 = ha[lane], va1 = ha[64 + lane], va2 = ha[128 + lane];
    float vb0 = hb[lane], vb1 = hb[64 + lane], vb2 = hb[128 + lane];
    la0 = (la0 > 0.f) ? la0 : NEG_SLOPE * la0;
    la1 = (la1 > 0.f) ? la1 : NEG_SLOPE * la1;
    la2 = (la2 > 0.f) ? la2 : NEG_SLOPE * la2;
    lb0 = (lb0 > 0.f) ? lb0 : NEG_SLOPE * lb0;
    lb1 = (lb1 > 0.f) ? lb1 : NEG_SLOPE * lb1;
    lb2 = (lb2 > 0.f) ? lb2 : NEG_SLOPE * lb2;
    float wa0 = __expf(la0), wa1 = __expf(la1), wa2 = __expf(la2);
    float wb0 = __expf(lb0), wb1 = __expf(lb1), wb2 = __expf(lb2);
    sA0 += wa0; aA0 += wa0 * va0;
    sA1 += wa1; aA1 += wa1 * va1;
    sA2 += wa2; aA2 += wa2 * va2;
    sB0 += wb0; aB0 += wb0 * vb0;
    sB1 += wb1; aB1 += wb1 * vb1;
    sB2 += wb2; aB2 += wb2 * vb2;
  }
  if (p < end) {
    int sa = srcs[p];
    const float* ha = h + (size_t)sa * HOUT;
    float la0 = als[sa * 3 + 0] + ad0;
    float la1 = als[sa * 3 + 1] + ad1;
    float la2 = als[sa * 3 + 2] + ad2;
    float va0 = ha[lane], va1 = ha[64 + lane], va2 = ha[128 + lane];
    la0 = (la0 > 0.f) ? la0 : NEG_SLOPE * la0;
    la1 = (la1 > 0.f) ? la1 : NEG_SLOPE * la1;
    la2 = (la2 > 0.f) ? la2 : NEG_SLOPE * la2;
    float wa0 = __expf(la0), wa1 = __expf(la1), wa2 = __expf(la2);
    sA0 += wa0; aA0 += wa0 * va0;
    sA1 += wa1; aA1 += wa1 * va1;
    sA2 += wa2; aA2 += wa2 * va2;
  }
  float s0 = sA0 + sB0, s1 = sA1 + sB1, s2 = sA2 + sB2;
  float a0 = aA0 + aB0, a1 = aA1 + aB1, a2 = aA2 + aB2;
  float* o = out + (size_t)node * HOUT;
  o[lane]       = fmaxf(a0 / (s0 + 1e-16f) + bias[lane], 0.f);
  o[64 + lane]  = fmaxf(a1 / (s1 + 1e-16f) + bias[64 + lane], 0.f);
  o[128 + lane] = fmaxf(a2 / (s2 + 1e-16f) + bias[128 + lane], 0.f);
}

// ---------------- mean pool over sorted batch + relu ----------------
__global__ void pool_kernel(const float* __restrict__ h, const int* __restrict__ batch,
                            float* __restrict__ out, int n_nodes) {
  __shared__ int sbe[2];
  int g = blockIdx.x;
  if (threadIdx.x < 2) {
    int key = g + (int)threadIdx.x;
    int lo = 0, hi = n_nodes;
    while (lo < hi) {
      int mid = (lo + hi) >> 1;
      if (batch[mid] < key) lo = mid + 1; else hi = mid;
    }
    sbe[threadIdx.x] = lo;
  }
  __syncthreads();
  int beg = sbe[0], end = sbe[1];
  float sum = 0.f;
  for (int i = beg; i < end; ++i) sum += h[(size_t)i * HOUT + threadIdx.x];
  float cnt = (float)(end - beg);
  float v = (cnt > 0.f) ? sum / cnt : 0.f;
  out[(size_t)g * HOUT + threadIdx.x] = fmaxf(v, 0.f);
}

// ---------------- launcher ----------------

extern "C" void kernel_launch(void* const* d_in, const int* in_sizes, int n_in,
                              void* d_out, int out_size, void* d_ws, size_t ws_size,
                              hipStream_t stream) {
  const float* x   = (const float*)d_in[0];
  const int*   ei  = (const int*)d_in[1];
  const int*   bat = (const int*)d_in[2];
  const float* W1  = (const float*)d_in[3];
  const float* a1s = (const float*)d_in[4];
  const float* a1d = (const float*)d_in[5];
  const float* b1  = (const float*)d_in[6];
  const float* W2  = (const float*)d_in[7];
  const float* a2s = (const float*)d_in[8];
  const float* a2d = (const float*)d_in[9];
  const float* b2  = (const float*)d_in[10];
  float* out = (float*)d_out;

  int N   = in_sizes[2];
  int Fin = in_sizes[0] / N;
  int E   = in_sizes[1] / 2;
  int E2  = E + N;
  int G   = out_size / HOUT;

  char* p = (char*)d_ws;
  auto carve = [&](size_t bytes) -> char* {
    char* r = p;
    p += (bytes + 255) & ~(size_t)255;
    return r;
  };
  int*   counts    = (int*)carve((size_t)N * 4);
  int*   offsets   = (int*)carve((size_t)(N + 1) * 4);
  int*   cursor    = (int*)carve((size_t)N * 4);
  int*   blocksums = (int*)carve(256 * 4);
  int*   blockbase = (int*)carve(256 * 4);
  int*   srcs      = (int*)carve((size_t)E2 * 4);
  float* als       = (float*)carve((size_t)N * 3 * 4);
  float* ald       = (float*)carve((size_t)N * 3 * 4);
  float* bufA      = (float*)carve((size_t)N * HOUT * 4);
  float* bufB      = (float*)carve((size_t)N * HOUT * 4);
  (void)ws_size;

  // --- CSR build (dst-sorted edge list) ---
  zero_int_kernel<<<(N + 255) / 256, 256, 0, stream>>>(counts, N);
  hist_kernel<<<(E2 + 255) / 256, 256, 0, stream>>>(ei, E, N, counts);
  int nb = (N + 1023) / 1024;
  scan1_kernel<<<nb, 256, 0, stream>>>(counts, offsets, blocksums, N);
  scan2_kernel<<<1, 64, 0, stream>>>(blocksums, blockbase, nb, offsets + N);
  scan3_kernel<<<(N + 255) / 256, 256, 0, stream>>>(offsets, blockbase, cursor, N);
  scatter_kernel<<<(E2 + 255) / 256, 256, 0, stream>>>(ei, E, N, cursor, srcs);

  int wave_blocks = (N * 64 + 255) / 256;
  int gemm_blocks = (N + GBM - 1) / GBM;

  // --- layer 1 ---
  gemm_f32_kernel<<<gemm_blocks, 256, 0, stream>>>(x, W1, bufA, N, Fin);
  al_kernel<<<wave_blocks, 256, 0, stream>>>(bufA, a1s, a1d, als, ald, N);
  agg_kernel<<<wave_blocks, 256, 0, stream>>>(bufA, als, ald, offsets, srcs, b1, bufB, N);

  // --- layer 2 ---
  gemm_f32_kernel<<<gemm_blocks, 256, 0, stream>>>(bufB, W2, bufA, N, HOUT);
  al_kernel<<<wave_blocks, 256, 0, stream>>>(bufA, a2s, a2d, als, ald, N);
  agg_kernel<<<wave_blocks, 256, 0, stream>>>(bufA, als, ald, offsets, srcs, b2, bufB, N);

  // --- pool ---
  pool_kernel<<<G, HOUT, 0, stream>>>(bufB, bat, out, N);
}

// Round 3
// 555.077 us; speedup vs baseline: 1.1668x; 1.0151x over previous
//
#include <hip/hip_runtime.h>
#include <math.h>

#define HEADS 3
#define HID 64
#define HOUT 192
#define NEG_SLOPE 0.2f

// ---------------- CSR build ----------------

__global__ void zero_int_kernel(int* __restrict__ p, int n) {
  int i = blockIdx.x * 256 + threadIdx.x;
  if (i < n) p[i] = 0;
}

__global__ void hist_kernel(const int* __restrict__ ei, int E, int N,
                            int* __restrict__ counts) {
  int e = blockIdx.x * 256 + threadIdx.x;
  int E2 = E + N;
  if (e >= E2) return;
  int d = (e < E) ? ei[E + e] : (e - E);
  atomicAdd(&counts[d], 1);
}

__global__ void scan1_kernel(const int* __restrict__ counts, int* __restrict__ excl,
                             int* __restrict__ blocksums, int n) {
  int t = threadIdx.x;
  int base = blockIdx.x * 1024 + t * 4;
  int v[4];
  int s = 0;
#pragma unroll
  for (int j = 0; j < 4; ++j) {
    int i = base + j;
    v[j] = (i < n) ? counts[i] : 0;
    s += v[j];
  }
  int lane = t & 63, wid = t >> 6;
  int x = s;
#pragma unroll
  for (int d = 1; d < 64; d <<= 1) {
    int y = __shfl_up(x, d);
    if (lane >= d) x += y;
  }
  __shared__ int wsum[4];
  if (lane == 63) wsum[wid] = x;
  __syncthreads();
  int wbase = 0;
  for (int w = 0; w < wid; ++w) wbase += wsum[w];
  int run = wbase + x - s;
#pragma unroll
  for (int j = 0; j < 4; ++j) {
    int i = base + j;
    if (i < n) excl[i] = run;
    run += v[j];
  }
  if (t == 255) blocksums[blockIdx.x] = wbase + x;
}

__global__ void scan2_kernel(const int* __restrict__ blocksums, int* __restrict__ blockbase,
                             int nb, int* __restrict__ total_out) {
  int lane = threadIdx.x;
  __shared__ int running_s;
  if (lane == 0) running_s = 0;
  __syncthreads();
  for (int base = 0; base < nb; base += 64) {
    int i = base + lane;
    int v = (i < nb) ? blocksums[i] : 0;
    int x = v;
#pragma unroll
    for (int d = 1; d < 64; d <<= 1) {
      int y = __shfl_up(x, d);
      if (lane >= d) x += y;
    }
    int running = running_s;
    if (i < nb) blockbase[i] = running + x - v;
    __syncthreads();
    if (lane == 63) running_s = running + x;
    __syncthreads();
  }
  if (lane == 0) *total_out = running_s;
}

__global__ void scan3_kernel(int* __restrict__ excl, const int* __restrict__ blockbase,
                             int* __restrict__ cursor, int n) {
  int i = blockIdx.x * 256 + threadIdx.x;
  if (i < n) {
    int v = excl[i] + blockbase[i >> 10];
    excl[i] = v;
    cursor[i] = v;
  }
}

__global__ void scatter_kernel(const int* __restrict__ ei, int E, int N,
                               int* __restrict__ cursor, int* __restrict__ srcs,
                               int* __restrict__ dsts) {
  int e = blockIdx.x * 256 + threadIdx.x;
  int E2 = E + N;
  if (e >= E2) return;
  int s, d;
  if (e < E) { s = ei[e]; d = ei[E + e]; }
  else       { s = e - E; d = e - E; }
  int pos = atomicAdd(&cursor[d], 1);
  srcs[pos] = s;
  dsts[pos] = d;
}

// ---------------- f32 GEMM: C[M,192] = A[M,K] @ B[K,192] ----------------
#define GBM 128
#define GBK 32

__global__ __launch_bounds__(256) void gemm_f32_kernel(
    const float* __restrict__ A, const float* __restrict__ B, float* __restrict__ C,
    int M, int K) {
  __shared__ float As[GBM][GBK + 4];
  __shared__ float Bs[GBK][HOUT];
  int bm = blockIdx.x * GBM;
  int tid = threadIdx.x;
  int tx = tid & 15;
  int ty = tid >> 4;
  float acc[8][12];
#pragma unroll
  for (int i = 0; i < 8; ++i)
#pragma unroll
    for (int n = 0; n < 12; ++n) acc[i][n] = 0.f;

  for (int kt = 0; kt < K; kt += GBK) {
#pragma unroll
    for (int it = 0; it < 4; ++it) {
      int m = it * 32 + (tid >> 3);
      int k4 = (tid & 7) * 4;
      int gm = bm + m;
      float4 av;
      if (gm < M) av = *(const float4*)&A[(size_t)gm * K + kt + k4];
      else av = make_float4(0.f, 0.f, 0.f, 0.f);
      *(float4*)&As[m][k4] = av;
    }
#pragma unroll
    for (int it = 0; it < 6; ++it) {
      int f = tid + it * 256;
      int kk = f / 48;
      int c4 = (f % 48) * 4;
      *(float4*)&Bs[kk][c4] = *(const float4*)&B[(size_t)(kt + kk) * HOUT + c4];
    }
    __syncthreads();

    for (int k4 = 0; k4 < GBK; k4 += 4) {
      float4 a4[8];
#pragma unroll
      for (int i = 0; i < 8; ++i)
        a4[i] = *(const float4*)&As[ty + 16 * i][k4];
#pragma unroll
      for (int j = 0; j < 4; ++j) {
        float4 b0 = *(const float4*)&Bs[k4 + j][tx * 12];
        float4 b1 = *(const float4*)&Bs[k4 + j][tx * 12 + 4];
        float4 b2 = *(const float4*)&Bs[k4 + j][tx * 12 + 8];
        float bv[12] = {b0.x, b0.y, b0.z, b0.w, b1.x, b1.y, b1.z, b1.w,
                        b2.x, b2.y, b2.z, b2.w};
#pragma unroll
        for (int i = 0; i < 8; ++i) {
          float av = (j == 0) ? a4[i].x : (j == 1) ? a4[i].y : (j == 2) ? a4[i].z : a4[i].w;
#pragma unroll
          for (int n = 0; n < 12; ++n) acc[i][n] += av * bv[n];
        }
      }
    }
    __syncthreads();
  }
#pragma unroll
  for (int i = 0; i < 8; ++i) {
    int gm = bm + ty + 16 * i;
    if (gm < M) {
      float* cr = &C[(size_t)gm * HOUT + tx * 12];
      *(float4*)&cr[0] = make_float4(acc[i][0], acc[i][1], acc[i][2], acc[i][3]);
      *(float4*)&cr[4] = make_float4(acc[i][4], acc[i][5], acc[i][6], acc[i][7]);
      *(float4*)&cr[8] = make_float4(acc[i][8], acc[i][9], acc[i][10], acc[i][11]);
    }
  }
}

// ---------------- attention coefficients ----------------
__global__ void al_kernel(const float* __restrict__ h, const float* __restrict__ asrc,
                          const float* __restrict__ adst, float* __restrict__ als,
                          float* __restrict__ ald, int n_nodes) {
  int wave = (blockIdx.x * blockDim.x + threadIdx.x) >> 6;
  int lane = threadIdx.x & 63;
  if (wave >= n_nodes) return;
  const float* hr = h + (size_t)wave * HOUT;
  float ps[3], pd[3];
#pragma unroll
  for (int hd = 0; hd < 3; ++hd) {
    float v = hr[hd * 64 + lane];
    ps[hd] = v * asrc[hd * 64 + lane];
    pd[hd] = v * adst[hd * 64 + lane];
  }
#pragma unroll
  for (int d = 32; d > 0; d >>= 1) {
#pragma unroll
    for (int hd = 0; hd < 3; ++hd) {
      ps[hd] += __shfl_xor(ps[hd], d);
      pd[hd] += __shfl_xor(pd[hd], d);
    }
  }
  if (lane == 0) {
#pragma unroll
    for (int hd = 0; hd < 3; ++hd) {
      als[wave * 3 + hd] = ps[hd];
      ald[wave * 3 + hd] = pd[hd];
    }
  }
}

// ---------------- per-edge softmax numerators (exp weights) ----------------
// Direct exp (no running max): logits are leaky_relu of O(1) dots; the max
// subtraction cancels in e/s, so this is mathematically identical to the ref.
__global__ void w_kernel(const float* __restrict__ als, const float* __restrict__ ald,
                         const int* __restrict__ srcs, const int* __restrict__ dsts,
                         float* __restrict__ w, int E2) {
  int p = blockIdx.x * 256 + threadIdx.x;
  if (p >= E2) return;
  int s = srcs[p], d = dsts[p];
  float l0 = als[s * 3 + 0] + ald[d * 3 + 0];
  float l1 = als[s * 3 + 1] + ald[d * 3 + 1];
  float l2 = als[s * 3 + 2] + ald[d * 3 + 2];
  l0 = (l0 > 0.f) ? l0 : NEG_SLOPE * l0;
  l1 = (l1 > 0.f) ? l1 : NEG_SLOPE * l1;
  l2 = (l2 > 0.f) ? l2 : NEG_SLOPE * l2;
  w[p * 3 + 0] = __expf(l0);
  w[p * 3 + 1] = __expf(l1);
  w[p * 3 + 2] = __expf(l2);
}

// ---------------- per-dst-node aggregation: pure gather + fma ----------------
__global__ void agg_kernel(const float* __restrict__ h, const float* __restrict__ w,
                           const int* __restrict__ offsets, const int* __restrict__ srcs,
                           const float* __restrict__ bias, float* __restrict__ out,
                           int n_nodes) {
  int wave = (blockIdx.x * blockDim.x + threadIdx.x) >> 6;
  int lane = threadIdx.x & 63;
  if (wave >= n_nodes) return;
  int node = wave;
  int beg = offsets[node], end = offsets[node + 1];
  float s0 = 0.f, s1 = 0.f, s2 = 0.f;
  float a0 = 0.f, a1 = 0.f, a2 = 0.f;
  int p = beg;
  for (; p + 3 < end; p += 4) {
    int sa = srcs[p], sb = srcs[p + 1], sc = srcs[p + 2], sd = srcs[p + 3];
    const float* ha = h + (size_t)sa * HOUT;
    const float* hb = h + (size_t)sb * HOUT;
    const float* hc = h + (size_t)sc * HOUT;
    const float* hd = h + (size_t)sd * HOUT;
    float wa0 = w[p * 3 + 0],  wa1 = w[p * 3 + 1],  wa2 = w[p * 3 + 2];
    float wb0 = w[p * 3 + 3],  wb1 = w[p * 3 + 4],  wb2 = w[p * 3 + 5];
    float wc0 = w[p * 3 + 6],  wc1 = w[p * 3 + 7],  wc2 = w[p * 3 + 8];
    float wd0 = w[p * 3 + 9],  wd1 = w[p * 3 + 10], wd2 = w[p * 3 + 11];
    float va0 = ha[lane], va1 = ha[64 + lane], va2 = ha[128 + lane];
    float vb0 = hb[lane], vb1 = hb[64 + lane], vb2 = hb[128 + lane];
    float vc0 = hc[lane], vc1 = hc[64 + lane], vc2 = hc[128 + lane];
    float vd0 = hd[lane], vd1 = hd[64 + lane], vd2 = hd[128 + lane];
    s0 += wa0 + wb0 + wc0 + wd0;
    s1 += wa1 + wb1 + wc1 + wd1;
    s2 += wa2 + wb2 + wc2 + wd2;
    a0 += wa0 * va0 + wb0 * vb0 + wc0 * vc0 + wd0 * vd0;
    a1 += wa1 * va1 + wb1 * vb1 + wc1 * vc1 + wd1 * vd1;
    a2 += wa2 * va2 + wb2 * vb2 + wc2 * vc2 + wd2 * vd2;
  }
  for (; p < end; ++p) {
    int sa = srcs[p];
    const float* ha = h + (size_t)sa * HOUT;
    float wa0 = w[p * 3 + 0], wa1 = w[p * 3 + 1], wa2 = w[p * 3 + 2];
    s0 += wa0; a0 += wa0 * ha[lane];
    s1 += wa1; a1 += wa1 * ha[64 + lane];
    s2 += wa2; a2 += wa2 * ha[128 + lane];
  }
  float r0 = 1.f / (s0 + 1e-16f);
  float r1 = 1.f / (s1 + 1e-16f);
  float r2 = 1.f / (s2 + 1e-16f);
  float* o = out + (size_t)node * HOUT;
  o[lane]       = fmaxf(a0 * r0 + bias[lane], 0.f);
  o[64 + lane]  = fmaxf(a1 * r1 + bias[64 + lane], 0.f);
  o[128 + lane] = fmaxf(a2 * r2 + bias[128 + lane], 0.f);
}

// ---------------- mean pool over sorted batch + relu ----------------
__global__ void pool_kernel(const float* __restrict__ h, const int* __restrict__ batch,
                            float* __restrict__ out, int n_nodes) {
  __shared__ int sbe[2];
  int g = blockIdx.x;
  if (threadIdx.x < 2) {
    int key = g + (int)threadIdx.x;
    int lo = 0, hi = n_nodes;
    while (lo < hi) {
      int mid = (lo + hi) >> 1;
      if (batch[mid] < key) lo = mid + 1; else hi = mid;
    }
    sbe[threadIdx.x] = lo;
  }
  __syncthreads();
  int beg = sbe[0], end = sbe[1];
  float sum = 0.f;
  for (int i = beg; i < end; ++i) sum += h[(size_t)i * HOUT + threadIdx.x];
  float cnt = (float)(end - beg);
  float v = (cnt > 0.f) ? sum / cnt : 0.f;
  out[(size_t)g * HOUT + threadIdx.x] = fmaxf(v, 0.f);
}

// ---------------- launcher ----------------

extern "C" void kernel_launch(void* const* d_in, const int* in_sizes, int n_in,
                              void* d_out, int out_size, void* d_ws, size_t ws_size,
                              hipStream_t stream) {
  const float* x   = (const float*)d_in[0];
  const int*   ei  = (const int*)d_in[1];
  const int*   bat = (const int*)d_in[2];
  const float* W1  = (const float*)d_in[3];
  const float* a1s = (const float*)d_in[4];
  const float* a1d = (const float*)d_in[5];
  const float* b1  = (const float*)d_in[6];
  const float* W2  = (const float*)d_in[7];
  const float* a2s = (const float*)d_in[8];
  const float* a2d = (const float*)d_in[9];
  const float* b2  = (const float*)d_in[10];
  float* out = (float*)d_out;

  int N   = in_sizes[2];
  int Fin = in_sizes[0] / N;
  int E   = in_sizes[1] / 2;
  int E2  = E + N;
  int G   = out_size / HOUT;

  char* p = (char*)d_ws;
  auto carve = [&](size_t bytes) -> char* {
    char* r = p;
    p += (bytes + 255) & ~(size_t)255;
    return r;
  };
  int*   counts    = (int*)carve((size_t)N * 4);
  int*   offsets   = (int*)carve((size_t)(N + 1) * 4);
  int*   cursor    = (int*)carve((size_t)N * 4);
  int*   blocksums = (int*)carve(256 * 4);
  int*   blockbase = (int*)carve(256 * 4);
  int*   srcs      = (int*)carve((size_t)E2 * 4);
  int*   dsts      = (int*)carve((size_t)E2 * 4);
  float* wbuf      = (float*)carve((size_t)E2 * 3 * 4);
  float* als       = (float*)carve((size_t)N * 3 * 4);
  float* ald       = (float*)carve((size_t)N * 3 * 4);
  float* bufA      = (float*)carve((size_t)N * HOUT * 4);
  float* bufB      = (float*)carve((size_t)N * HOUT * 4);
  (void)ws_size;

  // --- CSR build (dst-sorted edge list) ---
  zero_int_kernel<<<(N + 255) / 256, 256, 0, stream>>>(counts, N);
  hist_kernel<<<(E2 + 255) / 256, 256, 0, stream>>>(ei, E, N, counts);
  int nb = (N + 1023) / 1024;
  scan1_kernel<<<nb, 256, 0, stream>>>(counts, offsets, blocksums, N);
  scan2_kernel<<<1, 64, 0, stream>>>(blocksums, blockbase, nb, offsets + N);
  scan3_kernel<<<(N + 255) / 256, 256, 0, stream>>>(offsets, blockbase, cursor, N);
  scatter_kernel<<<(E2 + 255) / 256, 256, 0, stream>>>(ei, E, N, cursor, srcs, dsts);

  int wave_blocks = (N * 64 + 255) / 256;
  int gemm_blocks = (N + GBM - 1) / GBM;
  int edge_blocks = (E2 + 255) / 256;

  // --- layer 1 ---
  gemm_f32_kernel<<<gemm_blocks, 256, 0, stream>>>(x, W1, bufA, N, Fin);
  al_kernel<<<wave_blocks, 256, 0, stream>>>(bufA, a1s, a1d, als, ald, N);
  w_kernel<<<edge_blocks, 256, 0, stream>>>(als, ald, srcs, dsts, wbuf, E2);
  agg_kernel<<<wave_blocks, 256, 0, stream>>>(bufA, wbuf, offsets, srcs, b1, bufB, N);

  // --- layer 2 ---
  gemm_f32_kernel<<<gemm_blocks, 256, 0, stream>>>(bufB, W2, bufA, N, HOUT);
  al_kernel<<<wave_blocks, 256, 0, stream>>>(bufA, a2s, a2d, als, ald, N);
  w_kernel<<<edge_blocks, 256, 0, stream>>>(als, ald, srcs, dsts, wbuf, E2);
  agg_kernel<<<wave_blocks, 256, 0, stream>>>(bufA, wbuf, offsets, srcs, b2, bufB, N);

  // --- pool ---
  pool_kernel<<<G, HOUT, 0, stream>>>(bufB, bat, out, N);
}

// Round 4
// 503.955 us; speedup vs baseline: 1.2852x; 1.1014x over previous
//
#include <hip/hip_runtime.h>
#include <hip/hip_fp16.h>
#include <math.h>

#define HEADS 3
#define HID 64
#define HOUT 192
#define NEG_SLOPE 0.2f

// ---------------- CSR build ----------------

__global__ void zero_int_kernel(int* __restrict__ p, int n) {
  int i = blockIdx.x * 256 + threadIdx.x;
  if (i < n) p[i] = 0;
}

__global__ void hist_kernel(const int* __restrict__ ei, int E, int N,
                            int* __restrict__ counts) {
  int e = blockIdx.x * 256 + threadIdx.x;
  int E2 = E + N;
  if (e >= E2) return;
  int d = (e < E) ? ei[E + e] : (e - E);
  atomicAdd(&counts[d], 1);
}

__global__ void scan1_kernel(const int* __restrict__ counts, int* __restrict__ excl,
                             int* __restrict__ blocksums, int n) {
  int t = threadIdx.x;
  int base = blockIdx.x * 1024 + t * 4;
  int v[4];
  int s = 0;
#pragma unroll
  for (int j = 0; j < 4; ++j) {
    int i = base + j;
    v[j] = (i < n) ? counts[i] : 0;
    s += v[j];
  }
  int lane = t & 63, wid = t >> 6;
  int x = s;
#pragma unroll
  for (int d = 1; d < 64; d <<= 1) {
    int y = __shfl_up(x, d);
    if (lane >= d) x += y;
  }
  __shared__ int wsum[4];
  if (lane == 63) wsum[wid] = x;
  __syncthreads();
  int wbase = 0;
  for (int w = 0; w < wid; ++w) wbase += wsum[w];
  int run = wbase + x - s;
#pragma unroll
  for (int j = 0; j < 4; ++j) {
    int i = base + j;
    if (i < n) excl[i] = run;
    run += v[j];
  }
  if (t == 255) blocksums[blockIdx.x] = wbase + x;
}

__global__ void scan2_kernel(const int* __restrict__ blocksums, int* __restrict__ blockbase,
                             int nb, int* __restrict__ total_out) {
  int lane = threadIdx.x;
  __shared__ int running_s;
  if (lane == 0) running_s = 0;
  __syncthreads();
  for (int base = 0; base < nb; base += 64) {
    int i = base + lane;
    int v = (i < nb) ? blocksums[i] : 0;
    int x = v;
#pragma unroll
    for (int d = 1; d < 64; d <<= 1) {
      int y = __shfl_up(x, d);
      if (lane >= d) x += y;
    }
    int running = running_s;
    if (i < nb) blockbase[i] = running + x - v;
    __syncthreads();
    if (lane == 63) running_s = running + x;
    __syncthreads();
  }
  if (lane == 0) *total_out = running_s;
}

__global__ void scan3_kernel(int* __restrict__ excl, const int* __restrict__ blockbase,
                             int* __restrict__ cursor, int n) {
  int i = blockIdx.x * 256 + threadIdx.x;
  if (i < n) {
    int v = excl[i] + blockbase[i >> 10];
    excl[i] = v;
    cursor[i] = v;
  }
}

__global__ void scatter_kernel(const int* __restrict__ ei, int E, int N,
                               int* __restrict__ cursor, int* __restrict__ srcs,
                               int* __restrict__ dsts) {
  int e = blockIdx.x * 256 + threadIdx.x;
  int E2 = E + N;
  if (e >= E2) return;
  int s, d;
  if (e < E) { s = ei[e]; d = ei[E + e]; }
  else       { s = e - E; d = e - E; }
  int pos = atomicAdd(&cursor[d], 1);
  srcs[pos] = s;
  dsts[pos] = d;
}

// ---------------- f32 GEMM: C[M,192] = A[M,K] @ B[K,192]; also fp16 copy ----------------
#define GBM 128
#define GBK 32

__global__ __launch_bounds__(256) void gemm_f32_kernel(
    const float* __restrict__ A, const float* __restrict__ B, float* __restrict__ C,
    __half* __restrict__ Ch, int M, int K) {
  __shared__ float As[GBM][GBK + 4];
  __shared__ float Bs[GBK][HOUT];
  int bm = blockIdx.x * GBM;
  int tid = threadIdx.x;
  int tx = tid & 15;
  int ty = tid >> 4;
  float acc[8][12];
#pragma unroll
  for (int i = 0; i < 8; ++i)
#pragma unroll
    for (int n = 0; n < 12; ++n) acc[i][n] = 0.f;

  for (int kt = 0; kt < K; kt += GBK) {
#pragma unroll
    for (int it = 0; it < 4; ++it) {
      int m = it * 32 + (tid >> 3);
      int k4 = (tid & 7) * 4;
      int gm = bm + m;
      float4 av;
      if (gm < M) av = *(const float4*)&A[(size_t)gm * K + kt + k4];
      else av = make_float4(0.f, 0.f, 0.f, 0.f);
      *(float4*)&As[m][k4] = av;
    }
#pragma unroll
    for (int it = 0; it < 6; ++it) {
      int f = tid + it * 256;
      int kk = f / 48;
      int c4 = (f % 48) * 4;
      *(float4*)&Bs[kk][c4] = *(const float4*)&B[(size_t)(kt + kk) * HOUT + c4];
    }
    __syncthreads();

    for (int k4 = 0; k4 < GBK; k4 += 4) {
      float4 a4[8];
#pragma unroll
      for (int i = 0; i < 8; ++i)
        a4[i] = *(const float4*)&As[ty + 16 * i][k4];
#pragma unroll
      for (int j = 0; j < 4; ++j) {
        float4 b0 = *(const float4*)&Bs[k4 + j][tx * 12];
        float4 b1 = *(const float4*)&Bs[k4 + j][tx * 12 + 4];
        float4 b2 = *(const float4*)&Bs[k4 + j][tx * 12 + 8];
        float bv[12] = {b0.x, b0.y, b0.z, b0.w, b1.x, b1.y, b1.z, b1.w,
                        b2.x, b2.y, b2.z, b2.w};
#pragma unroll
        for (int i = 0; i < 8; ++i) {
          float av = (j == 0) ? a4[i].x : (j == 1) ? a4[i].y : (j == 2) ? a4[i].z : a4[i].w;
#pragma unroll
          for (int n = 0; n < 12; ++n) acc[i][n] += av * bv[n];
        }
      }
    }
    __syncthreads();
  }
#pragma unroll
  for (int i = 0; i < 8; ++i) {
    int gm = bm + ty + 16 * i;
    if (gm < M) {
      float* cr = &C[(size_t)gm * HOUT + tx * 12];
      *(float4*)&cr[0] = make_float4(acc[i][0], acc[i][1], acc[i][2], acc[i][3]);
      *(float4*)&cr[4] = make_float4(acc[i][4], acc[i][5], acc[i][6], acc[i][7]);
      *(float4*)&cr[8] = make_float4(acc[i][8], acc[i][9], acc[i][10], acc[i][11]);
      __half hv[12];
#pragma unroll
      for (int n = 0; n < 12; ++n) hv[n] = __float2half(acc[i][n]);
      __half* hr = &Ch[(size_t)gm * HOUT + tx * 12];
      *(uint2*)&hr[0] = *(uint2*)&hv[0];
      *(uint2*)&hr[4] = *(uint2*)&hv[4];
      *(uint2*)&hr[8] = *(uint2*)&hv[8];
    }
  }
}

// ---------------- attention coefficients (stride-4 output) ----------------
__global__ void al_kernel(const float* __restrict__ h, const float* __restrict__ asrc,
                          const float* __restrict__ adst, float* __restrict__ als,
                          float* __restrict__ ald, int n_nodes) {
  int wave = (blockIdx.x * blockDim.x + threadIdx.x) >> 6;
  int lane = threadIdx.x & 63;
  if (wave >= n_nodes) return;
  const float* hr = h + (size_t)wave * HOUT;
  float ps[3], pd[3];
#pragma unroll
  for (int hd = 0; hd < 3; ++hd) {
    float v = hr[hd * 64 + lane];
    ps[hd] = v * asrc[hd * 64 + lane];
    pd[hd] = v * adst[hd * 64 + lane];
  }
#pragma unroll
  for (int d = 32; d > 0; d >>= 1) {
#pragma unroll
    for (int hd = 0; hd < 3; ++hd) {
      ps[hd] += __shfl_xor(ps[hd], d);
      pd[hd] += __shfl_xor(pd[hd], d);
    }
  }
  if (lane == 0) {
#pragma unroll
    for (int hd = 0; hd < 3; ++hd) {
      als[wave * 4 + hd] = ps[hd];
      ald[wave * 4 + hd] = pd[hd];
    }
    als[wave * 4 + 3] = 0.f;
    ald[wave * 4 + 3] = 0.f;
  }
}

// ---------------- per-edge softmax numerators (stride-4) ----------------
__global__ void w_kernel(const float* __restrict__ als, const float* __restrict__ ald,
                         const int* __restrict__ srcs, const int* __restrict__ dsts,
                         float* __restrict__ w, int E2) {
  int p = blockIdx.x * 256 + threadIdx.x;
  if (p >= E2) return;
  int s = srcs[p], d = dsts[p];
  float4 as4 = *(const float4*)&als[s * 4];
  float4 ad4 = *(const float4*)&ald[d * 4];
  float l0 = as4.x + ad4.x;
  float l1 = as4.y + ad4.y;
  float l2 = as4.z + ad4.z;
  l0 = (l0 > 0.f) ? l0 : NEG_SLOPE * l0;
  l1 = (l1 > 0.f) ? l1 : NEG_SLOPE * l1;
  l2 = (l2 > 0.f) ? l2 : NEG_SLOPE * l2;
  float4 wv = make_float4(__expf(l0), __expf(l1), __expf(l2), 0.f);
  *(float4*)&w[p * 4] = wv;
}

// ---------------- per-dst-node aggregation: fp16 gather + f32 fma ----------------
__global__ void agg_kernel(const __half* __restrict__ hh, const float4* __restrict__ w4,
                           const int* __restrict__ offsets, const int* __restrict__ srcs,
                           const float* __restrict__ bias, float* __restrict__ out,
                           int n_nodes) {
  int wave = (blockIdx.x * blockDim.x + threadIdx.x) >> 6;
  int lane = threadIdx.x & 63;
  if (wave >= n_nodes) return;
  int node = wave;
  int beg = offsets[node], end = offsets[node + 1];
  float s0 = 0.f, s1 = 0.f, s2 = 0.f;
  float a0 = 0.f, a1 = 0.f, a2 = 0.f;
  int p = beg;
  for (; p + 3 < end; p += 4) {
    int sa = srcs[p], sb = srcs[p + 1], sc = srcs[p + 2], sd = srcs[p + 3];
    const __half* ha = hh + (size_t)sa * HOUT;
    const __half* hb = hh + (size_t)sb * HOUT;
    const __half* hc = hh + (size_t)sc * HOUT;
    const __half* hd = hh + (size_t)sd * HOUT;
    float4 wa = w4[p], wb = w4[p + 1], wc = w4[p + 2], wd = w4[p + 3];
    float va0 = __half2float(ha[lane]);
    float va1 = __half2float(ha[64 + lane]);
    float va2 = __half2float(ha[128 + lane]);
    float vb0 = __half2float(hb[lane]);
    float vb1 = __half2float(hb[64 + lane]);
    float vb2 = __half2float(hb[128 + lane]);
    float vc0 = __half2float(hc[lane]);
    float vc1 = __half2float(hc[64 + lane]);
    float vc2 = __half2float(hc[128 + lane]);
    float vd0 = __half2float(hd[lane]);
    float vd1 = __half2float(hd[64 + lane]);
    float vd2 = __half2float(hd[128 + lane]);
    s0 += wa.x + wb.x + wc.x + wd.x;
    s1 += wa.y + wb.y + wc.y + wd.y;
    s2 += wa.z + wb.z + wc.z + wd.z;
    a0 += wa.x * va0 + wb.x * vb0 + wc.x * vc0 + wd.x * vd0;
    a1 += wa.y * va1 + wb.y * vb1 + wc.y * vc1 + wd.y * vd1;
    a2 += wa.z * va2 + wb.z * vb2 + wc.z * vc2 + wd.z * vd2;
  }
  for (; p < end; ++p) {
    int sa = srcs[p];
    const __half* ha = hh + (size_t)sa * HOUT;
    float4 wa = w4[p];
    s0 += wa.x; a0 += wa.x * __half2float(ha[lane]);
    s1 += wa.y; a1 += wa.y * __half2float(ha[64 + lane]);
    s2 += wa.z; a2 += wa.z * __half2float(ha[128 + lane]);
  }
  float r0 = 1.f / (s0 + 1e-16f);
  float r1 = 1.f / (s1 + 1e-16f);
  float r2 = 1.f / (s2 + 1e-16f);
  float* o = out + (size_t)node * HOUT;
  o[lane]       = fmaxf(a0 * r0 + bias[lane], 0.f);
  o[64 + lane]  = fmaxf(a1 * r1 + bias[64 + lane], 0.f);
  o[128 + lane] = fmaxf(a2 * r2 + bias[128 + lane], 0.f);
}

// ---------------- mean pool over sorted batch + relu ----------------
__global__ void pool_kernel(const float* __restrict__ h, const int* __restrict__ batch,
                            float* __restrict__ out, int n_nodes) {
  __shared__ int sbe[2];
  int g = blockIdx.x;
  if (threadIdx.x < 2) {
    int key = g + (int)threadIdx.x;
    int lo = 0, hi = n_nodes;
    while (lo < hi) {
      int mid = (lo + hi) >> 1;
      if (batch[mid] < key) lo = mid + 1; else hi = mid;
    }
    sbe[threadIdx.x] = lo;
  }
  __syncthreads();
  int beg = sbe[0], end = sbe[1];
  float sum = 0.f;
  for (int i = beg; i < end; ++i) sum += h[(size_t)i * HOUT + threadIdx.x];
  float cnt = (float)(end - beg);
  float v = (cnt > 0.f) ? sum / cnt : 0.f;
  out[(size_t)g * HOUT + threadIdx.x] = fmaxf(v, 0.f);
}

// ---------------- launcher ----------------

extern "C" void kernel_launch(void* const* d_in, const int* in_sizes, int n_in,
                              void* d_out, int out_size, void* d_ws, size_t ws_size,
                              hipStream_t stream) {
  const float* x   = (const float*)d_in[0];
  const int*   ei  = (const int*)d_in[1];
  const int*   bat = (const int*)d_in[2];
  const float* W1  = (const float*)d_in[3];
  const float* a1s = (const float*)d_in[4];
  const float* a1d = (const float*)d_in[5];
  const float* b1  = (const float*)d_in[6];
  const float* W2  = (const float*)d_in[7];
  const float* a2s = (const float*)d_in[8];
  const float* a2d = (const float*)d_in[9];
  const float* b2  = (const float*)d_in[10];
  float* out = (float*)d_out;

  int N   = in_sizes[2];
  int Fin = in_sizes[0] / N;
  int E   = in_sizes[1] / 2;
  int E2  = E + N;
  int G   = out_size / HOUT;

  char* p = (char*)d_ws;
  auto carve = [&](size_t bytes) -> char* {
    char* r = p;
    p += (bytes + 255) & ~(size_t)255;
    return r;
  };
  int*    counts    = (int*)carve((size_t)N * 4);
  int*    offsets   = (int*)carve((size_t)(N + 1) * 4);
  int*    cursor    = (int*)carve((size_t)N * 4);
  int*    blocksums = (int*)carve(256 * 4);
  int*    blockbase = (int*)carve(256 * 4);
  int*    srcs      = (int*)carve((size_t)E2 * 4);
  int*    dsts      = (int*)carve((size_t)E2 * 4);
  float*  wbuf      = (float*)carve((size_t)E2 * 4 * 4);
  float*  als       = (float*)carve((size_t)N * 4 * 4);
  float*  ald       = (float*)carve((size_t)N * 4 * 4);
  float*  bufA      = (float*)carve((size_t)N * HOUT * 4);
  float*  bufB      = (float*)carve((size_t)N * HOUT * 4);
  __half* hh        = (__half*)carve((size_t)N * HOUT * 2);
  (void)ws_size;

  // --- CSR build (dst-sorted edge list) ---
  zero_int_kernel<<<(N + 255) / 256, 256, 0, stream>>>(counts, N);
  hist_kernel<<<(E2 + 255) / 256, 256, 0, stream>>>(ei, E, N, counts);
  int nb = (N + 1023) / 1024;
  scan1_kernel<<<nb, 256, 0, stream>>>(counts, offsets, blocksums, N);
  scan2_kernel<<<1, 64, 0, stream>>>(blocksums, blockbase, nb, offsets + N);
  scan3_kernel<<<(N + 255) / 256, 256, 0, stream>>>(offsets, blockbase, cursor, N);
  scatter_kernel<<<(E2 + 255) / 256, 256, 0, stream>>>(ei, E, N, cursor, srcs, dsts);

  int wave_blocks = (N * 64 + 255) / 256;
  int gemm_blocks = (N + GBM - 1) / GBM;
  int edge_blocks = (E2 + 255) / 256;

  // --- layer 1 ---
  gemm_f32_kernel<<<gemm_blocks, 256, 0, stream>>>(x, W1, bufA, hh, N, Fin);
  al_kernel<<<wave_blocks, 256, 0, stream>>>(bufA, a1s, a1d, als, ald, N);
  w_kernel<<<edge_blocks, 256, 0, stream>>>(als, ald, srcs, dsts, wbuf, E2);
  agg_kernel<<<wave_blocks, 256, 0, stream>>>(hh, (const float4*)wbuf, offsets, srcs, b1, bufB, N);

  // --- layer 2 ---
  gemm_f32_kernel<<<gemm_blocks, 256, 0, stream>>>(bufB, W2, bufA, hh, N, HOUT);
  al_kernel<<<wave_blocks, 256, 0, stream>>>(bufA, a2s, a2d, als, ald, N);
  w_kernel<<<edge_blocks, 256, 0, stream>>>(als, ald, srcs, dsts, wbuf, E2);
  agg_kernel<<<wave_blocks, 256, 0, stream>>>(hh, (const float4*)wbuf, offsets, srcs, b2, bufB, N);

  // --- pool ---
  pool_kernel<<<G, HOUT, 0, stream>>>(bufB, bat, out, N);
}

// Round 5
// 405.384 us; speedup vs baseline: 1.5977x; 1.2432x over previous
//
#include <hip/hip_runtime.h>
#include <hip/hip_fp16.h>
#include <math.h>

#define HEADS 3
#define HID 64
#define HOUT 192
#define NEG_SLOPE 0.2f

typedef _Float16 half8 __attribute__((ext_vector_type(8)));
typedef float floatx4 __attribute__((ext_vector_type(4)));

// ---------------- CSR build ----------------

__global__ void zero_int_kernel(int* __restrict__ p, int n) {
  int i = blockIdx.x * 256 + threadIdx.x;
  if (i < n) p[i] = 0;
}

__global__ void hist_kernel(const int* __restrict__ ei, int E, int N,
                            int* __restrict__ counts) {
  int e = blockIdx.x * 256 + threadIdx.x;
  int E2 = E + N;
  if (e >= E2) return;
  int d = (e < E) ? ei[E + e] : (e - E);
  atomicAdd(&counts[d], 1);
}

__global__ void scan1_kernel(const int* __restrict__ counts, int* __restrict__ excl,
                             int* __restrict__ blocksums, int n) {
  int t = threadIdx.x;
  int base = blockIdx.x * 1024 + t * 4;
  int v[4];
  int s = 0;
#pragma unroll
  for (int j = 0; j < 4; ++j) {
    int i = base + j;
    v[j] = (i < n) ? counts[i] : 0;
    s += v[j];
  }
  int lane = t & 63, wid = t >> 6;
  int x = s;
#pragma unroll
  for (int d = 1; d < 64; d <<= 1) {
    int y = __shfl_up(x, d);
    if (lane >= d) x += y;
  }
  __shared__ int wsum[4];
  if (lane == 63) wsum[wid] = x;
  __syncthreads();
  int wbase = 0;
  for (int w = 0; w < wid; ++w) wbase += wsum[w];
  int run = wbase + x - s;
#pragma unroll
  for (int j = 0; j < 4; ++j) {
    int i = base + j;
    if (i < n) excl[i] = run;
    run += v[j];
  }
  if (t == 255) blocksums[blockIdx.x] = wbase + x;
}

__global__ void scan2_kernel(const int* __restrict__ blocksums, int* __restrict__ blockbase,
                             int nb, int* __restrict__ total_out) {
  int lane = threadIdx.x;
  __shared__ int running_s;
  if (lane == 0) running_s = 0;
  __syncthreads();
  for (int base = 0; base < nb; base += 64) {
    int i = base + lane;
    int v = (i < nb) ? blocksums[i] : 0;
    int x = v;
#pragma unroll
    for (int d = 1; d < 64; d <<= 1) {
      int y = __shfl_up(x, d);
      if (lane >= d) x += y;
    }
    int running = running_s;
    if (i < nb) blockbase[i] = running + x - v;
    __syncthreads();
    if (lane == 63) running_s = running + x;
    __syncthreads();
  }
  if (lane == 0) *total_out = running_s;
}

__global__ void scan3_kernel(int* __restrict__ excl, const int* __restrict__ blockbase,
                             int* __restrict__ cursor, int n) {
  int i = blockIdx.x * 256 + threadIdx.x;
  if (i < n) {
    int v = excl[i] + blockbase[i >> 10];
    excl[i] = v;
    cursor[i] = v;
  }
}

__global__ void scatter_kernel(const int* __restrict__ ei, int E, int N,
                               int* __restrict__ cursor, int* __restrict__ srcs,
                               int* __restrict__ dsts) {
  int e = blockIdx.x * 256 + threadIdx.x;
  int E2 = E + N;
  if (e >= E2) return;
  int s, d;
  if (e < E) { s = ei[e]; d = ei[E + e]; }
  else       { s = e - E; d = e - E; }
  int pos = atomicAdd(&cursor[d], 1);
  srcs[pos] = s;
  dsts[pos] = d;
}

// ---------------- W -> transposed fp16 (Bt[n*K+k] = W[k*HOUT+n]) ----------------
__global__ void convw_kernel(const float* __restrict__ W, _Float16* __restrict__ Bt, int K) {
  int i = blockIdx.x * 256 + threadIdx.x;
  if (i >= HOUT * K) return;
  int n = i / K, k = i - n * K;
  Bt[i] = (_Float16)W[(size_t)k * HOUT + n];
}

// ---------------- fp16 MFMA GEMM with fused al epilogue ----------------
// C[M,192] = A[M,K](f32) @ Bt^T (Bt is [192][K] fp16). Writes fp16 Ch and
// per-node al_s/al_d (f32 dot of the f32 accumulators with a_src/a_dst).
// Block: 256 thr = 4 waves; BM=64 (16 rows/wave); full N=192 (12 MFMA col-blocks).
#define GBM 64
#define GBK 32

__global__ __launch_bounds__(256) void gemm_mfma_kernel(
    const float* __restrict__ A, const _Float16* __restrict__ Bt,
    _Float16* __restrict__ Ch, const float* __restrict__ asrc,
    const float* __restrict__ adst, float* __restrict__ als,
    float* __restrict__ ald, int M, int K) {
  __shared__ _Float16 As[GBM][GBK];     // [row][k]
  __shared__ _Float16 Bs[HOUT][GBK];    // [col][k]  (transposed weights)
  int tid = threadIdx.x;
  int bm = blockIdx.x * GBM;
  int w  = tid >> 6;    // wave 0..3 -> rows w*16..w*16+15
  int l  = tid & 63;
  int lg = l & 15;
  int lh = l >> 4;

  floatx4 acc[12];
#pragma unroll
  for (int cb = 0; cb < 12; ++cb) acc[cb] = (floatx4){0.f, 0.f, 0.f, 0.f};

  for (int kt = 0; kt < K; kt += GBK) {
    // stage A: 64 rows x 32 k, f32 -> fp16
    {
      int ar = tid >> 2;
      int ak = (tid & 3) * 8;
      int gm = bm + ar;
      float4 f0 = make_float4(0.f, 0.f, 0.f, 0.f), f1 = f0;
      if (gm < M) {
        const float* src = &A[(size_t)gm * K + kt + ak];
        f0 = *(const float4*)&src[0];
        f1 = *(const float4*)&src[4];
      }
      half8 h8;
      h8[0] = (_Float16)f0.x; h8[1] = (_Float16)f0.y;
      h8[2] = (_Float16)f0.z; h8[3] = (_Float16)f0.w;
      h8[4] = (_Float16)f1.x; h8[5] = (_Float16)f1.y;
      h8[6] = (_Float16)f1.z; h8[7] = (_Float16)f1.w;
      *(half8*)&As[ar][ak] = h8;
    }
    // stage B: 192 cols x 32 k fp16 (3 x b128 per thread)
#pragma unroll
    for (int i = 0; i < 3; ++i) {
      int c = tid + 256 * i;
      int row = c >> 2;
      int part = (c & 3) * 8;
      *(half8*)&Bs[row][part] = *(const half8*)&Bt[(size_t)row * K + kt + part];
    }
    __syncthreads();

    half8 a8 = *(const half8*)&As[w * 16 + lg][lh * 8];
#pragma unroll
    for (int cb = 0; cb < 12; ++cb) {
      half8 b8 = *(const half8*)&Bs[cb * 16 + lg][lh * 8];
      acc[cb] = __builtin_amdgcn_mfma_f32_16x16x32_f16(a8, b8, acc[cb], 0, 0, 0);
    }
    __syncthreads();
  }

  // epilogue: lane holds C[row = bm + w*16 + lh*4 + r][col = cb*16 + lg]
  float as_c[12], ad_c[12];
#pragma unroll
  for (int cb = 0; cb < 12; ++cb) {
    int col = cb * 16 + lg;
    as_c[cb] = asrc[col];
    ad_c[cb] = adst[col];
  }
#pragma unroll
  for (int r = 0; r < 4; ++r) {
    int node = bm + w * 16 + lh * 4 + r;
    if (node < M) {
      _Float16* hr = &Ch[(size_t)node * HOUT];
#pragma unroll
      for (int cb = 0; cb < 12; ++cb) hr[cb * 16 + lg] = (_Float16)acc[cb][r];
    }
    float ps0 = 0.f, ps1 = 0.f, ps2 = 0.f, pd0 = 0.f, pd1 = 0.f, pd2 = 0.f;
#pragma unroll
    for (int q = 0; q < 4; ++q) {
      ps0 += acc[q][r] * as_c[q];
      pd0 += acc[q][r] * ad_c[q];
      ps1 += acc[4 + q][r] * as_c[4 + q];
      pd1 += acc[4 + q][r] * ad_c[4 + q];
      ps2 += acc[8 + q][r] * as_c[8 + q];
      pd2 += acc[8 + q][r] * ad_c[8 + q];
    }
#pragma unroll
    for (int m = 1; m < 16; m <<= 1) {
      ps0 += __shfl_xor(ps0, m);
      ps1 += __shfl_xor(ps1, m);
      ps2 += __shfl_xor(ps2, m);
      pd0 += __shfl_xor(pd0, m);
      pd1 += __shfl_xor(pd1, m);
      pd2 += __shfl_xor(pd2, m);
    }
    if (lg == 0 && node < M) {
      als[node * 4 + 0] = ps0;
      als[node * 4 + 1] = ps1;
      als[node * 4 + 2] = ps2;
      ald[node * 4 + 0] = pd0;
      ald[node * 4 + 1] = pd1;
      ald[node * 4 + 2] = pd2;
    }
  }
}

// ---------------- per-edge softmax numerators (stride-4) ----------------
__global__ void w_kernel(const float* __restrict__ als, const float* __restrict__ ald,
                         const int* __restrict__ srcs, const int* __restrict__ dsts,
                         float* __restrict__ w, int E2) {
  int p = blockIdx.x * 256 + threadIdx.x;
  if (p >= E2) return;
  int s = srcs[p], d = dsts[p];
  float4 as4 = *(const float4*)&als[s * 4];
  float4 ad4 = *(const float4*)&ald[d * 4];
  float l0 = as4.x + ad4.x;
  float l1 = as4.y + ad4.y;
  float l2 = as4.z + ad4.z;
  l0 = (l0 > 0.f) ? l0 : NEG_SLOPE * l0;
  l1 = (l1 > 0.f) ? l1 : NEG_SLOPE * l1;
  l2 = (l2 > 0.f) ? l2 : NEG_SLOPE * l2;
  float4 wv = make_float4(__expf(l0), __expf(l1), __expf(l2), 0.f);
  *(float4*)&w[p * 4] = wv;
}

// ---------------- per-dst-node aggregation: fp16 gather + f32 fma ----------------
__global__ void agg_kernel(const __half* __restrict__ hh, const float4* __restrict__ w4,
                           const int* __restrict__ offsets, const int* __restrict__ srcs,
                           const float* __restrict__ bias, float* __restrict__ out,
                           int n_nodes) {
  int wave = (blockIdx.x * blockDim.x + threadIdx.x) >> 6;
  int lane = threadIdx.x & 63;
  if (wave >= n_nodes) return;
  int node = wave;
  int beg = offsets[node], end = offsets[node + 1];
  float s0 = 0.f, s1 = 0.f, s2 = 0.f;
  float a0 = 0.f, a1 = 0.f, a2 = 0.f;
  int p = beg;
  for (; p + 3 < end; p += 4) {
    int sa = srcs[p], sb = srcs[p + 1], sc = srcs[p + 2], sd = srcs[p + 3];
    const __half* ha = hh + (size_t)sa * HOUT;
    const __half* hb = hh + (size_t)sb * HOUT;
    const __half* hc = hh + (size_t)sc * HOUT;
    const __half* hd = hh + (size_t)sd * HOUT;
    float4 wa = w4[p], wb = w4[p + 1], wc = w4[p + 2], wd = w4[p + 3];
    float va0 = __half2float(ha[lane]);
    float va1 = __half2float(ha[64 + lane]);
    float va2 = __half2float(ha[128 + lane]);
    float vb0 = __half2float(hb[lane]);
    float vb1 = __half2float(hb[64 + lane]);
    float vb2 = __half2float(hb[128 + lane]);
    float vc0 = __half2float(hc[lane]);
    float vc1 = __half2float(hc[64 + lane]);
    float vc2 = __half2float(hc[128 + lane]);
    float vd0 = __half2float(hd[lane]);
    float vd1 = __half2float(hd[64 + lane]);
    float vd2 = __half2float(hd[128 + lane]);
    s0 += wa.x + wb.x + wc.x + wd.x;
    s1 += wa.y + wb.y + wc.y + wd.y;
    s2 += wa.z + wb.z + wc.z + wd.z;
    a0 += wa.x * va0 + wb.x * vb0 + wc.x * vc0 + wd.x * vd0;
    a1 += wa.y * va1 + wb.y * vb1 + wc.y * vc1 + wd.y * vd1;
    a2 += wa.z * va2 + wb.z * vb2 + wc.z * vc2 + wd.z * vd2;
  }
  for (; p < end; ++p) {
    int sa = srcs[p];
    const __half* ha = hh + (size_t)sa * HOUT;
    float4 wa = w4[p];
    s0 += wa.x; a0 += wa.x * __half2float(ha[lane]);
    s1 += wa.y; a1 += wa.y * __half2float(ha[64 + lane]);
    s2 += wa.z; a2 += wa.z * __half2float(ha[128 + lane]);
  }
  float r0 = 1.f / (s0 + 1e-16f);
  float r1 = 1.f / (s1 + 1e-16f);
  float r2 = 1.f / (s2 + 1e-16f);
  float* o = out + (size_t)node * HOUT;
  o[lane]       = fmaxf(a0 * r0 + bias[lane], 0.f);
  o[64 + lane]  = fmaxf(a1 * r1 + bias[64 + lane], 0.f);
  o[128 + lane] = fmaxf(a2 * r2 + bias[128 + lane], 0.f);
}

// ---------------- mean pool over sorted batch + relu ----------------
__global__ void pool_kernel(const float* __restrict__ h, const int* __restrict__ batch,
                            float* __restrict__ out, int n_nodes) {
  __shared__ int sbe[2];
  int g = blockIdx.x;
  if (threadIdx.x < 2) {
    int key = g + (int)threadIdx.x;
    int lo = 0, hi = n_nodes;
    while (lo < hi) {
      int mid = (lo + hi) >> 1;
      if (batch[mid] < key) lo = mid + 1; else hi = mid;
    }
    sbe[threadIdx.x] = lo;
  }
  __syncthreads();
  int beg = sbe[0], end = sbe[1];
  float sum = 0.f;
  for (int i = beg; i < end; ++i) sum += h[(size_t)i * HOUT + threadIdx.x];
  float cnt = (float)(end - beg);
  float v = (cnt > 0.f) ? sum / cnt : 0.f;
  out[(size_t)g * HOUT + threadIdx.x] = fmaxf(v, 0.f);
}

// ---------------- launcher ----------------

extern "C" void kernel_launch(void* const* d_in, const int* in_sizes, int n_in,
                              void* d_out, int out_size, void* d_ws, size_t ws_size,
                              hipStream_t stream) {
  const float* x   = (const float*)d_in[0];
  const int*   ei  = (const int*)d_in[1];
  const int*   bat = (const int*)d_in[2];
  const float* W1  = (const float*)d_in[3];
  const float* a1s = (const float*)d_in[4];
  const float* a1d = (const float*)d_in[5];
  const float* b1  = (const float*)d_in[6];
  const float* W2  = (const float*)d_in[7];
  const float* a2s = (const float*)d_in[8];
  const float* a2d = (const float*)d_in[9];
  const float* b2  = (const float*)d_in[10];
  float* out = (float*)d_out;

  int N   = in_sizes[2];
  int Fin = in_sizes[0] / N;
  int E   = in_sizes[1] / 2;
  int E2  = E + N;
  int G   = out_size / HOUT;

  char* p = (char*)d_ws;
  auto carve = [&](size_t bytes) -> char* {
    char* r = p;
    p += (bytes + 255) & ~(size_t)255;
    return r;
  };
  int*      counts    = (int*)carve((size_t)N * 4);
  int*      offsets   = (int*)carve((size_t)(N + 1) * 4);
  int*      cursor    = (int*)carve((size_t)N * 4);
  int*      blocksums = (int*)carve(256 * 4);
  int*      blockbase = (int*)carve(256 * 4);
  int*      srcs      = (int*)carve((size_t)E2 * 4);
  int*      dsts      = (int*)carve((size_t)E2 * 4);
  float*    wbuf      = (float*)carve((size_t)E2 * 4 * 4);
  float*    als       = (float*)carve((size_t)N * 4 * 4);
  float*    ald       = (float*)carve((size_t)N * 4 * 4);
  float*    bufB      = (float*)carve((size_t)N * HOUT * 4);
  _Float16* hh        = (_Float16*)carve((size_t)N * HOUT * 2);
  _Float16* W1t       = (_Float16*)carve((size_t)HOUT * Fin * 2);
  _Float16* W2t       = (_Float16*)carve((size_t)HOUT * HOUT * 2);
  (void)ws_size;

  // --- CSR build (dst-sorted edge list) + weight conversion ---
  zero_int_kernel<<<(N + 255) / 256, 256, 0, stream>>>(counts, N);
  hist_kernel<<<(E2 + 255) / 256, 256, 0, stream>>>(ei, E, N, counts);
  int nb = (N + 1023) / 1024;
  scan1_kernel<<<nb, 256, 0, stream>>>(counts, offsets, blocksums, N);
  scan2_kernel<<<1, 64, 0, stream>>>(blocksums, blockbase, nb, offsets + N);
  scan3_kernel<<<(N + 255) / 256, 256, 0, stream>>>(offsets, blockbase, cursor, N);
  scatter_kernel<<<(E2 + 255) / 256, 256, 0, stream>>>(ei, E, N, cursor, srcs, dsts);
  convw_kernel<<<(HOUT * Fin + 255) / 256, 256, 0, stream>>>(W1, W1t, Fin);
  convw_kernel<<<(HOUT * HOUT + 255) / 256, 256, 0, stream>>>(W2, W2t, HOUT);

  int wave_blocks = (N * 64 + 255) / 256;
  int gemm_blocks = (N + GBM - 1) / GBM;
  int edge_blocks = (E2 + 255) / 256;

  // --- layer 1 ---
  gemm_mfma_kernel<<<gemm_blocks, 256, 0, stream>>>(x, W1t, hh, a1s, a1d, als, ald, N, Fin);
  w_kernel<<<edge_blocks, 256, 0, stream>>>(als, ald, srcs, dsts, wbuf, E2);
  agg_kernel<<<wave_blocks, 256, 0, stream>>>((const __half*)hh, (const float4*)wbuf,
                                              offsets, srcs, b1, bufB, N);

  // --- layer 2 ---
  gemm_mfma_kernel<<<gemm_blocks, 256, 0, stream>>>(bufB, W2t, hh, a2s, a2d, als, ald, N, HOUT);
  w_kernel<<<edge_blocks, 256, 0, stream>>>(als, ald, srcs, dsts, wbuf, E2);
  agg_kernel<<<wave_blocks, 256, 0, stream>>>((const __half*)hh, (const float4*)wbuf,
                                              offsets, srcs, b2, bufB, N);

  // --- pool ---
  pool_kernel<<<G, HOUT, 0, stream>>>(bufB, bat, out, N);
}

// Round 8
// 369.342 us; speedup vs baseline: 1.7536x; 1.0976x over previous
//
#include <hip/hip_runtime.h>
#include <hip/hip_fp16.h>
#include <math.h>

#define HEADS 3
#define HID 64
#define HOUT 192
#define NEG_SLOPE 0.2f

typedef _Float16 half8 __attribute__((ext_vector_type(8)));
typedef float floatx4 __attribute__((ext_vector_type(4)));

// ---------------- CSR build ----------------

__global__ void hist_kernel(const int* __restrict__ ei, int E, int N,
                            int* __restrict__ counts) {
  int e = blockIdx.x * 256 + threadIdx.x;
  int E2 = E + N;
  if (e >= E2) return;
  int d = (e < E) ? ei[E + e] : (e - E);
  atomicAdd(&counts[d], 1);
}

__global__ void scan1_kernel(const int* __restrict__ counts, int* __restrict__ excl,
                             int* __restrict__ blocksums, int n) {
  int t = threadIdx.x;
  int base = blockIdx.x * 1024 + t * 4;
  int v[4];
  int s = 0;
#pragma unroll
  for (int j = 0; j < 4; ++j) {
    int i = base + j;
    v[j] = (i < n) ? counts[i] : 0;
    s += v[j];
  }
  int lane = t & 63, wid = t >> 6;
  int x = s;
#pragma unroll
  for (int d = 1; d < 64; d <<= 1) {
    int y = __shfl_up(x, d);
    if (lane >= d) x += y;
  }
  __shared__ int wsum[4];
  if (lane == 63) wsum[wid] = x;
  __syncthreads();
  int wbase = 0;
  for (int w = 0; w < wid; ++w) wbase += wsum[w];
  int run = wbase + x - s;
#pragma unroll
  for (int j = 0; j < 4; ++j) {
    int i = base + j;
    if (i < n) excl[i] = run;
    run += v[j];
  }
  if (t == 255) blocksums[blockIdx.x] = wbase + x;
}

__global__ void scan2_kernel(const int* __restrict__ blocksums, int* __restrict__ blockbase,
                             int nb, int* __restrict__ total_out) {
  int lane = threadIdx.x;
  __shared__ int running_s;
  if (lane == 0) running_s = 0;
  __syncthreads();
  for (int base = 0; base < nb; base += 64) {
    int i = base + lane;
    int v = (i < nb) ? blocksums[i] : 0;
    int x = v;
#pragma unroll
    for (int d = 1; d < 64; d <<= 1) {
      int y = __shfl_up(x, d);
      if (lane >= d) x += y;
    }
    int running = running_s;
    if (i < nb) blockbase[i] = running + x - v;
    __syncthreads();
    if (lane == 63) running_s = running + x;
    __syncthreads();
  }
  if (lane == 0) *total_out = running_s;
}

__global__ void scan3_kernel(int* __restrict__ excl, const int* __restrict__ blockbase,
                             int* __restrict__ cursor, int n) {
  int i = blockIdx.x * 256 + threadIdx.x;
  if (i < n) {
    int v = excl[i] + blockbase[i >> 10];
    excl[i] = v;
    cursor[i] = v;
  }
}

__global__ void scatter_kernel(const int* __restrict__ ei, int E, int N,
                               int* __restrict__ cursor, int* __restrict__ srcs,
                               int* __restrict__ dsts) {
  int e = blockIdx.x * 256 + threadIdx.x;
  int E2 = E + N;
  if (e >= E2) return;
  int s, d;
  if (e < E) { s = ei[e]; d = ei[E + e]; }
  else       { s = e - E; d = e - E; }
  int pos = atomicAdd(&cursor[d], 1);
  srcs[pos] = s;
  dsts[pos] = d;
}

// ---------------- W -> transposed fp16 (Bt[n*K+k] = W[k*HOUT+n]) ----------------
__global__ void convw_kernel(const float* __restrict__ W, _Float16* __restrict__ Bt, int K) {
  int i = blockIdx.x * 256 + threadIdx.x;
  if (i >= HOUT * K) return;
  int n = i / K, k = i - n * K;
  Bt[i] = (_Float16)W[(size_t)k * HOUT + n];
}

// ---------------- fp16 MFMA GEMM with fused al epilogue ----------------
// C[M,192] = A[M,K] @ Bt^T (Bt is [192][K] fp16). A is f32 or fp16 (templated).
// Writes fp16 Ch and per-node al_s/al_d from the f32 accumulators.
// Block: 256 thr = 4 waves; BM=64 (16 rows/wave); full N=192 (12 MFMA col-blocks).
#define GBM 64
#define GBK 32

template <typename T>
__global__ __launch_bounds__(256) void gemm_mfma_kernel(
    const T* __restrict__ A, const _Float16* __restrict__ Bt,
    _Float16* __restrict__ Ch, const float* __restrict__ asrc,
    const float* __restrict__ adst, float* __restrict__ als,
    float* __restrict__ ald, int M, int K) {
  __shared__ _Float16 As[GBM][GBK];     // [row][k]
  __shared__ _Float16 Bs[HOUT][GBK];    // [col][k]  (transposed weights)
  int tid = threadIdx.x;
  int bm = blockIdx.x * GBM;
  int w  = tid >> 6;    // wave 0..3 -> rows w*16..w*16+15
  int l  = tid & 63;
  int lg = l & 15;
  int lh = l >> 4;

  floatx4 acc[12];
#pragma unroll
  for (int cb = 0; cb < 12; ++cb) acc[cb] = (floatx4){0.f, 0.f, 0.f, 0.f};

  for (int kt = 0; kt < K; kt += GBK) {
    // stage A: 64 rows x 32 k -> fp16
    {
      int ar = tid >> 2;
      int ak = (tid & 3) * 8;
      int gm = bm + ar;
      half8 h8 = {};
      if (gm < M) {
        if constexpr (sizeof(T) == 4) {
          const float* src = (const float*)&A[(size_t)gm * K + kt + ak];
          float4 f0 = *(const float4*)&src[0];
          float4 f1 = *(const float4*)&src[4];
          h8[0] = (_Float16)f0.x; h8[1] = (_Float16)f0.y;
          h8[2] = (_Float16)f0.z; h8[3] = (_Float16)f0.w;
          h8[4] = (_Float16)f1.x; h8[5] = (_Float16)f1.y;
          h8[6] = (_Float16)f1.z; h8[7] = (_Float16)f1.w;
        } else {
          h8 = *(const half8*)&A[(size_t)gm * K + kt + ak];
        }
      }
      *(half8*)&As[ar][ak] = h8;
    }
    // stage B: 192 cols x 32 k fp16 (3 x b128 per thread)
#pragma unroll
    for (int i = 0; i < 3; ++i) {
      int c = tid + 256 * i;
      int row = c >> 2;
      int part = (c & 3) * 8;
      *(half8*)&Bs[row][part] = *(const half8*)&Bt[(size_t)row * K + kt + part];
    }
    __syncthreads();

    half8 a8 = *(const half8*)&As[w * 16 + lg][lh * 8];
#pragma unroll
    for (int cb = 0; cb < 12; ++cb) {
      half8 b8 = *(const half8*)&Bs[cb * 16 + lg][lh * 8];
      acc[cb] = __builtin_amdgcn_mfma_f32_16x16x32_f16(a8, b8, acc[cb], 0, 0, 0);
    }
    __syncthreads();
  }

  // epilogue: lane holds C[row = bm + w*16 + lh*4 + r][col = cb*16 + lg]
  float as_c[12], ad_c[12];
#pragma unroll
  for (int cb = 0; cb < 12; ++cb) {
    int col = cb * 16 + lg;
    as_c[cb] = asrc[col];
    ad_c[cb] = adst[col];
  }
#pragma unroll
  for (int r = 0; r < 4; ++r) {
    int node = bm + w * 16 + lh * 4 + r;
    if (node < M) {
      _Float16* hr = &Ch[(size_t)node * HOUT];
#pragma unroll
      for (int cb = 0; cb < 12; ++cb) hr[cb * 16 + lg] = (_Float16)acc[cb][r];
    }
    float ps0 = 0.f, ps1 = 0.f, ps2 = 0.f, pd0 = 0.f, pd1 = 0.f, pd2 = 0.f;
#pragma unroll
    for (int q = 0; q < 4; ++q) {
      ps0 += acc[q][r] * as_c[q];
      pd0 += acc[q][r] * ad_c[q];
      ps1 += acc[4 + q][r] * as_c[4 + q];
      pd1 += acc[4 + q][r] * ad_c[4 + q];
      ps2 += acc[8 + q][r] * as_c[8 + q];
      pd2 += acc[8 + q][r] * ad_c[8 + q];
    }
#pragma unroll
    for (int m = 1; m < 16; m <<= 1) {
      ps0 += __shfl_xor(ps0, m);
      ps1 += __shfl_xor(ps1, m);
      ps2 += __shfl_xor(ps2, m);
      pd0 += __shfl_xor(pd0, m);
      pd1 += __shfl_xor(pd1, m);
      pd2 += __shfl_xor(pd2, m);
    }
    if (lg == 0 && node < M) {
      als[node * 4 + 0] = ps0;
      als[node * 4 + 1] = ps1;
      als[node * 4 + 2] = ps2;
      ald[node * 4 + 0] = pd0;
      ald[node * 4 + 1] = pd1;
      ald[node * 4 + 2] = pd2;
    }
  }
}

// ---------------- per-edge softmax numerators (stride-4) ----------------
__global__ void w_kernel(const float* __restrict__ als, const float* __restrict__ ald,
                         const int* __restrict__ srcs, const int* __restrict__ dsts,
                         float* __restrict__ w, int E2) {
  int p = blockIdx.x * 256 + threadIdx.x;
  if (p >= E2) return;
  int s = srcs[p], d = dsts[p];
  float4 as4 = *(const float4*)&als[s * 4];
  float4 ad4 = *(const float4*)&ald[d * 4];
  float l0 = as4.x + ad4.x;
  float l1 = as4.y + ad4.y;
  float l2 = as4.z + ad4.z;
  l0 = (l0 > 0.f) ? l0 : NEG_SLOPE * l0;
  l1 = (l1 > 0.f) ? l1 : NEG_SLOPE * l1;
  l2 = (l2 > 0.f) ? l2 : NEG_SLOPE * l2;
  float4 wv = make_float4(__expf(l0), __expf(l1), __expf(l2), 0.f);
  *(float4*)&w[p * 4] = wv;
}

// ---------------- per-dst-node aggregation: fp16 gather + f32 fma ----------------
// Writes fp16 (next layer input) and/or f32 (pool input); bias+relu fused.
__global__ void agg_kernel(const __half* __restrict__ hh, const float4* __restrict__ w4,
                           const int* __restrict__ offsets, const int* __restrict__ srcs,
                           const float* __restrict__ bias, float* __restrict__ out_f,
                           _Float16* __restrict__ out_h, int n_nodes) {
  int wave = (blockIdx.x * blockDim.x + threadIdx.x) >> 6;
  int lane = threadIdx.x & 63;
  if (wave >= n_nodes) return;
  int node = wave;
  int beg = offsets[node], end = offsets[node + 1];
  float s0 = 0.f, s1 = 0.f, s2 = 0.f;
  float a0 = 0.f, a1 = 0.f, a2 = 0.f;
  int p = beg;
  for (; p + 3 < end; p += 4) {
    int sa = srcs[p], sb = srcs[p + 1], sc = srcs[p + 2], sd = srcs[p + 3];
    const __half* ha = hh + (size_t)sa * HOUT;
    const __half* hb = hh + (size_t)sb * HOUT;
    const __half* hc = hh + (size_t)sc * HOUT;
    const __half* hd = hh + (size_t)sd * HOUT;
    float4 wa = w4[p], wb = w4[p + 1], wc = w4[p + 2], wd = w4[p + 3];
    float va0 = __half2float(ha[lane]);
    float va1 = __half2float(ha[64 + lane]);
    float va2 = __half2float(ha[128 + lane]);
    float vb0 = __half2float(hb[lane]);
    float vb1 = __half2float(hb[64 + lane]);
    float vb2 = __half2float(hb[128 + lane]);
    float vc0 = __half2float(hc[lane]);
    float vc1 = __half2float(hc[64 + lane]);
    float vc2 = __half2float(hc[128 + lane]);
    float vd0 = __half2float(hd[lane]);
    float vd1 = __half2float(hd[64 + lane]);
    float vd2 = __half2float(hd[128 + lane]);
    s0 += wa.x + wb.x + wc.x + wd.x;
    s1 += wa.y + wb.y + wc.y + wd.y;
    s2 += wa.z + wb.z + wc.z + wd.z;
    a0 += wa.x * va0 + wb.x * vb0 + wc.x * vc0 + wd.x * vd0;
    a1 += wa.y * va1 + wb.y * vb1 + wc.y * vc1 + wd.y * vd1;
    a2 += wa.z * va2 + wb.z * vb2 + wc.z * vc2 + wd.z * vd2;
  }
  for (; p < end; ++p) {
    int sa = srcs[p];
    const __half* ha = hh + (size_t)sa * HOUT;
    float4 wa = w4[p];
    s0 += wa.x; a0 += wa.x * __half2float(ha[lane]);
    s1 += wa.y; a1 += wa.y * __half2float(ha[64 + lane]);
    s2 += wa.z; a2 += wa.z * __half2float(ha[128 + lane]);
  }
  float r0 = 1.f / (s0 + 1e-16f);
  float r1 = 1.f / (s1 + 1e-16f);
  float r2 = 1.f / (s2 + 1e-16f);
  float v0 = fmaxf(a0 * r0 + bias[lane], 0.f);
  float v1 = fmaxf(a1 * r1 + bias[64 + lane], 0.f);
  float v2 = fmaxf(a2 * r2 + bias[128 + lane], 0.f);
  if (out_f) {
    float* o = out_f + (size_t)node * HOUT;
    o[lane] = v0; o[64 + lane] = v1; o[128 + lane] = v2;
  }
  if (out_h) {
    _Float16* o = out_h + (size_t)node * HOUT;
    o[lane] = (_Float16)v0; o[64 + lane] = (_Float16)v1; o[128 + lane] = (_Float16)v2;
  }
}

// ---------------- mean pool over sorted batch + relu ----------------
__global__ void pool_kernel(const float* __restrict__ h, const int* __restrict__ batch,
                            float* __restrict__ out, int n_nodes) {
  __shared__ int sbe[2];
  int g = blockIdx.x;
  if (threadIdx.x < 2) {
    int key = g + (int)threadIdx.x;
    int lo = 0, hi = n_nodes;
    while (lo < hi) {
      int mid = (lo + hi) >> 1;
      if (batch[mid] < key) lo = mid + 1; else hi = mid;
    }
    sbe[threadIdx.x] = lo;
  }
  __syncthreads();
  int beg = sbe[0], end = sbe[1];
  int t = threadIdx.x;
  float sum = 0.f;
  int i = beg;
  for (; i + 7 < end; i += 8) {
    float x0 = h[(size_t)(i + 0) * HOUT + t];
    float x1 = h[(size_t)(i + 1) * HOUT + t];
    float x2 = h[(size_t)(i + 2) * HOUT + t];
    float x3 = h[(size_t)(i + 3) * HOUT + t];
    float x4 = h[(size_t)(i + 4) * HOUT + t];
    float x5 = h[(size_t)(i + 5) * HOUT + t];
    float x6 = h[(size_t)(i + 6) * HOUT + t];
    float x7 = h[(size_t)(i + 7) * HOUT + t];
    sum += ((x0 + x1) + (x2 + x3)) + ((x4 + x5) + (x6 + x7));
  }
  for (; i < end; ++i) sum += h[(size_t)i * HOUT + t];
  float cnt = (float)(end - beg);
  float v = (cnt > 0.f) ? sum / cnt : 0.f;
  out[(size_t)g * HOUT + t] = fmaxf(v, 0.f);
}

// ---------------- launcher ----------------

extern "C" void kernel_launch(void* const* d_in, const int* in_sizes, int n_in,
                              void* d_out, int out_size, void* d_ws, size_t ws_size,
                              hipStream_t stream) {
  const float* x   = (const float*)d_in[0];
  const int*   ei  = (const int*)d_in[1];
  const int*   bat = (const int*)d_in[2];
  const float* W1  = (const float*)d_in[3];
  const float* a1s = (const float*)d_in[4];
  const float* a1d = (const float*)d_in[5];
  const float* b1  = (const float*)d_in[6];
  const float* W2  = (const float*)d_in[7];
  const float* a2s = (const float*)d_in[8];
  const float* a2d = (const float*)d_in[9];
  const float* b2  = (const float*)d_in[10];
  float* out = (float*)d_out;

  int N   = in_sizes[2];
  int Fin = in_sizes[0] / N;
  int E   = in_sizes[1] / 2;
  int E2  = E + N;
  int G   = out_size / HOUT;

  char* p = (char*)d_ws;
  auto carve = [&](size_t bytes) -> char* {
    char* r = p;
    p += (bytes + 255) & ~(size_t)255;
    return r;
  };
  int*      counts    = (int*)carve((size_t)N * 4);
  int*      offsets   = (int*)carve((size_t)(N + 1) * 4);
  int*      cursor    = (int*)carve((size_t)N * 4);
  int*      blocksums = (int*)carve(256 * 4);
  int*      blockbase = (int*)carve(256 * 4);
  int*      srcs      = (int*)carve((size_t)E2 * 4);
  int*      dsts      = (int*)carve((size_t)E2 * 4);
  float*    wbuf      = (float*)carve((size_t)E2 * 4 * 4);
  float*    als       = (float*)carve((size_t)N * 4 * 4);
  float*    ald       = (float*)carve((size_t)N * 4 * 4);
  float*    bufB      = (float*)carve((size_t)N * HOUT * 4);
  _Float16* hh        = (_Float16*)carve((size_t)N * HOUT * 2);
  _Float16* hh2       = (_Float16*)carve((size_t)N * HOUT * 2);
  _Float16* W1t       = (_Float16*)carve((size_t)HOUT * Fin * 2);
  _Float16* W2t       = (_Float16*)carve((size_t)HOUT * HOUT * 2);
  (void)ws_size;

  // --- CSR build (dst-sorted edge list) + weight conversion ---
  hipMemsetAsync(counts, 0, (size_t)N * 4, stream);
  hist_kernel<<<(E2 + 255) / 256, 256, 0, stream>>>(ei, E, N, counts);
  int nb = (N + 1023) / 1024;
  scan1_kernel<<<nb, 256, 0, stream>>>(counts, offsets, blocksums, N);
  scan2_kernel<<<1, 64, 0, stream>>>(blocksums, blockbase, nb, offsets + N);
  scan3_kernel<<<(N + 255) / 256, 256, 0, stream>>>(offsets, blockbase, cursor, N);
  scatter_kernel<<<(E2 + 255) / 256, 256, 0, stream>>>(ei, E, N, cursor, srcs, dsts);
  convw_kernel<<<(HOUT * Fin + 255) / 256, 256, 0, stream>>>(W1, W1t, Fin);
  convw_kernel<<<(HOUT * HOUT + 255) / 256, 256, 0, stream>>>(W2, W2t, HOUT);

  int wave_blocks = (N * 64 + 255) / 256;
  int gemm_blocks = (N + GBM - 1) / GBM;
  int edge_blocks = (E2 + 255) / 256;

  // --- layer 1 ---
  gemm_mfma_kernel<float><<<gemm_blocks, 256, 0, stream>>>(x, W1t, hh, a1s, a1d, als, ald, N, Fin);
  w_kernel<<<edge_blocks, 256, 0, stream>>>(als, ald, srcs, dsts, wbuf, E2);
  agg_kernel<<<wave_blocks, 256, 0, stream>>>((const __half*)hh, (const float4*)wbuf,
                                              offsets, srcs, b1, nullptr, hh2, N);

  // --- layer 2 ---
  gemm_mfma_kernel<_Float16><<<gemm_blocks, 256, 0, stream>>>(hh2, W2t, hh, a2s, a2d, als, ald, N, HOUT);
  w_kernel<<<edge_blocks, 256, 0, stream>>>(als, ald, srcs, dsts, wbuf, E2);
  agg_kernel<<<wave_blocks, 256, 0, stream>>>((const __half*)hh, (const float4*)wbuf,
                                              offsets, srcs, b2, bufB, nullptr, N);

  // --- pool ---
  pool_kernel<<<G, HOUT, 0, stream>>>(bufB, bat, out, N);
}

// Round 9
// 366.168 us; speedup vs baseline: 1.7688x; 1.0087x over previous
//
#include <hip/hip_runtime.h>
#include <hip/hip_fp16.h>
#include <math.h>

#define HOUT 192
#define NEG_SLOPE 0.2f
#define BCOLS 208   // 192 h-cols + 3 wsrc + 3 wdst + 10 pad (unused)

typedef _Float16 half8 __attribute__((ext_vector_type(8)));
typedef float floatx4 __attribute__((ext_vector_type(4)));

// ---------------- CSR build ----------------

__global__ void hist_kernel(const int* __restrict__ ei, int E, int N,
                            int* __restrict__ counts) {
  int e = blockIdx.x * 256 + threadIdx.x;
  int E2 = E + N;
  if (e >= E2) return;
  int d = (e < E) ? ei[E + e] : (e - E);
  atomicAdd(&counts[d], 1);
}

__global__ void scan1_kernel(const int* __restrict__ counts, int* __restrict__ excl,
                             int* __restrict__ blocksums, int n) {
  int t = threadIdx.x;
  int base = blockIdx.x * 1024 + t * 4;
  int v[4];
  int s = 0;
#pragma unroll
  for (int j = 0; j < 4; ++j) {
    int i = base + j;
    v[j] = (i < n) ? counts[i] : 0;
    s += v[j];
  }
  int lane = t & 63, wid = t >> 6;
  int x = s;
#pragma unroll
  for (int d = 1; d < 64; d <<= 1) {
    int y = __shfl_up(x, d);
    if (lane >= d) x += y;
  }
  __shared__ int wsum[4];
  if (lane == 63) wsum[wid] = x;
  __syncthreads();
  int wbase = 0;
  for (int w = 0; w < wid; ++w) wbase += wsum[w];
  int run = wbase + x - s;
#pragma unroll
  for (int j = 0; j < 4; ++j) {
    int i = base + j;
    if (i < n) excl[i] = run;
    run += v[j];
  }
  if (t == 255) blocksums[blockIdx.x] = wbase + x;
}

__global__ void scan2_kernel(const int* __restrict__ blocksums, int* __restrict__ blockbase,
                             int nb, int* __restrict__ total_out) {
  int lane = threadIdx.x;
  __shared__ int running_s;
  if (lane == 0) running_s = 0;
  __syncthreads();
  for (int base = 0; base < nb; base += 64) {
    int i = base + lane;
    int v = (i < nb) ? blocksums[i] : 0;
    int x = v;
#pragma unroll
    for (int d = 1; d < 64; d <<= 1) {
      int y = __shfl_up(x, d);
      if (lane >= d) x += y;
    }
    int running = running_s;
    if (i < nb) blockbase[i] = running + x - v;
    __syncthreads();
    if (lane == 63) running_s = running + x;
    __syncthreads();
  }
  if (lane == 0) *total_out = running_s;
}

__global__ void scan3_kernel(int* __restrict__ excl, const int* __restrict__ blockbase,
                             int* __restrict__ cursor, int n) {
  int i = blockIdx.x * 256 + threadIdx.x;
  if (i < n) {
    int v = excl[i] + blockbase[i >> 10];
    excl[i] = v;
    cursor[i] = v;
  }
}

__global__ void scatter_kernel(const int* __restrict__ ei, int E, int N,
                               int* __restrict__ cursor, int* __restrict__ srcs) {
  int e = blockIdx.x * 256 + threadIdx.x;
  int E2 = E + N;
  if (e >= E2) return;
  int s, d;
  if (e < E) { s = ei[e]; d = ei[E + e]; }
  else       { s = e - E; d = e - E; }
  int pos = atomicAdd(&cursor[d], 1);
  srcs[pos] = s;
}

// ---- W -> transposed fp16 Bt[col][K] with 6 extra al-columns ----
// col<192: Bt[col*K+k] = W[k*192+col]
// col=192+h (h<3):  wsrc_h[k] = sum_d W[k][h*64+d]*asrc[h*64+d]
// col=195+h (h<3):  wdst_h[k]
__global__ void convw_kernel(const float* __restrict__ W, const float* __restrict__ asrc,
                             const float* __restrict__ adst, _Float16* __restrict__ Bt,
                             int K) {
  int i = blockIdx.x * 256 + threadIdx.x;
  int nT = 192 * K;
  if (i < nT) {
    int col = i / K, k = i - col * K;
    Bt[i] = (_Float16)W[(size_t)k * HOUT + col];
    return;
  }
  int j = i - nT;
  if (j >= 6 * K) return;
  int which = j / K, k = j - which * K;
  const float* a = (which < 3) ? asrc : adst;
  int h = (which < 3) ? which : which - 3;
  float s = 0.f;
#pragma unroll 8
  for (int d = 0; d < 64; ++d)
    s += W[(size_t)k * HOUT + h * 64 + d] * a[h * 64 + d];
  Bt[(size_t)(192 + which) * K + k] = (_Float16)s;
}

// ---------------- fp16 MFMA GEMM (BK=64, swizzled LDS, al via MFMA) ----------------
// C[M,192] = A[M,K] @ Bt^T. Extra col-block 12 computes als (lg 0..2) / ald (lg 3..5).
#define GBM 64
#define GBK 64

template <typename T>
__global__ __launch_bounds__(256) void gemm_mfma_kernel(
    const T* __restrict__ A, const _Float16* __restrict__ Bt,
    _Float16* __restrict__ Ch, float* __restrict__ als, float* __restrict__ ald,
    int M, int K) {
  __shared__ _Float16 As[GBM][GBK];     // 8 KB, row=128B, chunk-XOR swizzled
  __shared__ _Float16 Bs[BCOLS][GBK];   // 26 KB, same swizzle
  int tid = threadIdx.x;
  int bm = blockIdx.x * GBM;
  int w  = tid >> 6;
  int l  = tid & 63;
  int lg = l & 15;
  int lh = l >> 4;

  floatx4 acc[13];
#pragma unroll
  for (int cb = 0; cb < 13; ++cb) acc[cb] = (floatx4){0.f, 0.f, 0.f, 0.f};

  for (int kt = 0; kt < K; kt += GBK) {
    // stage A: 64 rows x 64 k -> fp16, 16 elems (2 chunks) per thread
    {
      int ar = tid >> 2;
      int c0 = (tid & 3) * 2;
      int swz = ar & 7;
      int gm = bm + ar;
      half8 h8a = {}, h8b = {};
      if (gm < M) {
        if constexpr (sizeof(T) == 4) {
          const float* src = (const float*)&A[(size_t)gm * K + kt + c0 * 8];
          float4 f0 = *(const float4*)&src[0];
          float4 f1 = *(const float4*)&src[4];
          float4 f2 = *(const float4*)&src[8];
          float4 f3 = *(const float4*)&src[12];
          h8a[0] = (_Float16)f0.x; h8a[1] = (_Float16)f0.y;
          h8a[2] = (_Float16)f0.z; h8a[3] = (_Float16)f0.w;
          h8a[4] = (_Float16)f1.x; h8a[5] = (_Float16)f1.y;
          h8a[6] = (_Float16)f1.z; h8a[7] = (_Float16)f1.w;
          h8b[0] = (_Float16)f2.x; h8b[1] = (_Float16)f2.y;
          h8b[2] = (_Float16)f2.z; h8b[3] = (_Float16)f2.w;
          h8b[4] = (_Float16)f3.x; h8b[5] = (_Float16)f3.y;
          h8b[6] = (_Float16)f3.z; h8b[7] = (_Float16)f3.w;
        } else {
          const T* src = &A[(size_t)gm * K + kt + c0 * 8];
          h8a = *(const half8*)&src[0];
          h8b = *(const half8*)&src[8];
        }
      }
      *(half8*)&As[ar][(c0 ^ swz) * 8]       = h8a;
      *(half8*)&As[ar][((c0 + 1) ^ swz) * 8] = h8b;
    }
    // stage B: 208 rows x 64 k fp16 = 1664 chunks, 6.5/thread
#pragma unroll
    for (int i = 0; i < 7; ++i) {
      int f = tid + 256 * i;
      if (f < BCOLS * 8) {
        int row = f >> 3, c = f & 7;
        *(half8*)&Bs[row][(c ^ (row & 7)) * 8] =
            *(const half8*)&Bt[(size_t)row * K + kt + c * 8];
      }
    }
    __syncthreads();

    int rowa = w * 16 + lg;
    int swa = rowa & 7;
    half8 a0 = *(const half8*)&As[rowa][(lh ^ swa) * 8];
    half8 a1 = *(const half8*)&As[rowa][((4 + lh) ^ swa) * 8];
#pragma unroll
    for (int cb = 0; cb < 13; ++cb) {
      int rowb = cb * 16 + lg;
      int swb = rowb & 7;
      half8 b0 = *(const half8*)&Bs[rowb][(lh ^ swb) * 8];
      half8 b1 = *(const half8*)&Bs[rowb][((4 + lh) ^ swb) * 8];
      acc[cb] = __builtin_amdgcn_mfma_f32_16x16x32_f16(a0, b0, acc[cb], 0, 0, 0);
      acc[cb] = __builtin_amdgcn_mfma_f32_16x16x32_f16(a1, b1, acc[cb], 0, 0, 0);
    }
    __syncthreads();
  }

  // epilogue: lane holds C[row = bm+w*16+lh*4+r][col = cb*16+lg]
#pragma unroll
  for (int r = 0; r < 4; ++r) {
    int node = bm + w * 16 + lh * 4 + r;
    if (node < M) {
      _Float16* hr = &Ch[(size_t)node * HOUT];
#pragma unroll
      for (int cb = 0; cb < 12; ++cb) hr[cb * 16 + lg] = (_Float16)acc[cb][r];
      float alv = acc[12][r];
      if (lg < 3)      als[node * 4 + lg] = alv;
      else if (lg < 6) ald[node * 4 + (lg - 3)] = alv;
    }
  }
}

// ---------------- per-dst aggregation: fused softmax-weights, unroll 8 ----------------
__global__ void agg_kernel(const __half* __restrict__ hh, const float* __restrict__ als,
                           const float* __restrict__ ald, const int* __restrict__ offsets,
                           const int* __restrict__ srcs, const float* __restrict__ bias,
                           float* __restrict__ out_f, _Float16* __restrict__ out_h,
                           int n_nodes) {
  int wv = (blockIdx.x * blockDim.x + threadIdx.x) >> 6;
  int lane = threadIdx.x & 63;
  int node = __builtin_amdgcn_readfirstlane(wv);   // wave-uniform -> SMEM paths
  if (node >= n_nodes) return;
  int beg = offsets[node], end = offsets[node + 1];
  float4 ad = *(const float4*)&ald[node * 4];
  float sA0 = 0.f, sA1 = 0.f, sA2 = 0.f, aA0 = 0.f, aA1 = 0.f, aA2 = 0.f;
  float sB0 = 0.f, sB1 = 0.f, sB2 = 0.f, aB0 = 0.f, aB1 = 0.f, aB2 = 0.f;
  int p = beg;
  for (; p + 7 < end; p += 8) {
    int sx[8];
#pragma unroll
    for (int j = 0; j < 8; ++j) sx[j] = srcs[p + j];
    float v[8][3];
#pragma unroll
    for (int j = 0; j < 8; ++j) {
      const __half* h = hh + (size_t)sx[j] * HOUT;
      v[j][0] = __half2float(h[lane]);
      v[j][1] = __half2float(h[64 + lane]);
      v[j][2] = __half2float(h[128 + lane]);
    }
    float wt[8][3];
#pragma unroll
    for (int j = 0; j < 8; ++j) {
      float4 as4 = *(const float4*)&als[sx[j] * 4];
      float l0 = as4.x + ad.x;
      float l1 = as4.y + ad.y;
      float l2 = as4.z + ad.z;
      l0 = (l0 > 0.f) ? l0 : NEG_SLOPE * l0;
      l1 = (l1 > 0.f) ? l1 : NEG_SLOPE * l1;
      l2 = (l2 > 0.f) ? l2 : NEG_SLOPE * l2;
      wt[j][0] = __expf(l0);
      wt[j][1] = __expf(l1);
      wt[j][2] = __expf(l2);
    }
#pragma unroll
    for (int j = 0; j < 8; j += 2) {
      sA0 += wt[j][0]; aA0 += wt[j][0] * v[j][0];
      sA1 += wt[j][1]; aA1 += wt[j][1] * v[j][1];
      sA2 += wt[j][2]; aA2 += wt[j][2] * v[j][2];
      sB0 += wt[j + 1][0]; aB0 += wt[j + 1][0] * v[j + 1][0];
      sB1 += wt[j + 1][1]; aB1 += wt[j + 1][1] * v[j + 1][1];
      sB2 += wt[j + 1][2]; aB2 += wt[j + 1][2] * v[j + 1][2];
    }
  }
  for (; p < end; ++p) {
    int s = srcs[p];
    const __half* h = hh + (size_t)s * HOUT;
    float4 as4 = *(const float4*)&als[s * 4];
    float l0 = as4.x + ad.x;
    float l1 = as4.y + ad.y;
    float l2 = as4.z + ad.z;
    l0 = (l0 > 0.f) ? l0 : NEG_SLOPE * l0;
    l1 = (l1 > 0.f) ? l1 : NEG_SLOPE * l1;
    l2 = (l2 > 0.f) ? l2 : NEG_SLOPE * l2;
    float w0 = __expf(l0), w1 = __expf(l1), w2 = __expf(l2);
    sA0 += w0; aA0 += w0 * __half2float(h[lane]);
    sA1 += w1; aA1 += w1 * __half2float(h[64 + lane]);
    sA2 += w2; aA2 += w2 * __half2float(h[128 + lane]);
  }
  float s0 = sA0 + sB0, s1 = sA1 + sB1, s2 = sA2 + sB2;
  float a0 = aA0 + aB0, a1 = aA1 + aB1, a2 = aA2 + aB2;
  float r0 = 1.f / (s0 + 1e-16f);
  float r1 = 1.f / (s1 + 1e-16f);
  float r2 = 1.f / (s2 + 1e-16f);
  float v0 = fmaxf(a0 * r0 + bias[lane], 0.f);
  float v1 = fmaxf(a1 * r1 + bias[64 + lane], 0.f);
  float v2 = fmaxf(a2 * r2 + bias[128 + lane], 0.f);
  if (out_f) {
    float* o = out_f + (size_t)node * HOUT;
    o[lane] = v0; o[64 + lane] = v1; o[128 + lane] = v2;
  }
  if (out_h) {
    _Float16* o = out_h + (size_t)node * HOUT;
    o[lane] = (_Float16)v0; o[64 + lane] = (_Float16)v1; o[128 + lane] = (_Float16)v2;
  }
}

// ---------------- mean pool over sorted batch + relu ----------------
__global__ void pool_kernel(const float* __restrict__ h, const int* __restrict__ batch,
                            float* __restrict__ out, int n_nodes) {
  __shared__ int sbe[2];
  int g = blockIdx.x;
  if (threadIdx.x < 2) {
    int key = g + (int)threadIdx.x;
    int lo = 0, hi = n_nodes;
    while (lo < hi) {
      int mid = (lo + hi) >> 1;
      if (batch[mid] < key) lo = mid + 1; else hi = mid;
    }
    sbe[threadIdx.x] = lo;
  }
  __syncthreads();
  int beg = sbe[0], end = sbe[1];
  int t = threadIdx.x;
  float sum = 0.f;
  int i = beg;
  for (; i + 7 < end; i += 8) {
    float x0 = h[(size_t)(i + 0) * HOUT + t];
    float x1 = h[(size_t)(i + 1) * HOUT + t];
    float x2 = h[(size_t)(i + 2) * HOUT + t];
    float x3 = h[(size_t)(i + 3) * HOUT + t];
    float x4 = h[(size_t)(i + 4) * HOUT + t];
    float x5 = h[(size_t)(i + 5) * HOUT + t];
    float x6 = h[(size_t)(i + 6) * HOUT + t];
    float x7 = h[(size_t)(i + 7) * HOUT + t];
    sum += ((x0 + x1) + (x2 + x3)) + ((x4 + x5) + (x6 + x7));
  }
  for (; i < end; ++i) sum += h[(size_t)i * HOUT + t];
  float cnt = (float)(end - beg);
  float v = (cnt > 0.f) ? sum / cnt : 0.f;
  out[(size_t)g * HOUT + t] = fmaxf(v, 0.f);
}

// ---------------- launcher ----------------

extern "C" void kernel_launch(void* const* d_in, const int* in_sizes, int n_in,
                              void* d_out, int out_size, void* d_ws, size_t ws_size,
                              hipStream_t stream) {
  const float* x   = (const float*)d_in[0];
  const int*   ei  = (const int*)d_in[1];
  const int*   bat = (const int*)d_in[2];
  const float* W1  = (const float*)d_in[3];
  const float* a1s = (const float*)d_in[4];
  const float* a1d = (const float*)d_in[5];
  const float* b1  = (const float*)d_in[6];
  const float* W2  = (const float*)d_in[7];
  const float* a2s = (const float*)d_in[8];
  const float* a2d = (const float*)d_in[9];
  const float* b2  = (const float*)d_in[10];
  float* out = (float*)d_out;

  int N   = in_sizes[2];
  int Fin = in_sizes[0] / N;
  int E   = in_sizes[1] / 2;
  int E2  = E + N;
  int G   = out_size / HOUT;

  char* p = (char*)d_ws;
  auto carve = [&](size_t bytes) -> char* {
    char* r = p;
    p += (bytes + 255) & ~(size_t)255;
    return r;
  };
  int*      counts    = (int*)carve((size_t)N * 4);
  int*      offsets   = (int*)carve((size_t)(N + 1) * 4);
  int*      cursor    = (int*)carve((size_t)N * 4);
  int*      blocksums = (int*)carve(256 * 4);
  int*      blockbase = (int*)carve(256 * 4);
  int*      srcs      = (int*)carve((size_t)E2 * 4);
  float*    als       = (float*)carve((size_t)N * 4 * 4);
  float*    ald       = (float*)carve((size_t)N * 4 * 4);
  float*    bufB      = (float*)carve((size_t)N * HOUT * 4);
  _Float16* hh        = (_Float16*)carve((size_t)N * HOUT * 2);
  _Float16* hh2       = (_Float16*)carve((size_t)N * HOUT * 2);
  _Float16* W1t       = (_Float16*)carve((size_t)BCOLS * Fin * 2);
  _Float16* W2t       = (_Float16*)carve((size_t)BCOLS * HOUT * 2);
  (void)ws_size;

  // --- CSR build + weight conversion ---
  hipMemsetAsync(counts, 0, (size_t)N * 4, stream);
  hist_kernel<<<(E2 + 255) / 256, 256, 0, stream>>>(ei, E, N, counts);
  int nb = (N + 1023) / 1024;
  scan1_kernel<<<nb, 256, 0, stream>>>(counts, offsets, blocksums, N);
  scan2_kernel<<<1, 64, 0, stream>>>(blocksums, blockbase, nb, offsets + N);
  scan3_kernel<<<(N + 255) / 256, 256, 0, stream>>>(offsets, blockbase, cursor, N);
  scatter_kernel<<<(E2 + 255) / 256, 256, 0, stream>>>(ei, E, N, cursor, srcs);
  convw_kernel<<<(198 * Fin + 255) / 256, 256, 0, stream>>>(W1, a1s, a1d, W1t, Fin);
  convw_kernel<<<(198 * HOUT + 255) / 256, 256, 0, stream>>>(W2, a2s, a2d, W2t, HOUT);

  int wave_blocks = (N * 64 + 255) / 256;
  int gemm_blocks = (N + GBM - 1) / GBM;

  // --- layer 1 ---
  gemm_mfma_kernel<float><<<gemm_blocks, 256, 0, stream>>>(x, W1t, hh, als, ald, N, Fin);
  agg_kernel<<<wave_blocks, 256, 0, stream>>>((const __half*)hh, als, ald, offsets, srcs,
                                              b1, nullptr, hh2, N);

  // --- layer 2 ---
  gemm_mfma_kernel<_Float16><<<gemm_blocks, 256, 0, stream>>>(hh2, W2t, hh, als, ald, N, HOUT);
  agg_kernel<<<wave_blocks, 256, 0, stream>>>((const __half*)hh, als, ald, offsets, srcs,
                                              b2, bufB, nullptr, N);

  // --- pool ---
  pool_kernel<<<G, HOUT, 0, stream>>>(bufB, bat, out, N);
}

// Round 11
// 337.447 us; speedup vs baseline: 1.9193x; 1.0851x over previous
//
#include <hip/hip_runtime.h>
#include <hip/hip_fp16.h>
#include <math.h>

#define HOUT 192
#define NEG_SLOPE 0.2f
#define BCOLS 208   // 192 h-cols + 3 wsrc + 3 wdst + 10 pad (unused)

typedef _Float16 half8 __attribute__((ext_vector_type(8)));
typedef float floatx4 __attribute__((ext_vector_type(4)));

// ---------------- CSR build ----------------

__global__ void hist_kernel(const int* __restrict__ ei, int E, int N,
                            int* __restrict__ counts) {
  int e = blockIdx.x * 256 + threadIdx.x;
  int E2 = E + N;
  if (e >= E2) return;
  int d = (e < E) ? ei[E + e] : (e - E);
  atomicAdd(&counts[d], 1);
}

__global__ void scan1_kernel(const int* __restrict__ counts, int* __restrict__ excl,
                             int* __restrict__ blocksums, int n) {
  int t = threadIdx.x;
  int base = blockIdx.x * 1024 + t * 4;
  int v[4];
  int s = 0;
#pragma unroll
  for (int j = 0; j < 4; ++j) {
    int i = base + j;
    v[j] = (i < n) ? counts[i] : 0;
    s += v[j];
  }
  int lane = t & 63, wid = t >> 6;
  int x = s;
#pragma unroll
  for (int d = 1; d < 64; d <<= 1) {
    int y = __shfl_up(x, d);
    if (lane >= d) x += y;
  }
  __shared__ int wsum[4];
  if (lane == 63) wsum[wid] = x;
  __syncthreads();
  int wbase = 0;
  for (int w = 0; w < wid; ++w) wbase += wsum[w];
  int run = wbase + x - s;
#pragma unroll
  for (int j = 0; j < 4; ++j) {
    int i = base + j;
    if (i < n) excl[i] = run;
    run += v[j];
  }
  if (t == 255) blocksums[blockIdx.x] = wbase + x;
}

__global__ void scan2_kernel(const int* __restrict__ blocksums, int* __restrict__ blockbase,
                             int nb, int* __restrict__ total_out) {
  int lane = threadIdx.x;
  __shared__ int running_s;
  if (lane == 0) running_s = 0;
  __syncthreads();
  for (int base = 0; base < nb; base += 64) {
    int i = base + lane;
    int v = (i < nb) ? blocksums[i] : 0;
    int x = v;
#pragma unroll
    for (int d = 1; d < 64; d <<= 1) {
      int y = __shfl_up(x, d);
      if (lane >= d) x += y;
    }
    int running = running_s;
    if (i < nb) blockbase[i] = running + x - v;
    __syncthreads();
    if (lane == 63) running_s = running + x;
    __syncthreads();
  }
  if (lane == 0) *total_out = running_s;
}

__global__ void scan3_kernel(int* __restrict__ excl, const int* __restrict__ blockbase,
                             int* __restrict__ cursor, int n) {
  int i = blockIdx.x * 256 + threadIdx.x;
  if (i < n) {
    int v = excl[i] + blockbase[i >> 10];
    excl[i] = v;
    cursor[i] = v;
  }
}

__global__ void scatter_kernel(const int* __restrict__ ei, int E, int N,
                               int* __restrict__ cursor, int* __restrict__ srcs) {
  int e = blockIdx.x * 256 + threadIdx.x;
  int E2 = E + N;
  if (e >= E2) return;
  int s, d;
  if (e < E) { s = ei[e]; d = ei[E + e]; }
  else       { s = e - E; d = e - E; }
  int pos = atomicAdd(&cursor[d], 1);
  srcs[pos] = s;
}

// ---- W -> transposed fp16 Bt[col][K] with 6 extra al-columns ----
__global__ void convw_kernel(const float* __restrict__ W, const float* __restrict__ asrc,
                             const float* __restrict__ adst, _Float16* __restrict__ Bt,
                             int K) {
  int i = blockIdx.x * 256 + threadIdx.x;
  int nT = 192 * K;
  if (i < nT) {
    int col = i / K, k = i - col * K;
    Bt[i] = (_Float16)W[(size_t)k * HOUT + col];
    return;
  }
  int j = i - nT;
  if (j >= 6 * K) return;
  int which = j / K, k = j - which * K;
  const float* a = (which < 3) ? asrc : adst;
  int h = (which < 3) ? which : which - 3;
  float s = 0.f;
#pragma unroll 8
  for (int d = 0; d < 64; ++d)
    s += W[(size_t)k * HOUT + h * 64 + d] * a[h * 64 + d];
  Bt[(size_t)(192 + which) * K + k] = (_Float16)s;
}

// ---------------- fp16 MFMA GEMM (BK=64, swizzled LDS, al via MFMA) ----------------
#define GBM 64
#define GBK 64

template <typename T>
__global__ __launch_bounds__(256) void gemm_mfma_kernel(
    const T* __restrict__ A, const _Float16* __restrict__ Bt,
    _Float16* __restrict__ Ch, float* __restrict__ als, float* __restrict__ ald,
    int M, int K) {
  __shared__ _Float16 As[GBM][GBK];
  __shared__ _Float16 Bs[BCOLS][GBK];
  int tid = threadIdx.x;
  int bm = blockIdx.x * GBM;
  int w  = tid >> 6;
  int l  = tid & 63;
  int lg = l & 15;
  int lh = l >> 4;

  floatx4 acc[13];
#pragma unroll
  for (int cb = 0; cb < 13; ++cb) acc[cb] = (floatx4){0.f, 0.f, 0.f, 0.f};

  for (int kt = 0; kt < K; kt += GBK) {
    {
      int ar = tid >> 2;
      int c0 = (tid & 3) * 2;
      int swz = ar & 7;
      int gm = bm + ar;
      half8 h8a = {}, h8b = {};
      if (gm < M) {
        if constexpr (sizeof(T) == 4) {
          const float* src = (const float*)&A[(size_t)gm * K + kt + c0 * 8];
          float4 f0 = *(const float4*)&src[0];
          float4 f1 = *(const float4*)&src[4];
          float4 f2 = *(const float4*)&src[8];
          float4 f3 = *(const float4*)&src[12];
          h8a[0] = (_Float16)f0.x; h8a[1] = (_Float16)f0.y;
          h8a[2] = (_Float16)f0.z; h8a[3] = (_Float16)f0.w;
          h8a[4] = (_Float16)f1.x; h8a[5] = (_Float16)f1.y;
          h8a[6] = (_Float16)f1.z; h8a[7] = (_Float16)f1.w;
          h8b[0] = (_Float16)f2.x; h8b[1] = (_Float16)f2.y;
          h8b[2] = (_Float16)f2.z; h8b[3] = (_Float16)f2.w;
          h8b[4] = (_Float16)f3.x; h8b[5] = (_Float16)f3.y;
          h8b[6] = (_Float16)f3.z; h8b[7] = (_Float16)f3.w;
        } else {
          const T* src = &A[(size_t)gm * K + kt + c0 * 8];
          h8a = *(const half8*)&src[0];
          h8b = *(const half8*)&src[8];
        }
      }
      *(half8*)&As[ar][(c0 ^ swz) * 8]       = h8a;
      *(half8*)&As[ar][((c0 + 1) ^ swz) * 8] = h8b;
    }
#pragma unroll
    for (int i = 0; i < 7; ++i) {
      int f = tid + 256 * i;
      if (f < BCOLS * 8) {
        int row = f >> 3, c = f & 7;
        *(half8*)&Bs[row][(c ^ (row & 7)) * 8] =
            *(const half8*)&Bt[(size_t)row * K + kt + c * 8];
      }
    }
    __syncthreads();

    int rowa = w * 16 + lg;
    int swa = rowa & 7;
    half8 a0 = *(const half8*)&As[rowa][(lh ^ swa) * 8];
    half8 a1 = *(const half8*)&As[rowa][((4 + lh) ^ swa) * 8];
#pragma unroll
    for (int cb = 0; cb < 13; ++cb) {
      int rowb = cb * 16 + lg;
      int swb = rowb & 7;
      half8 b0 = *(const half8*)&Bs[rowb][(lh ^ swb) * 8];
      half8 b1 = *(const half8*)&Bs[rowb][((4 + lh) ^ swb) * 8];
      acc[cb] = __builtin_amdgcn_mfma_f32_16x16x32_f16(a0, b0, acc[cb], 0, 0, 0);
      acc[cb] = __builtin_amdgcn_mfma_f32_16x16x32_f16(a1, b1, acc[cb], 0, 0, 0);
    }
    __syncthreads();
  }

#pragma unroll
  for (int r = 0; r < 4; ++r) {
    int node = bm + w * 16 + lh * 4 + r;
    if (node < M) {
      _Float16* hr = &Ch[(size_t)node * HOUT];
#pragma unroll
      for (int cb = 0; cb < 12; ++cb) hr[cb * 16 + lg] = (_Float16)acc[cb][r];
      float alv = acc[12][r];
      if (lg < 3)      als[node * 4 + lg] = alv;
      else if (lg < 6) ald[node * 4 + (lg - 3)] = alv;
    }
  }
}

// ---------------- per-dst aggregation ----------------
// 64-edge chunks: prologue computes softmax weights edge-parallel (lane=edge),
// stashes {w0,w1,w2,src} in per-wave LDS; gather loop broadcast-reads records.
__global__ void agg_kernel(const __half* __restrict__ hh, const float* __restrict__ als,
                           const float* __restrict__ ald, const int* __restrict__ offsets,
                           const int* __restrict__ srcs, const float* __restrict__ bias,
                           float* __restrict__ out_f, _Float16* __restrict__ out_h,
                           int n_nodes) {
  __shared__ float4 wls[4][64];
  int wv = (blockIdx.x * blockDim.x + threadIdx.x) >> 6;
  int wid = (threadIdx.x >> 6) & 3;
  int lane = threadIdx.x & 63;
  int node = __builtin_amdgcn_readfirstlane(wv);
  if (node >= n_nodes) return;
  int beg = offsets[node], end = offsets[node + 1];
  float4 ad = *(const float4*)&ald[node * 4];
  float sA0 = 0.f, sA1 = 0.f, sA2 = 0.f, aA0 = 0.f, aA1 = 0.f, aA2 = 0.f;
  float sB0 = 0.f, sB1 = 0.f, sB2 = 0.f, aB0 = 0.f, aB1 = 0.f, aB2 = 0.f;

  for (int cb = beg; cb < end; cb += 64) {
    int rem = end - cb;
    int cnt = rem < 64 ? rem : 64;
    // ---- prologue: lane j computes edge (cb+j)'s weights ----
    if (lane < cnt) {
      int s = srcs[cb + lane];
      float4 as4 = *(const float4*)&als[s * 4];
      float l0 = as4.x + ad.x;
      float l1 = as4.y + ad.y;
      float l2 = as4.z + ad.z;
      l0 = (l0 > 0.f) ? l0 : NEG_SLOPE * l0;
      l1 = (l1 > 0.f) ? l1 : NEG_SLOPE * l1;
      l2 = (l2 > 0.f) ? l2 : NEG_SLOPE * l2;
      float4 rec;
      rec.x = __expf(l0);
      rec.y = __expf(l1);
      rec.z = __expf(l2);
      rec.w = __int_as_float(s);
      wls[wid][lane] = rec;
    }
    // same wave wrote, same wave reads: fence LDS writes, no block barrier
    asm volatile("s_waitcnt lgkmcnt(0)" ::: "memory");
    // ---- gather loop: broadcast-read edge records ----
    int j = 0;
    for (; j + 3 < cnt; j += 4) {
      float4 rA = wls[wid][j];
      float4 rB = wls[wid][j + 1];
      float4 rC = wls[wid][j + 2];
      float4 rD = wls[wid][j + 3];
      const __half* ha = hh + (size_t)__float_as_int(rA.w) * HOUT + lane;
      const __half* hb = hh + (size_t)__float_as_int(rB.w) * HOUT + lane;
      const __half* hc = hh + (size_t)__float_as_int(rC.w) * HOUT + lane;
      const __half* hd = hh + (size_t)__float_as_int(rD.w) * HOUT + lane;
      float va0 = __half2float(ha[0]);
      float va1 = __half2float(ha[64]);
      float va2 = __half2float(ha[128]);
      float vb0 = __half2float(hb[0]);
      float vb1 = __half2float(hb[64]);
      float vb2 = __half2float(hb[128]);
      float vc0 = __half2float(hc[0]);
      float vc1 = __half2float(hc[64]);
      float vc2 = __half2float(hc[128]);
      float vd0 = __half2float(hd[0]);
      float vd1 = __half2float(hd[64]);
      float vd2 = __half2float(hd[128]);
      sA0 += rA.x + rC.x; sA1 += rA.y + rC.y; sA2 += rA.z + rC.z;
      sB0 += rB.x + rD.x; sB1 += rB.y + rD.y; sB2 += rB.z + rD.z;
      aA0 += rA.x * va0 + rC.x * vc0;
      aA1 += rA.y * va1 + rC.y * vc1;
      aA2 += rA.z * va2 + rC.z * vc2;
      aB0 += rB.x * vb0 + rD.x * vd0;
      aB1 += rB.y * vb1 + rD.y * vd1;
      aB2 += rB.z * vb2 + rD.z * vd2;
    }
    for (; j < cnt; ++j) {
      float4 rA = wls[wid][j];
      const __half* ha = hh + (size_t)__float_as_int(rA.w) * HOUT + lane;
      float va0 = __half2float(ha[0]);
      float va1 = __half2float(ha[64]);
      float va2 = __half2float(ha[128]);
      sA0 += rA.x; aA0 += rA.x * va0;
      sA1 += rA.y; aA1 += rA.y * va1;
      sA2 += rA.z; aA2 += rA.z * va2;
    }
  }
  float s0 = sA0 + sB0, s1 = sA1 + sB1, s2 = sA2 + sB2;
  float a0 = aA0 + aB0, a1 = aA1 + aB1, a2 = aA2 + aB2;
  float r0 = 1.f / (s0 + 1e-16f);
  float r1 = 1.f / (s1 + 1e-16f);
  float r2 = 1.f / (s2 + 1e-16f);
  float v0 = fmaxf(a0 * r0 + bias[lane], 0.f);
  float v1 = fmaxf(a1 * r1 + bias[64 + lane], 0.f);
  float v2 = fmaxf(a2 * r2 + bias[128 + lane], 0.f);
  if (out_f) {
    float* o = out_f + (size_t)node * HOUT;
    o[lane] = v0; o[64 + lane] = v1; o[128 + lane] = v2;
  }
  if (out_h) {
    _Float16* o = out_h + (size_t)node * HOUT;
    o[lane] = (_Float16)v0; o[64 + lane] = (_Float16)v1; o[128 + lane] = (_Float16)v2;
  }
}

// ---------------- mean pool over sorted batch + relu ----------------
__global__ void pool_kernel(const float* __restrict__ h, const int* __restrict__ batch,
                            float* __restrict__ out, int n_nodes) {
  __shared__ int sbe[2];
  int g = blockIdx.x;
  if (threadIdx.x < 2) {
    int key = g + (int)threadIdx.x;
    int lo = 0, hi = n_nodes;
    while (lo < hi) {
      int mid = (lo + hi) >> 1;
      if (batch[mid] < key) lo = mid + 1; else hi = mid;
    }
    sbe[threadIdx.x] = lo;
  }
  __syncthreads();
  int beg = sbe[0], end = sbe[1];
  int t = threadIdx.x;
  float sum = 0.f;
  int i = beg;
  for (; i + 7 < end; i += 8) {
    float x0 = h[(size_t)(i + 0) * HOUT + t];
    float x1 = h[(size_t)(i + 1) * HOUT + t];
    float x2 = h[(size_t)(i + 2) * HOUT + t];
    float x3 = h[(size_t)(i + 3) * HOUT + t];
    float x4 = h[(size_t)(i + 4) * HOUT + t];
    float x5 = h[(size_t)(i + 5) * HOUT + t];
    float x6 = h[(size_t)(i + 6) * HOUT + t];
    float x7 = h[(size_t)(i + 7) * HOUT + t];
    sum += ((x0 + x1) + (x2 + x3)) + ((x4 + x5) + (x6 + x7));
  }
  for (; i < end; ++i) sum += h[(size_t)i * HOUT + t];
  float cnt = (float)(end - beg);
  float v = (cnt > 0.f) ? sum / cnt : 0.f;
  out[(size_t)g * HOUT + t] = fmaxf(v, 0.f);
}

// ---------------- launcher ----------------

extern "C" void kernel_launch(void* const* d_in, const int* in_sizes, int n_in,
                              void* d_out, int out_size, void* d_ws, size_t ws_size,
                              hipStream_t stream) {
  const float* x   = (const float*)d_in[0];
  const int*   ei  = (const int*)d_in[1];
  const int*   bat = (const int*)d_in[2];
  const float* W1  = (const float*)d_in[3];
  const float* a1s = (const float*)d_in[4];
  const float* a1d = (const float*)d_in[5];
  const float* b1  = (const float*)d_in[6];
  const float* W2  = (const float*)d_in[7];
  const float* a2s = (const float*)d_in[8];
  const float* a2d = (const float*)d_in[9];
  const float* b2  = (const float*)d_in[10];
  float* out = (float*)d_out;

  int N   = in_sizes[2];
  int Fin = in_sizes[0] / N;
  int E   = in_sizes[1] / 2;
  int E2  = E + N;
  int G   = out_size / HOUT;

  char* p = (char*)d_ws;
  auto carve = [&](size_t bytes) -> char* {
    char* r = p;
    p += (bytes + 255) & ~(size_t)255;
    return r;
  };
  int*      counts    = (int*)carve((size_t)N * 4);
  int*      offsets   = (int*)carve((size_t)(N + 1) * 4);
  int*      cursor    = (int*)carve((size_t)N * 4);
  int*      blocksums = (int*)carve(256 * 4);
  int*      blockbase = (int*)carve(256 * 4);
  int*      srcs      = (int*)carve((size_t)E2 * 4);
  float*    als       = (float*)carve((size_t)N * 4 * 4);
  float*    ald       = (float*)carve((size_t)N * 4 * 4);
  float*    bufB      = (float*)carve((size_t)N * HOUT * 4);
  _Float16* hh        = (_Float16*)carve((size_t)N * HOUT * 2);
  _Float16* hh2       = (_Float16*)carve((size_t)N * HOUT * 2);
  _Float16* W1t       = (_Float16*)carve((size_t)BCOLS * Fin * 2);
  _Float16* W2t       = (_Float16*)carve((size_t)BCOLS * HOUT * 2);
  (void)ws_size;

  // --- CSR build + weight conversion ---
  hipMemsetAsync(counts, 0, (size_t)N * 4, stream);
  hist_kernel<<<(E2 + 255) / 256, 256, 0, stream>>>(ei, E, N, counts);
  int nb = (N + 1023) / 1024;
  scan1_kernel<<<nb, 256, 0, stream>>>(counts, offsets, blocksums, N);
  scan2_kernel<<<1, 64, 0, stream>>>(blocksums, blockbase, nb, offsets + N);
  scan3_kernel<<<(N + 255) / 256, 256, 0, stream>>>(offsets, blockbase, cursor, N);
  scatter_kernel<<<(E2 + 255) / 256, 256, 0, stream>>>(ei, E, N, cursor, srcs);
  convw_kernel<<<(198 * Fin + 255) / 256, 256, 0, stream>>>(W1, a1s, a1d, W1t, Fin);
  convw_kernel<<<(198 * HOUT + 255) / 256, 256, 0, stream>>>(W2, a2s, a2d, W2t, HOUT);

  int wave_blocks = (N * 64 + 255) / 256;
  int gemm_blocks = (N + GBM - 1) / GBM;

  // --- layer 1 ---
  gemm_mfma_kernel<float><<<gemm_blocks, 256, 0, stream>>>(x, W1t, hh, als, ald, N, Fin);
  agg_kernel<<<wave_blocks, 256, 0, stream>>>((const __half*)hh, als, ald, offsets, srcs,
                                              b1, nullptr, hh2, N);

  // --- layer 2 ---
  gemm_mfma_kernel<_Float16><<<gemm_blocks, 256, 0, stream>>>(hh2, W2t, hh, als, ald, N, HOUT);
  agg_kernel<<<wave_blocks, 256, 0, stream>>>((const __half*)hh, als, ald, offsets, srcs,
                                              b2, bufB, nullptr, N);

  // --- pool ---
  pool_kernel<<<G, HOUT, 0, stream>>>(bufB, bat, out, N);
}

// Round 12
// 334.507 us; speedup vs baseline: 1.9362x; 1.0088x over previous
//
#include <hip/hip_runtime.h>
#include <hip/hip_fp16.h>
#include <math.h>

#define HOUT 192
#define NEG_SLOPE 0.2f
#define BCOLS 208   // 192 h-cols + 3 wsrc + 3 wdst + 10 pad (unused)

// CSR bucket-sort params (requires N < 2^20)
#define BSHIFT 7
#define BNODES 128
#define NXCD 8
#define CAP 2816

typedef _Float16 half8 __attribute__((ext_vector_type(8)));
typedef float floatx4 __attribute__((ext_vector_type(4)));

// ---------------- CSR build: XCD-private bucket sort ----------------

// Phase A: append packed (local_d<<20 | src) to per-(XCD,bucket) region.
__global__ void bucketA_kernel(const int* __restrict__ ei, int E, int N, int NB,
                               int* __restrict__ bcnt, unsigned* __restrict__ ibuf) {
  int e = blockIdx.x * 256 + threadIdx.x;
  int E2 = E + N;
  if (e >= E2) return;
  int s, d;
  if (e < E) { s = ei[e]; d = ei[E + e]; }
  else       { s = e - E; d = e - E; }
  int b = d >> BSHIFT;
  int x;
  asm("s_getreg_b32 %0, hwreg(HW_REG_XCC_ID)" : "=s"(x));
  x &= (NXCD - 1);
  int slot = x * NB + b;
  int pos = atomicAdd(&bcnt[slot], 1);
  if (pos < CAP)
    ibuf[(size_t)slot * CAP + pos] = (unsigned)s | ((unsigned)(d & (BNODES - 1)) << 20);
}

// Bucket-total exclusive scan (one block, 256 threads, NB <= 512).
__global__ void bscan_kernel(const int* __restrict__ bcnt, int* __restrict__ bstart,
                             int NB, int E2, int* __restrict__ offsets, int N) {
  int t = threadIdx.x;
  int b0 = 2 * t, b1 = 2 * t + 1;
  int v0 = 0, v1 = 0;
  if (b0 < NB)
    for (int x = 0; x < NXCD; ++x) v0 += bcnt[x * NB + b0];
  if (b1 < NB)
    for (int x = 0; x < NXCD; ++x) v1 += bcnt[x * NB + b1];
  int s = v0 + v1;
  int lane = t & 63, wid = t >> 6;
  int xs = s;
#pragma unroll
  for (int d = 1; d < 64; d <<= 1) {
    int y = __shfl_up(xs, d);
    if (lane >= d) xs += y;
  }
  __shared__ int wsum[4];
  if (lane == 63) wsum[wid] = xs;
  __syncthreads();
  int wbase = 0;
  for (int w = 0; w < wid; ++w) wbase += wsum[w];
  int excl = wbase + xs - s;
  if (b0 < NB) bstart[b0] = excl;
  if (b1 < NB) bstart[b1] = excl + v0;
  if (t == 0) offsets[N] = E2;
}

// Phase B: per bucket: LDS histogram -> LDS scan -> write offsets + final srcs.
__global__ __launch_bounds__(256) void bucketB_kernel(
    const unsigned* __restrict__ ibuf, const int* __restrict__ bcnt,
    const int* __restrict__ bstart, int NB, int N,
    int* __restrict__ srcs, int* __restrict__ offsets) {
  __shared__ int lens[NXCD];
  __shared__ int cnt[BNODES];
  __shared__ int sa[BNODES], sb_[BNODES];
  __shared__ int cur[BNODES];
  int b = blockIdx.x;
  int t = threadIdx.x;
  if (t < NXCD) {
    int v = bcnt[t * NB + b];
    lens[t] = v < CAP ? v : CAP;
  }
  if (t < BNODES) cnt[t] = 0;
  __syncthreads();
  for (int x = 0; x < NXCD; ++x) {
    int len = lens[x];
    const unsigned* seg = ibuf + (size_t)(x * NB + b) * CAP;
    for (int i = t; i < len; i += 256) atomicAdd(&cnt[seg[i] >> 20], 1);
  }
  __syncthreads();
  if (t < BNODES) sa[t] = cnt[t];
  __syncthreads();
  int* pin = sa;
  int* pout = sb_;
  for (int off = 1; off < BNODES; off <<= 1) {
    if (t < BNODES) pout[t] = pin[t] + ((t >= off) ? pin[t - off] : 0);
    __syncthreads();
    int* tmp = pin; pin = pout; pout = tmp;
  }
  int bst = bstart[b];
  if (t < BNODES) {
    int ex = pin[t] - cnt[t];
    cur[t] = bst + ex;
    int d = b * BNODES + t;
    if (d < N) offsets[d] = bst + ex;
  }
  __syncthreads();
  for (int x = 0; x < NXCD; ++x) {
    int len = lens[x];
    const unsigned* seg = ibuf + (size_t)(x * NB + b) * CAP;
    for (int i = t; i < len; i += 256) {
      unsigned r = seg[i];
      int pos = atomicAdd(&cur[r >> 20], 1);
      srcs[pos] = (int)(r & 0xFFFFFu);
    }
  }
}

// ---- W -> transposed fp16 Bt[col][K] with 6 extra al-columns ----
__global__ void convw_kernel(const float* __restrict__ W, const float* __restrict__ asrc,
                             const float* __restrict__ adst, _Float16* __restrict__ Bt,
                             int K) {
  int i = blockIdx.x * 256 + threadIdx.x;
  int nT = 192 * K;
  if (i < nT) {
    int col = i / K, k = i - col * K;
    Bt[i] = (_Float16)W[(size_t)k * HOUT + col];
    return;
  }
  int j = i - nT;
  if (j >= 6 * K) return;
  int which = j / K, k = j - which * K;
  const float* a = (which < 3) ? asrc : adst;
  int h = (which < 3) ? which : which - 3;
  float s = 0.f;
#pragma unroll 8
  for (int d = 0; d < 64; ++d)
    s += W[(size_t)k * HOUT + h * 64 + d] * a[h * 64 + d];
  Bt[(size_t)(192 + which) * K + k] = (_Float16)s;
}

// ---------------- fp16 MFMA GEMM (BK=64, swizzled LDS, al via MFMA) ----------------
#define GBM 64
#define GBK 64

template <typename T>
__global__ __launch_bounds__(256) void gemm_mfma_kernel(
    const T* __restrict__ A, const _Float16* __restrict__ Bt,
    _Float16* __restrict__ Ch, float* __restrict__ als, float* __restrict__ ald,
    int M, int K) {
  __shared__ _Float16 As[GBM][GBK];
  __shared__ _Float16 Bs[BCOLS][GBK];
  int tid = threadIdx.x;
  int bm = blockIdx.x * GBM;
  int w  = tid >> 6;
  int l  = tid & 63;
  int lg = l & 15;
  int lh = l >> 4;

  floatx4 acc[13];
#pragma unroll
  for (int cb = 0; cb < 13; ++cb) acc[cb] = (floatx4){0.f, 0.f, 0.f, 0.f};

  for (int kt = 0; kt < K; kt += GBK) {
    {
      int ar = tid >> 2;
      int c0 = (tid & 3) * 2;
      int swz = ar & 7;
      int gm = bm + ar;
      half8 h8a = {}, h8b = {};
      if (gm < M) {
        if constexpr (sizeof(T) == 4) {
          const float* src = (const float*)&A[(size_t)gm * K + kt + c0 * 8];
          float4 f0 = *(const float4*)&src[0];
          float4 f1 = *(const float4*)&src[4];
          float4 f2 = *(const float4*)&src[8];
          float4 f3 = *(const float4*)&src[12];
          h8a[0] = (_Float16)f0.x; h8a[1] = (_Float16)f0.y;
          h8a[2] = (_Float16)f0.z; h8a[3] = (_Float16)f0.w;
          h8a[4] = (_Float16)f1.x; h8a[5] = (_Float16)f1.y;
          h8a[6] = (_Float16)f1.z; h8a[7] = (_Float16)f1.w;
          h8b[0] = (_Float16)f2.x; h8b[1] = (_Float16)f2.y;
          h8b[2] = (_Float16)f2.z; h8b[3] = (_Float16)f2.w;
          h8b[4] = (_Float16)f3.x; h8b[5] = (_Float16)f3.y;
          h8b[6] = (_Float16)f3.z; h8b[7] = (_Float16)f3.w;
        } else {
          const T* src = &A[(size_t)gm * K + kt + c0 * 8];
          h8a = *(const half8*)&src[0];
          h8b = *(const half8*)&src[8];
        }
      }
      *(half8*)&As[ar][(c0 ^ swz) * 8]       = h8a;
      *(half8*)&As[ar][((c0 + 1) ^ swz) * 8] = h8b;
    }
#pragma unroll
    for (int i = 0; i < 7; ++i) {
      int f = tid + 256 * i;
      if (f < BCOLS * 8) {
        int row = f >> 3, c = f & 7;
        *(half8*)&Bs[row][(c ^ (row & 7)) * 8] =
            *(const half8*)&Bt[(size_t)row * K + kt + c * 8];
      }
    }
    __syncthreads();

    int rowa = w * 16 + lg;
    int swa = rowa & 7;
    half8 a0 = *(const half8*)&As[rowa][(lh ^ swa) * 8];
    half8 a1 = *(const half8*)&As[rowa][((4 + lh) ^ swa) * 8];
#pragma unroll
    for (int cb = 0; cb < 13; ++cb) {
      int rowb = cb * 16 + lg;
      int swb = rowb & 7;
      half8 b0 = *(const half8*)&Bs[rowb][(lh ^ swb) * 8];
      half8 b1 = *(const half8*)&Bs[rowb][((4 + lh) ^ swb) * 8];
      acc[cb] = __builtin_amdgcn_mfma_f32_16x16x32_f16(a0, b0, acc[cb], 0, 0, 0);
      acc[cb] = __builtin_amdgcn_mfma_f32_16x16x32_f16(a1, b1, acc[cb], 0, 0, 0);
    }
    __syncthreads();
  }

#pragma unroll
  for (int r = 0; r < 4; ++r) {
    int node = bm + w * 16 + lh * 4 + r;
    if (node < M) {
      _Float16* hr = &Ch[(size_t)node * HOUT];
#pragma unroll
      for (int cb = 0; cb < 12; ++cb) hr[cb * 16 + lg] = (_Float16)acc[cb][r];
      float alv = acc[12][r];
      if (lg < 3)      als[node * 4 + lg] = alv;
      else if (lg < 6) ald[node * 4 + (lg - 3)] = alv;
    }
  }
}

// ---------------- per-dst aggregation ----------------
// 64-edge chunks: prologue computes softmax weights edge-parallel (lane=edge),
// stashes {w0,w1,w2,src} in per-wave LDS; gather loop broadcast-reads records.
__global__ void agg_kernel(const __half* __restrict__ hh, const float* __restrict__ als,
                           const float* __restrict__ ald, const int* __restrict__ offsets,
                           const int* __restrict__ srcs, const float* __restrict__ bias,
                           float* __restrict__ out_f, _Float16* __restrict__ out_h,
                           int n_nodes) {
  __shared__ float4 wls[4][64];
  int wv = (blockIdx.x * blockDim.x + threadIdx.x) >> 6;
  int wid = (threadIdx.x >> 6) & 3;
  int lane = threadIdx.x & 63;
  int node = __builtin_amdgcn_readfirstlane(wv);
  if (node >= n_nodes) return;
  int beg = offsets[node], end = offsets[node + 1];
  float4 ad = *(const float4*)&ald[node * 4];
  float sA0 = 0.f, sA1 = 0.f, sA2 = 0.f, aA0 = 0.f, aA1 = 0.f, aA2 = 0.f;
  float sB0 = 0.f, sB1 = 0.f, sB2 = 0.f, aB0 = 0.f, aB1 = 0.f, aB2 = 0.f;

  for (int cb = beg; cb < end; cb += 64) {
    int rem = end - cb;
    int cnt = rem < 64 ? rem : 64;
    if (lane < cnt) {
      int s = srcs[cb + lane];
      float4 as4 = *(const float4*)&als[s * 4];
      float l0 = as4.x + ad.x;
      float l1 = as4.y + ad.y;
      float l2 = as4.z + ad.z;
      l0 = (l0 > 0.f) ? l0 : NEG_SLOPE * l0;
      l1 = (l1 > 0.f) ? l1 : NEG_SLOPE * l1;
      l2 = (l2 > 0.f) ? l2 : NEG_SLOPE * l2;
      float4 rec;
      rec.x = __expf(l0);
      rec.y = __expf(l1);
      rec.z = __expf(l2);
      rec.w = __int_as_float(s);
      wls[wid][lane] = rec;
    }
    asm volatile("s_waitcnt lgkmcnt(0)" ::: "memory");
    int j = 0;
    for (; j + 3 < cnt; j += 4) {
      float4 rA = wls[wid][j];
      float4 rB = wls[wid][j + 1];
      float4 rC = wls[wid][j + 2];
      float4 rD = wls[wid][j + 3];
      const __half* ha = hh + (size_t)__float_as_int(rA.w) * HOUT + lane;
      const __half* hb = hh + (size_t)__float_as_int(rB.w) * HOUT + lane;
      const __half* hc = hh + (size_t)__float_as_int(rC.w) * HOUT + lane;
      const __half* hd = hh + (size_t)__float_as_int(rD.w) * HOUT + lane;
      float va0 = __half2float(ha[0]);
      float va1 = __half2float(ha[64]);
      float va2 = __half2float(ha[128]);
      float vb0 = __half2float(hb[0]);
      float vb1 = __half2float(hb[64]);
      float vb2 = __half2float(hb[128]);
      float vc0 = __half2float(hc[0]);
      float vc1 = __half2float(hc[64]);
      float vc2 = __half2float(hc[128]);
      float vd0 = __half2float(hd[0]);
      float vd1 = __half2float(hd[64]);
      float vd2 = __half2float(hd[128]);
      sA0 += rA.x + rC.x; sA1 += rA.y + rC.y; sA2 += rA.z + rC.z;
      sB0 += rB.x + rD.x; sB1 += rB.y + rD.y; sB2 += rB.z + rD.z;
      aA0 += rA.x * va0 + rC.x * vc0;
      aA1 += rA.y * va1 + rC.y * vc1;
      aA2 += rA.z * va2 + rC.z * vc2;
      aB0 += rB.x * vb0 + rD.x * vd0;
      aB1 += rB.y * vb1 + rD.y * vd1;
      aB2 += rB.z * vb2 + rD.z * vd2;
    }
    for (; j < cnt; ++j) {
      float4 rA = wls[wid][j];
      const __half* ha = hh + (size_t)__float_as_int(rA.w) * HOUT + lane;
      float va0 = __half2float(ha[0]);
      float va1 = __half2float(ha[64]);
      float va2 = __half2float(ha[128]);
      sA0 += rA.x; aA0 += rA.x * va0;
      sA1 += rA.y; aA1 += rA.y * va1;
      sA2 += rA.z; aA2 += rA.z * va2;
    }
  }
  float s0 = sA0 + sB0, s1 = sA1 + sB1, s2 = sA2 + sB2;
  float a0 = aA0 + aB0, a1 = aA1 + aB1, a2 = aA2 + aB2;
  float r0 = 1.f / (s0 + 1e-16f);
  float r1 = 1.f / (s1 + 1e-16f);
  float r2 = 1.f / (s2 + 1e-16f);
  float v0 = fmaxf(a0 * r0 + bias[lane], 0.f);
  float v1 = fmaxf(a1 * r1 + bias[64 + lane], 0.f);
  float v2 = fmaxf(a2 * r2 + bias[128 + lane], 0.f);
  if (out_f) {
    float* o = out_f + (size_t)node * HOUT;
    o[lane] = v0; o[64 + lane] = v1; o[128 + lane] = v2;
  }
  if (out_h) {
    _Float16* o = out_h + (size_t)node * HOUT;
    o[lane] = (_Float16)v0; o[64 + lane] = (_Float16)v1; o[128 + lane] = (_Float16)v2;
  }
}

// ---------------- mean pool over sorted batch + relu ----------------
__global__ void pool_kernel(const float* __restrict__ h, const int* __restrict__ batch,
                            float* __restrict__ out, int n_nodes) {
  __shared__ int sbe[2];
  int g = blockIdx.x;
  if (threadIdx.x < 2) {
    int key = g + (int)threadIdx.x;
    int lo = 0, hi = n_nodes;
    while (lo < hi) {
      int mid = (lo + hi) >> 1;
      if (batch[mid] < key) lo = mid + 1; else hi = mid;
    }
    sbe[threadIdx.x] = lo;
  }
  __syncthreads();
  int beg = sbe[0], end = sbe[1];
  int t = threadIdx.x;
  float sum = 0.f;
  int i = beg;
  for (; i + 7 < end; i += 8) {
    float x0 = h[(size_t)(i + 0) * HOUT + t];
    float x1 = h[(size_t)(i + 1) * HOUT + t];
    float x2 = h[(size_t)(i + 2) * HOUT + t];
    float x3 = h[(size_t)(i + 3) * HOUT + t];
    float x4 = h[(size_t)(i + 4) * HOUT + t];
    float x5 = h[(size_t)(i + 5) * HOUT + t];
    float x6 = h[(size_t)(i + 6) * HOUT + t];
    float x7 = h[(size_t)(i + 7) * HOUT + t];
    sum += ((x0 + x1) + (x2 + x3)) + ((x4 + x5) + (x6 + x7));
  }
  for (; i < end; ++i) sum += h[(size_t)i * HOUT + t];
  float cnt = (float)(end - beg);
  float v = (cnt > 0.f) ? sum / cnt : 0.f;
  out[(size_t)g * HOUT + t] = fmaxf(v, 0.f);
}

// ---------------- launcher ----------------

extern "C" void kernel_launch(void* const* d_in, const int* in_sizes, int n_in,
                              void* d_out, int out_size, void* d_ws, size_t ws_size,
                              hipStream_t stream) {
  const float* x   = (const float*)d_in[0];
  const int*   ei  = (const int*)d_in[1];
  const int*   bat = (const int*)d_in[2];
  const float* W1  = (const float*)d_in[3];
  const float* a1s = (const float*)d_in[4];
  const float* a1d = (const float*)d_in[5];
  const float* b1  = (const float*)d_in[6];
  const float* W2  = (const float*)d_in[7];
  const float* a2s = (const float*)d_in[8];
  const float* a2d = (const float*)d_in[9];
  const float* b2  = (const float*)d_in[10];
  float* out = (float*)d_out;

  int N   = in_sizes[2];
  int Fin = in_sizes[0] / N;
  int E   = in_sizes[1] / 2;
  int E2  = E + N;
  int G   = out_size / HOUT;
  int NB  = (N + BNODES - 1) / BNODES;

  char* p = (char*)d_ws;
  auto carve = [&](size_t bytes) -> char* {
    char* r = p;
    p += (bytes + 255) & ~(size_t)255;
    return r;
  };
  int*      offsets   = (int*)carve((size_t)(N + 1) * 4);
  int*      srcs      = (int*)carve((size_t)E2 * 4);
  int*      bcnt      = (int*)carve((size_t)NXCD * NB * 4);
  int*      bstart    = (int*)carve((size_t)NB * 4);
  float*    als       = (float*)carve((size_t)N * 4 * 4);
  float*    ald       = (float*)carve((size_t)N * 4 * 4);
  float*    bufB      = (float*)carve((size_t)N * HOUT * 4);
  _Float16* hh        = (_Float16*)carve((size_t)N * HOUT * 2);
  _Float16* hh2       = (_Float16*)carve((size_t)N * HOUT * 2);
  _Float16* W1t       = (_Float16*)carve((size_t)BCOLS * Fin * 2);
  _Float16* W2t       = (_Float16*)carve((size_t)BCOLS * HOUT * 2);
  // ibuf (35 MB) aliases bufB (38 MB): ibuf is dead before bufB's first write
  unsigned* ibuf      = (unsigned*)bufB;
  (void)ws_size;

  // --- CSR build (XCD-private bucket sort) + weight conversion ---
  hipMemsetAsync(bcnt, 0, (size_t)NXCD * NB * 4, stream);
  bucketA_kernel<<<(E2 + 255) / 256, 256, 0, stream>>>(ei, E, N, NB, bcnt, ibuf);
  bscan_kernel<<<1, 256, 0, stream>>>(bcnt, bstart, NB, E2, offsets, N);
  bucketB_kernel<<<NB, 256, 0, stream>>>(ibuf, bcnt, bstart, NB, N, srcs, offsets);
  convw_kernel<<<(198 * Fin + 255) / 256, 256, 0, stream>>>(W1, a1s, a1d, W1t, Fin);
  convw_kernel<<<(198 * HOUT + 255) / 256, 256, 0, stream>>>(W2, a2s, a2d, W2t, HOUT);

  int wave_blocks = (N * 64 + 255) / 256;
  int gemm_blocks = (N + GBM - 1) / GBM;

  // --- layer 1 ---
  gemm_mfma_kernel<float><<<gemm_blocks, 256, 0, stream>>>(x, W1t, hh, als, ald, N, Fin);
  agg_kernel<<<wave_blocks, 256, 0, stream>>>((const __half*)hh, als, ald, offsets, srcs,
                                              b1, nullptr, hh2, N);

  // --- layer 2 ---
  gemm_mfma_kernel<_Float16><<<gemm_blocks, 256, 0, stream>>>(hh2, W2t, hh, als, ald, N, HOUT);
  agg_kernel<<<wave_blocks, 256, 0, stream>>>((const __half*)hh, als, ald, offsets, srcs,
                                              b2, bufB, nullptr, N);

  // --- pool ---
  pool_kernel<<<G, HOUT, 0, stream>>>(bufB, bat, out, N);
}

// Round 13
// 303.887 us; speedup vs baseline: 2.1313x; 1.1008x over previous
//
#include <hip/hip_runtime.h>
#include <hip/hip_fp16.h>
#include <math.h>

#define HOUT 192
#define NEG_SLOPE 0.2f
#define BCOLS 208   // 192 h-cols + 3 wsrc + 3 wdst + 10 pad (unused)

// CSR bucket-sort params (requires N < 2^20)
#define BSHIFT 7
#define BNODES 128
#define NXCD 8
#define CAP 2816
#define BSTRIDE 16  // one 64B line per bucket counter (atomic-contention fix)

typedef _Float16 half8 __attribute__((ext_vector_type(8)));
typedef float floatx4 __attribute__((ext_vector_type(4)));

// ---------------- CSR build: XCD-private bucket sort ----------------

// Phase A: append packed (local_d<<20 | src) to per-(XCD,bucket) region.
__global__ void bucketA_kernel(const int* __restrict__ ei, int E, int N, int NB,
                               int* __restrict__ bcnt, unsigned* __restrict__ ibuf) {
  int e = blockIdx.x * 256 + threadIdx.x;
  int E2 = E + N;
  if (e >= E2) return;
  int s, d;
  if (e < E) { s = ei[e]; d = ei[E + e]; }
  else       { s = e - E; d = e - E; }
  int b = d >> BSHIFT;
  int x;
  asm("s_getreg_b32 %0, hwreg(HW_REG_XCC_ID)" : "=s"(x));
  x &= (NXCD - 1);
  int slot = x * NB + b;
  int pos = atomicAdd(&bcnt[slot * BSTRIDE], 1);
  if (pos < CAP)
    ibuf[(size_t)slot * CAP + pos] = (unsigned)s | ((unsigned)(d & (BNODES - 1)) << 20);
}

// Bucket-total exclusive scan (one block, 256 threads, NB <= 512).
__global__ void bscan_kernel(const int* __restrict__ bcnt, int* __restrict__ bstart,
                             int NB, int E2, int* __restrict__ offsets, int N) {
  int t = threadIdx.x;
  int b0 = 2 * t, b1 = 2 * t + 1;
  int v0 = 0, v1 = 0;
  if (b0 < NB)
    for (int x = 0; x < NXCD; ++x) v0 += bcnt[(x * NB + b0) * BSTRIDE];
  if (b1 < NB)
    for (int x = 0; x < NXCD; ++x) v1 += bcnt[(x * NB + b1) * BSTRIDE];
  int s = v0 + v1;
  int lane = t & 63, wid = t >> 6;
  int xs = s;
#pragma unroll
  for (int d = 1; d < 64; d <<= 1) {
    int y = __shfl_up(xs, d);
    if (lane >= d) xs += y;
  }
  __shared__ int wsum[4];
  if (lane == 63) wsum[wid] = xs;
  __syncthreads();
  int wbase = 0;
  for (int w = 0; w < wid; ++w) wbase += wsum[w];
  int excl = wbase + xs - s;
  if (b0 < NB) bstart[b0] = excl;
  if (b1 < NB) bstart[b1] = excl + v0;
  if (t == 0) offsets[N] = E2;
}

// Phase B: per bucket: LDS histogram -> LDS scan -> write offsets + final srcs.
__global__ __launch_bounds__(256) void bucketB_kernel(
    const unsigned* __restrict__ ibuf, const int* __restrict__ bcnt,
    const int* __restrict__ bstart, int NB, int N,
    int* __restrict__ srcs, int* __restrict__ offsets) {
  __shared__ int lens[NXCD];
  __shared__ int cnt[BNODES];
  __shared__ int sa[BNODES], sb_[BNODES];
  __shared__ int cur[BNODES];
  int b = blockIdx.x;
  int t = threadIdx.x;
  if (t < NXCD) {
    int v = bcnt[(t * NB + b) * BSTRIDE];
    lens[t] = v < CAP ? v : CAP;
  }
  if (t < BNODES) cnt[t] = 0;
  __syncthreads();
  for (int x = 0; x < NXCD; ++x) {
    int len = lens[x];
    const unsigned* seg = ibuf + (size_t)(x * NB + b) * CAP;
    for (int i = t; i < len; i += 256) atomicAdd(&cnt[seg[i] >> 20], 1);
  }
  __syncthreads();
  if (t < BNODES) sa[t] = cnt[t];
  __syncthreads();
  int* pin = sa;
  int* pout = sb_;
  for (int off = 1; off < BNODES; off <<= 1) {
    if (t < BNODES) pout[t] = pin[t] + ((t >= off) ? pin[t - off] : 0);
    __syncthreads();
    int* tmp = pin; pin = pout; pout = tmp;
  }
  int bst = bstart[b];
  if (t < BNODES) {
    int ex = pin[t] - cnt[t];
    cur[t] = bst + ex;
    int d = b * BNODES + t;
    if (d < N) offsets[d] = bst + ex;
  }
  __syncthreads();
  for (int x = 0; x < NXCD; ++x) {
    int len = lens[x];
    const unsigned* seg = ibuf + (size_t)(x * NB + b) * CAP;
    for (int i = t; i < len; i += 256) {
      unsigned r = seg[i];
      int pos = atomicAdd(&cur[r >> 20], 1);
      srcs[pos] = (int)(r & 0xFFFFFu);
    }
  }
}

// ---- W -> transposed fp16 Bt[col][K] with 6 extra al-columns ----
__global__ void convw_kernel(const float* __restrict__ W, const float* __restrict__ asrc,
                             const float* __restrict__ adst, _Float16* __restrict__ Bt,
                             int K) {
  int i = blockIdx.x * 256 + threadIdx.x;
  int nT = 192 * K;
  if (i < nT) {
    int col = i / K, k = i - col * K;
    Bt[i] = (_Float16)W[(size_t)k * HOUT + col];
    return;
  }
  int j = i - nT;
  if (j >= 6 * K) return;
  int which = j / K, k = j - which * K;
  const float* a = (which < 3) ? asrc : adst;
  int h = (which < 3) ? which : which - 3;
  float s = 0.f;
#pragma unroll 8
  for (int d = 0; d < 64; ++d)
    s += W[(size_t)k * HOUT + h * 64 + d] * a[h * 64 + d];
  Bt[(size_t)(192 + which) * K + k] = (_Float16)s;
}

// ---------------- fp16 MFMA GEMM (BK=64, swizzled LDS, al via MFMA) ----------------
#define GBM 64
#define GBK 64

template <typename T>
__global__ __launch_bounds__(256) void gemm_mfma_kernel(
    const T* __restrict__ A, const _Float16* __restrict__ Bt,
    _Float16* __restrict__ Ch, float* __restrict__ als, float* __restrict__ ald,
    int M, int K) {
  __shared__ _Float16 As[GBM][GBK];
  __shared__ _Float16 Bs[BCOLS][GBK];
  int tid = threadIdx.x;
  int bm = blockIdx.x * GBM;
  int w  = tid >> 6;
  int l  = tid & 63;
  int lg = l & 15;
  int lh = l >> 4;

  floatx4 acc[13];
#pragma unroll
  for (int cb = 0; cb < 13; ++cb) acc[cb] = (floatx4){0.f, 0.f, 0.f, 0.f};

  for (int kt = 0; kt < K; kt += GBK) {
    {
      int ar = tid >> 2;
      int c0 = (tid & 3) * 2;
      int swz = ar & 7;
      int gm = bm + ar;
      half8 h8a = {}, h8b = {};
      if (gm < M) {
        if constexpr (sizeof(T) == 4) {
          const float* src = (const float*)&A[(size_t)gm * K + kt + c0 * 8];
          float4 f0 = *(const float4*)&src[0];
          float4 f1 = *(const float4*)&src[4];
          float4 f2 = *(const float4*)&src[8];
          float4 f3 = *(const float4*)&src[12];
          h8a[0] = (_Float16)f0.x; h8a[1] = (_Float16)f0.y;
          h8a[2] = (_Float16)f0.z; h8a[3] = (_Float16)f0.w;
          h8a[4] = (_Float16)f1.x; h8a[5] = (_Float16)f1.y;
          h8a[6] = (_Float16)f1.z; h8a[7] = (_Float16)f1.w;
          h8b[0] = (_Float16)f2.x; h8b[1] = (_Float16)f2.y;
          h8b[2] = (_Float16)f2.z; h8b[3] = (_Float16)f2.w;
          h8b[4] = (_Float16)f3.x; h8b[5] = (_Float16)f3.y;
          h8b[6] = (_Float16)f3.z; h8b[7] = (_Float16)f3.w;
        } else {
          const T* src = &A[(size_t)gm * K + kt + c0 * 8];
          h8a = *(const half8*)&src[0];
          h8b = *(const half8*)&src[8];
        }
      }
      *(half8*)&As[ar][(c0 ^ swz) * 8]       = h8a;
      *(half8*)&As[ar][((c0 + 1) ^ swz) * 8] = h8b;
    }
#pragma unroll
    for (int i = 0; i < 7; ++i) {
      int f = tid + 256 * i;
      if (f < BCOLS * 8) {
        int row = f >> 3, c = f & 7;
        *(half8*)&Bs[row][(c ^ (row & 7)) * 8] =
            *(const half8*)&Bt[(size_t)row * K + kt + c * 8];
      }
    }
    __syncthreads();

    int rowa = w * 16 + lg;
    int swa = rowa & 7;
    half8 a0 = *(const half8*)&As[rowa][(lh ^ swa) * 8];
    half8 a1 = *(const half8*)&As[rowa][((4 + lh) ^ swa) * 8];
#pragma unroll
    for (int cb = 0; cb < 13; ++cb) {
      int rowb = cb * 16 + lg;
      int swb = rowb & 7;
      half8 b0 = *(const half8*)&Bs[rowb][(lh ^ swb) * 8];
      half8 b1 = *(const half8*)&Bs[rowb][((4 + lh) ^ swb) * 8];
      acc[cb] = __builtin_amdgcn_mfma_f32_16x16x32_f16(a0, b0, acc[cb], 0, 0, 0);
      acc[cb] = __builtin_amdgcn_mfma_f32_16x16x32_f16(a1, b1, acc[cb], 0, 0, 0);
    }
    __syncthreads();
  }

#pragma unroll
  for (int r = 0; r < 4; ++r) {
    int node = bm + w * 16 + lh * 4 + r;
    if (node < M) {
      _Float16* hr = &Ch[(size_t)node * HOUT];
#pragma unroll
      for (int cb = 0; cb < 12; ++cb) hr[cb * 16 + lg] = (_Float16)acc[cb][r];
      float alv = acc[12][r];
      if (lg < 3)      als[node * 4 + lg] = alv;
      else if (lg < 6) ald[node * 4 + (lg - 3)] = alv;
    }
  }
}

// ---------------- per-dst aggregation ----------------
// 64-edge chunks: prologue computes softmax weights edge-parallel (lane=edge),
// stashes {w0,w1,w2,src} in per-wave LDS; gather loop broadcast-reads records.
__global__ void agg_kernel(const __half* __restrict__ hh, const float* __restrict__ als,
                           const float* __restrict__ ald, const int* __restrict__ offsets,
                           const int* __restrict__ srcs, const float* __restrict__ bias,
                           float* __restrict__ out_f, _Float16* __restrict__ out_h,
                           int n_nodes) {
  __shared__ float4 wls[4][64];
  int wv = (blockIdx.x * blockDim.x + threadIdx.x) >> 6;
  int wid = (threadIdx.x >> 6) & 3;
  int lane = threadIdx.x & 63;
  int node = __builtin_amdgcn_readfirstlane(wv);
  if (node >= n_nodes) return;
  int beg = offsets[node], end = offsets[node + 1];
  float4 ad = *(const float4*)&ald[node * 4];
  float sA0 = 0.f, sA1 = 0.f, sA2 = 0.f, aA0 = 0.f, aA1 = 0.f, aA2 = 0.f;
  float sB0 = 0.f, sB1 = 0.f, sB2 = 0.f, aB0 = 0.f, aB1 = 0.f, aB2 = 0.f;

  for (int cb = beg; cb < end; cb += 64) {
    int rem = end - cb;
    int cnt = rem < 64 ? rem : 64;
    if (lane < cnt) {
      int s = srcs[cb + lane];
      float4 as4 = *(const float4*)&als[s * 4];
      float l0 = as4.x + ad.x;
      float l1 = as4.y + ad.y;
      float l2 = as4.z + ad.z;
      l0 = (l0 > 0.f) ? l0 : NEG_SLOPE * l0;
      l1 = (l1 > 0.f) ? l1 : NEG_SLOPE * l1;
      l2 = (l2 > 0.f) ? l2 : NEG_SLOPE * l2;
      float4 rec;
      rec.x = __expf(l0);
      rec.y = __expf(l1);
      rec.z = __expf(l2);
      rec.w = __int_as_float(s);
      wls[wid][lane] = rec;
    }
    asm volatile("s_waitcnt lgkmcnt(0)" ::: "memory");
    int j = 0;
    for (; j + 3 < cnt; j += 4) {
      float4 rA = wls[wid][j];
      float4 rB = wls[wid][j + 1];
      float4 rC = wls[wid][j + 2];
      float4 rD = wls[wid][j + 3];
      const __half* ha = hh + (size_t)__float_as_int(rA.w) * HOUT + lane;
      const __half* hb = hh + (size_t)__float_as_int(rB.w) * HOUT + lane;
      const __half* hc = hh + (size_t)__float_as_int(rC.w) * HOUT + lane;
      const __half* hd = hh + (size_t)__float_as_int(rD.w) * HOUT + lane;
      float va0 = __half2float(ha[0]);
      float va1 = __half2float(ha[64]);
      float va2 = __half2float(ha[128]);
      float vb0 = __half2float(hb[0]);
      float vb1 = __half2float(hb[64]);
      float vb2 = __half2float(hb[128]);
      float vc0 = __half2float(hc[0]);
      float vc1 = __half2float(hc[64]);
      float vc2 = __half2float(hc[128]);
      float vd0 = __half2float(hd[0]);
      float vd1 = __half2float(hd[64]);
      float vd2 = __half2float(hd[128]);
      sA0 += rA.x + rC.x; sA1 += rA.y + rC.y; sA2 += rA.z + rC.z;
      sB0 += rB.x + rD.x; sB1 += rB.y + rD.y; sB2 += rB.z + rD.z;
      aA0 += rA.x * va0 + rC.x * vc0;
      aA1 += rA.y * va1 + rC.y * vc1;
      aA2 += rA.z * va2 + rC.z * vc2;
      aB0 += rB.x * vb0 + rD.x * vd0;
      aB1 += rB.y * vb1 + rD.y * vd1;
      aB2 += rB.z * vb2 + rD.z * vd2;
    }
    for (; j < cnt; ++j) {
      float4 rA = wls[wid][j];
      const __half* ha = hh + (size_t)__float_as_int(rA.w) * HOUT + lane;
      float va0 = __half2float(ha[0]);
      float va1 = __half2float(ha[64]);
      float va2 = __half2float(ha[128]);
      sA0 += rA.x; aA0 += rA.x * va0;
      sA1 += rA.y; aA1 += rA.y * va1;
      sA2 += rA.z; aA2 += rA.z * va2;
    }
  }
  float s0 = sA0 + sB0, s1 = sA1 + sB1, s2 = sA2 + sB2;
  float a0 = aA0 + aB0, a1 = aA1 + aB1, a2 = aA2 + aB2;
  float r0 = 1.f / (s0 + 1e-16f);
  float r1 = 1.f / (s1 + 1e-16f);
  float r2 = 1.f / (s2 + 1e-16f);
  float v0 = fmaxf(a0 * r0 + bias[lane], 0.f);
  float v1 = fmaxf(a1 * r1 + bias[64 + lane], 0.f);
  float v2 = fmaxf(a2 * r2 + bias[128 + lane], 0.f);
  if (out_f) {
    float* o = out_f + (size_t)node * HOUT;
    o[lane] = v0; o[64 + lane] = v1; o[128 + lane] = v2;
  }
  if (out_h) {
    _Float16* o = out_h + (size_t)node * HOUT;
    o[lane] = (_Float16)v0; o[64 + lane] = (_Float16)v1; o[128 + lane] = (_Float16)v2;
  }
}

// ---------------- mean pool over sorted batch + relu ----------------
__global__ void pool_kernel(const float* __restrict__ h, const int* __restrict__ batch,
                            float* __restrict__ out, int n_nodes) {
  __shared__ int sbe[2];
  int g = blockIdx.x;
  if (threadIdx.x < 2) {
    int key = g + (int)threadIdx.x;
    int lo = 0, hi = n_nodes;
    while (lo < hi) {
      int mid = (lo + hi) >> 1;
      if (batch[mid] < key) lo = mid + 1; else hi = mid;
    }
    sbe[threadIdx.x] = lo;
  }
  __syncthreads();
  int beg = sbe[0], end = sbe[1];
  int t = threadIdx.x;
  float sum = 0.f;
  int i = beg;
  for (; i + 7 < end; i += 8) {
    float x0 = h[(size_t)(i + 0) * HOUT + t];
    float x1 = h[(size_t)(i + 1) * HOUT + t];
    float x2 = h[(size_t)(i + 2) * HOUT + t];
    float x3 = h[(size_t)(i + 3) * HOUT + t];
    float x4 = h[(size_t)(i + 4) * HOUT + t];
    float x5 = h[(size_t)(i + 5) * HOUT + t];
    float x6 = h[(size_t)(i + 6) * HOUT + t];
    float x7 = h[(size_t)(i + 7) * HOUT + t];
    sum += ((x0 + x1) + (x2 + x3)) + ((x4 + x5) + (x6 + x7));
  }
  for (; i < end; ++i) sum += h[(size_t)i * HOUT + t];
  float cnt = (float)(end - beg);
  float v = (cnt > 0.f) ? sum / cnt : 0.f;
  out[(size_t)g * HOUT + t] = fmaxf(v, 0.f);
}

// ---------------- launcher ----------------

extern "C" void kernel_launch(void* const* d_in, const int* in_sizes, int n_in,
                              void* d_out, int out_size, void* d_ws, size_t ws_size,
                              hipStream_t stream) {
  const float* x   = (const float*)d_in[0];
  const int*   ei  = (const int*)d_in[1];
  const int*   bat = (const int*)d_in[2];
  const float* W1  = (const float*)d_in[3];
  const float* a1s = (const float*)d_in[4];
  const float* a1d = (const float*)d_in[5];
  const float* b1  = (const float*)d_in[6];
  const float* W2  = (const float*)d_in[7];
  const float* a2s = (const float*)d_in[8];
  const float* a2d = (const float*)d_in[9];
  const float* b2  = (const float*)d_in[10];
  float* out = (float*)d_out;

  int N   = in_sizes[2];
  int Fin = in_sizes[0] / N;
  int E   = in_sizes[1] / 2;
  int E2  = E + N;
  int G   = out_size / HOUT;
  int NB  = (N + BNODES - 1) / BNODES;

  char* p = (char*)d_ws;
  auto carve = [&](size_t bytes) -> char* {
    char* r = p;
    p += (bytes + 255) & ~(size_t)255;
    return r;
  };
  int*      offsets   = (int*)carve((size_t)(N + 1) * 4);
  int*      srcs      = (int*)carve((size_t)E2 * 4);
  int*      bcnt      = (int*)carve((size_t)NXCD * NB * BSTRIDE * 4);
  int*      bstart    = (int*)carve((size_t)NB * 4);
  float*    als       = (float*)carve((size_t)N * 4 * 4);
  float*    ald       = (float*)carve((size_t)N * 4 * 4);
  float*    bufB      = (float*)carve((size_t)N * HOUT * 4);
  _Float16* hh        = (_Float16*)carve((size_t)N * HOUT * 2);
  _Float16* hh2       = (_Float16*)carve((size_t)N * HOUT * 2);
  _Float16* W1t       = (_Float16*)carve((size_t)BCOLS * Fin * 2);
  _Float16* W2t       = (_Float16*)carve((size_t)BCOLS * HOUT * 2);
  // ibuf (35 MB) aliases bufB (38 MB): ibuf is dead before bufB's first write
  unsigned* ibuf      = (unsigned*)bufB;
  (void)ws_size;

  // --- CSR build (XCD-private bucket sort) + weight conversion ---
  hipMemsetAsync(bcnt, 0, (size_t)NXCD * NB * BSTRIDE * 4, stream);
  bucketA_kernel<<<(E2 + 255) / 256, 256, 0, stream>>>(ei, E, N, NB, bcnt, ibuf);
  bscan_kernel<<<1, 256, 0, stream>>>(bcnt, bstart, NB, E2, offsets, N);
  bucketB_kernel<<<NB, 256, 0, stream>>>(ibuf, bcnt, bstart, NB, N, srcs, offsets);
  convw_kernel<<<(198 * Fin + 255) / 256, 256, 0, stream>>>(W1, a1s, a1d, W1t, Fin);
  convw_kernel<<<(198 * HOUT + 255) / 256, 256, 0, stream>>>(W2, a2s, a2d, W2t, HOUT);

  int wave_blocks = (N * 64 + 255) / 256;
  int gemm_blocks = (N + GBM - 1) / GBM;

  // --- layer 1 ---
  gemm_mfma_kernel<float><<<gemm_blocks, 256, 0, stream>>>(x, W1t, hh, als, ald, N, Fin);
  agg_kernel<<<wave_blocks, 256, 0, stream>>>((const __half*)hh, als, ald, offsets, srcs,
                                              b1, nullptr, hh2, N);

  // --- layer 2 ---
  gemm_mfma_kernel<_Float16><<<gemm_blocks, 256, 0, stream>>>(hh2, W2t, hh, als, ald, N, HOUT);
  agg_kernel<<<wave_blocks, 256, 0, stream>>>((const __half*)hh, als, ald, offsets, srcs,
                                              b2, bufB, nullptr, N);

  // --- pool ---
  pool_kernel<<<G, HOUT, 0, stream>>>(bufB, bat, out, N);
}

// Round 14
// 260.772 us; speedup vs baseline: 2.4837x; 1.1653x over previous
//
#include <hip/hip_runtime.h>
#include <hip/hip_fp16.h>
#include <math.h>

#define HOUT 192
#define NEG_SLOPE 0.2f
#define BCOLS 208   // 192 h-cols + 3 wsrc + 3 wdst + 10 pad (unused)

// CSR counting-sort params (requires N < 2^20, NB <= 512)
#define BSHIFT 7
#define BNODES 128
#define NBLK 240

typedef _Float16 half8 __attribute__((ext_vector_type(8)));
typedef float floatx4 __attribute__((ext_vector_type(4)));

// ---------------- CSR build: deterministic two-pass counting sort ----------------

// Pass 1: per-block LDS histogram of dst-buckets -> cnt2d[blk][NB]. No global atomics.
__global__ __launch_bounds__(1024) void histA_kernel(const int* __restrict__ ei, int E, int N,
                                                     int NB, int* __restrict__ cnt2d) {
  __shared__ int cnt[512];
  int t = threadIdx.x, blk = blockIdx.x;
  int E2 = E + N;
  int chunk = (E2 + NBLK - 1) / NBLK;
  int lo = blk * chunk;
  int hi = lo + chunk; if (hi > E2) hi = E2;
  for (int i = t; i < NB; i += 1024) cnt[i] = 0;
  __syncthreads();
  for (int e = lo + t; e < hi; e += 1024) {
    int d = (e < E) ? ei[E + e] : (e - E);
    atomicAdd(&cnt[d >> BSHIFT], 1);
  }
  __syncthreads();
  for (int i = t; i < NB; i += 1024) cnt2d[blk * NB + i] = cnt[i];
}

// Per-bucket exclusive scan over blocks: base2d[blk][b], totals tot[b].
__global__ __launch_bounds__(256) void colscan_kernel(const int* __restrict__ cnt2d,
                                                      int* __restrict__ base2d,
                                                      int* __restrict__ tot, int NB) {
  int b = blockIdx.x;
  int t = threadIdx.x;
  int v = (t < NBLK) ? cnt2d[t * NB + b] : 0;
  int lane = t & 63, wid = t >> 6;
  int x = v;
#pragma unroll
  for (int d = 1; d < 64; d <<= 1) {
    int y = __shfl_up(x, d);
    if (lane >= d) x += y;
  }
  __shared__ int wsum[4];
  if (lane == 63) wsum[wid] = x;
  __syncthreads();
  int wbase = 0;
  for (int w = 0; w < wid; ++w) wbase += wsum[w];
  if (t < NBLK) base2d[t * NB + b] = wbase + x - v;
  if (t == 255) tot[b] = wbase + x;
}

// Scan 391 bucket totals -> bstart; also offsets[N] = E2.
__global__ void tscan_kernel(const int* __restrict__ tot, int* __restrict__ bstart,
                             int NB, int E2, int* __restrict__ offsets, int N) {
  int t = threadIdx.x;
  int b0 = 2 * t, b1 = 2 * t + 1;
  int v0 = (b0 < NB) ? tot[b0] : 0;
  int v1 = (b1 < NB) ? tot[b1] : 0;
  int s = v0 + v1;
  int lane = t & 63, wid = t >> 6;
  int xs = s;
#pragma unroll
  for (int d = 1; d < 64; d <<= 1) {
    int y = __shfl_up(xs, d);
    if (lane >= d) xs += y;
  }
  __shared__ int wsum[4];
  if (lane == 63) wsum[wid] = xs;
  __syncthreads();
  int wbase = 0;
  for (int w = 0; w < wid; ++w) wbase += wsum[w];
  int excl = wbase + xs - s;
  if (b0 < NB) bstart[b0] = excl;
  if (b1 < NB) bstart[b1] = excl + v0;
  if (t == 0) offsets[N] = E2;
}

// Pass 2: same edge partition; LDS rank counters give exact positions.
__global__ __launch_bounds__(1024) void scatterA_kernel(
    const int* __restrict__ ei, int E, int N, int NB,
    const int* __restrict__ base2d, const int* __restrict__ bstart,
    unsigned* __restrict__ ibuf) {
  __shared__ int loc[512];
  __shared__ int rk[512];
  int t = threadIdx.x, blk = blockIdx.x;
  int E2 = E + N;
  int chunk = (E2 + NBLK - 1) / NBLK;
  int lo = blk * chunk;
  int hi = lo + chunk; if (hi > E2) hi = E2;
  for (int i = t; i < NB; i += 1024) {
    loc[i] = bstart[i] + base2d[blk * NB + i];
    rk[i] = 0;
  }
  __syncthreads();
  for (int e = lo + t; e < hi; e += 1024) {
    int s, d;
    if (e < E) { s = ei[e]; d = ei[E + e]; }
    else       { s = e - E; d = e - E; }
    int b = d >> BSHIFT;
    int r = atomicAdd(&rk[b], 1);
    ibuf[loc[b] + r] = (unsigned)s | ((unsigned)(d & (BNODES - 1)) << 20);
  }
}

// Per bucket: LDS node-histogram -> scan -> offsets + final srcs.
__global__ __launch_bounds__(256) void bucketB_kernel(
    const unsigned* __restrict__ ibuf, const int* __restrict__ bstart,
    const int* __restrict__ tot, int N, int* __restrict__ srcs,
    int* __restrict__ offsets) {
  __shared__ int cnt[BNODES];
  __shared__ int sa[BNODES], sb_[BNODES];
  __shared__ int cur[BNODES];
  int b = blockIdx.x;
  int t = threadIdx.x;
  int len = tot[b];
  int bst = bstart[b];
  const unsigned* seg = ibuf + bst;
  if (t < BNODES) cnt[t] = 0;
  __syncthreads();
  for (int i = t; i < len; i += 256) atomicAdd(&cnt[seg[i] >> 20], 1);
  __syncthreads();
  if (t < BNODES) sa[t] = cnt[t];
  __syncthreads();
  int* pin = sa;
  int* pout = sb_;
  for (int off = 1; off < BNODES; off <<= 1) {
    if (t < BNODES) pout[t] = pin[t] + ((t >= off) ? pin[t - off] : 0);
    __syncthreads();
    int* tmp = pin; pin = pout; pout = tmp;
  }
  if (t < BNODES) {
    int ex = pin[t] - cnt[t];
    cur[t] = bst + ex;
    int d = b * BNODES + t;
    if (d < N) offsets[d] = bst + ex;
  }
  __syncthreads();
  for (int i = t; i < len; i += 256) {
    unsigned r = seg[i];
    int pos = atomicAdd(&cur[r >> 20], 1);
    srcs[pos] = (int)(r & 0xFFFFFu);
  }
}

// ---- W -> transposed fp16 Bt[col][K] with 6 extra al-columns ----
__global__ void convw_kernel(const float* __restrict__ W, const float* __restrict__ asrc,
                             const float* __restrict__ adst, _Float16* __restrict__ Bt,
                             int K) {
  int i = blockIdx.x * 256 + threadIdx.x;
  int nT = 192 * K;
  if (i < nT) {
    int col = i / K, k = i - col * K;
    Bt[i] = (_Float16)W[(size_t)k * HOUT + col];
    return;
  }
  int j = i - nT;
  if (j >= 6 * K) return;
  int which = j / K, k = j - which * K;
  const float* a = (which < 3) ? asrc : adst;
  int h = (which < 3) ? which : which - 3;
  float s = 0.f;
#pragma unroll 8
  for (int d = 0; d < 64; ++d)
    s += W[(size_t)k * HOUT + h * 64 + d] * a[h * 64 + d];
  Bt[(size_t)(192 + which) * K + k] = (_Float16)s;
}

// ---------------- fp16 MFMA GEMM (BK=64, swizzled LDS, al via MFMA) ----------------
#define GBM 64
#define GBK 64

template <typename T>
__global__ __launch_bounds__(256) void gemm_mfma_kernel(
    const T* __restrict__ A, const _Float16* __restrict__ Bt,
    _Float16* __restrict__ Ch, float* __restrict__ als, float* __restrict__ ald,
    int M, int K) {
  __shared__ _Float16 As[GBM][GBK];
  __shared__ _Float16 Bs[BCOLS][GBK];
  int tid = threadIdx.x;
  int bm = blockIdx.x * GBM;
  int w  = tid >> 6;
  int l  = tid & 63;
  int lg = l & 15;
  int lh = l >> 4;

  floatx4 acc[13];
#pragma unroll
  for (int cb = 0; cb < 13; ++cb) acc[cb] = (floatx4){0.f, 0.f, 0.f, 0.f};

  for (int kt = 0; kt < K; kt += GBK) {
    {
      int ar = tid >> 2;
      int c0 = (tid & 3) * 2;
      int swz = ar & 7;
      int gm = bm + ar;
      half8 h8a = {}, h8b = {};
      if (gm < M) {
        if constexpr (sizeof(T) == 4) {
          const float* src = (const float*)&A[(size_t)gm * K + kt + c0 * 8];
          float4 f0 = *(const float4*)&src[0];
          float4 f1 = *(const float4*)&src[4];
          float4 f2 = *(const float4*)&src[8];
          float4 f3 = *(const float4*)&src[12];
          h8a[0] = (_Float16)f0.x; h8a[1] = (_Float16)f0.y;
          h8a[2] = (_Float16)f0.z; h8a[3] = (_Float16)f0.w;
          h8a[4] = (_Float16)f1.x; h8a[5] = (_Float16)f1.y;
          h8a[6] = (_Float16)f1.z; h8a[7] = (_Float16)f1.w;
          h8b[0] = (_Float16)f2.x; h8b[1] = (_Float16)f2.y;
          h8b[2] = (_Float16)f2.z; h8b[3] = (_Float16)f2.w;
          h8b[4] = (_Float16)f3.x; h8b[5] = (_Float16)f3.y;
          h8b[6] = (_Float16)f3.z; h8b[7] = (_Float16)f3.w;
        } else {
          const T* src = &A[(size_t)gm * K + kt + c0 * 8];
          h8a = *(const half8*)&src[0];
          h8b = *(const half8*)&src[8];
        }
      }
      *(half8*)&As[ar][(c0 ^ swz) * 8]       = h8a;
      *(half8*)&As[ar][((c0 + 1) ^ swz) * 8] = h8b;
    }
#pragma unroll
    for (int i = 0; i < 7; ++i) {
      int f = tid + 256 * i;
      if (f < BCOLS * 8) {
        int row = f >> 3, c = f & 7;
        *(half8*)&Bs[row][(c ^ (row & 7)) * 8] =
            *(const half8*)&Bt[(size_t)row * K + kt + c * 8];
      }
    }
    __syncthreads();

    int rowa = w * 16 + lg;
    int swa = rowa & 7;
    half8 a0 = *(const half8*)&As[rowa][(lh ^ swa) * 8];
    half8 a1 = *(const half8*)&As[rowa][((4 + lh) ^ swa) * 8];
#pragma unroll
    for (int cb = 0; cb < 13; ++cb) {
      int rowb = cb * 16 + lg;
      int swb = rowb & 7;
      half8 b0 = *(const half8*)&Bs[rowb][(lh ^ swb) * 8];
      half8 b1 = *(const half8*)&Bs[rowb][((4 + lh) ^ swb) * 8];
      acc[cb] = __builtin_amdgcn_mfma_f32_16x16x32_f16(a0, b0, acc[cb], 0, 0, 0);
      acc[cb] = __builtin_amdgcn_mfma_f32_16x16x32_f16(a1, b1, acc[cb], 0, 0, 0);
    }
    __syncthreads();
  }

#pragma unroll
  for (int r = 0; r < 4; ++r) {
    int node = bm + w * 16 + lh * 4 + r;
    if (node < M) {
      _Float16* hr = &Ch[(size_t)node * HOUT];
#pragma unroll
      for (int cb = 0; cb < 12; ++cb) hr[cb * 16 + lg] = (_Float16)acc[cb][r];
      float alv = acc[12][r];
      if (lg < 3)      als[node * 4 + lg] = alv;
      else if (lg < 6) ald[node * 4 + (lg - 3)] = alv;
    }
  }
}

// ---------------- per-dst aggregation ----------------
// 64-edge chunks: prologue computes softmax weights edge-parallel (lane=edge),
// stashes {w0,w1,w2,src} in per-wave LDS; gather loop broadcast-reads records.
__global__ void agg_kernel(const __half* __restrict__ hh, const float* __restrict__ als,
                           const float* __restrict__ ald, const int* __restrict__ offsets,
                           const int* __restrict__ srcs, const float* __restrict__ bias,
                           float* __restrict__ out_f, _Float16* __restrict__ out_h,
                           int n_nodes) {
  __shared__ float4 wls[4][64];
  int wv = (blockIdx.x * blockDim.x + threadIdx.x) >> 6;
  int wid = (threadIdx.x >> 6) & 3;
  int lane = threadIdx.x & 63;
  int node = __builtin_amdgcn_readfirstlane(wv);
  if (node >= n_nodes) return;
  int beg = offsets[node], end = offsets[node + 1];
  float4 ad = *(const float4*)&ald[node * 4];
  float sA0 = 0.f, sA1 = 0.f, sA2 = 0.f, aA0 = 0.f, aA1 = 0.f, aA2 = 0.f;
  float sB0 = 0.f, sB1 = 0.f, sB2 = 0.f, aB0 = 0.f, aB1 = 0.f, aB2 = 0.f;

  for (int cb = beg; cb < end; cb += 64) {
    int rem = end - cb;
    int cnt = rem < 64 ? rem : 64;
    if (lane < cnt) {
      int s = srcs[cb + lane];
      float4 as4 = *(const float4*)&als[s * 4];
      float l0 = as4.x + ad.x;
      float l1 = as4.y + ad.y;
      float l2 = as4.z + ad.z;
      l0 = (l0 > 0.f) ? l0 : NEG_SLOPE * l0;
      l1 = (l1 > 0.f) ? l1 : NEG_SLOPE * l1;
      l2 = (l2 > 0.f) ? l2 : NEG_SLOPE * l2;
      float4 rec;
      rec.x = __expf(l0);
      rec.y = __expf(l1);
      rec.z = __expf(l2);
      rec.w = __int_as_float(s);
      wls[wid][lane] = rec;
    }
    asm volatile("s_waitcnt lgkmcnt(0)" ::: "memory");
    int j = 0;
    for (; j + 3 < cnt; j += 4) {
      float4 rA = wls[wid][j];
      float4 rB = wls[wid][j + 1];
      float4 rC = wls[wid][j + 2];
      float4 rD = wls[wid][j + 3];
      const __half* ha = hh + (size_t)__float_as_int(rA.w) * HOUT + lane;
      const __half* hb = hh + (size_t)__float_as_int(rB.w) * HOUT + lane;
      const __half* hc = hh + (size_t)__float_as_int(rC.w) * HOUT + lane;
      const __half* hd = hh + (size_t)__float_as_int(rD.w) * HOUT + lane;
      float va0 = __half2float(ha[0]);
      float va1 = __half2float(ha[64]);
      float va2 = __half2float(ha[128]);
      float vb0 = __half2float(hb[0]);
      float vb1 = __half2float(hb[64]);
      float vb2 = __half2float(hb[128]);
      float vc0 = __half2float(hc[0]);
      float vc1 = __half2float(hc[64]);
      float vc2 = __half2float(hc[128]);
      float vd0 = __half2float(hd[0]);
      float vd1 = __half2float(hd[64]);
      float vd2 = __half2float(hd[128]);
      sA0 += rA.x + rC.x; sA1 += rA.y + rC.y; sA2 += rA.z + rC.z;
      sB0 += rB.x + rD.x; sB1 += rB.y + rD.y; sB2 += rB.z + rD.z;
      aA0 += rA.x * va0 + rC.x * vc0;
      aA1 += rA.y * va1 + rC.y * vc1;
      aA2 += rA.z * va2 + rC.z * vc2;
      aB0 += rB.x * vb0 + rD.x * vd0;
      aB1 += rB.y * vb1 + rD.y * vd1;
      aB2 += rB.z * vb2 + rD.z * vd2;
    }
    for (; j < cnt; ++j) {
      float4 rA = wls[wid][j];
      const __half* ha = hh + (size_t)__float_as_int(rA.w) * HOUT + lane;
      float va0 = __half2float(ha[0]);
      float va1 = __half2float(ha[64]);
      float va2 = __half2float(ha[128]);
      sA0 += rA.x; aA0 += rA.x * va0;
      sA1 += rA.y; aA1 += rA.y * va1;
      sA2 += rA.z; aA2 += rA.z * va2;
    }
  }
  float s0 = sA0 + sB0, s1 = sA1 + sB1, s2 = sA2 + sB2;
  float a0 = aA0 + aB0, a1 = aA1 + aB1, a2 = aA2 + aB2;
  float r0 = 1.f / (s0 + 1e-16f);
  float r1 = 1.f / (s1 + 1e-16f);
  float r2 = 1.f / (s2 + 1e-16f);
  float v0 = fmaxf(a0 * r0 + bias[lane], 0.f);
  float v1 = fmaxf(a1 * r1 + bias[64 + lane], 0.f);
  float v2 = fmaxf(a2 * r2 + bias[128 + lane], 0.f);
  if (out_f) {
    float* o = out_f + (size_t)node * HOUT;
    o[lane] = v0; o[64 + lane] = v1; o[128 + lane] = v2;
  }
  if (out_h) {
    _Float16* o = out_h + (size_t)node * HOUT;
    o[lane] = (_Float16)v0; o[64 + lane] = (_Float16)v1; o[128 + lane] = (_Float16)v2;
  }
}

// ---------------- mean pool over sorted batch + relu ----------------
__global__ void pool_kernel(const float* __restrict__ h, const int* __restrict__ batch,
                            float* __restrict__ out, int n_nodes) {
  __shared__ int sbe[2];
  int g = blockIdx.x;
  if (threadIdx.x < 2) {
    int key = g + (int)threadIdx.x;
    int lo = 0, hi = n_nodes;
    while (lo < hi) {
      int mid = (lo + hi) >> 1;
      if (batch[mid] < key) lo = mid + 1; else hi = mid;
    }
    sbe[threadIdx.x] = lo;
  }
  __syncthreads();
  int beg = sbe[0], end = sbe[1];
  int t = threadIdx.x;
  float sum = 0.f;
  int i = beg;
  for (; i + 7 < end; i += 8) {
    float x0 = h[(size_t)(i + 0) * HOUT + t];
    float x1 = h[(size_t)(i + 1) * HOUT + t];
    float x2 = h[(size_t)(i + 2) * HOUT + t];
    float x3 = h[(size_t)(i + 3) * HOUT + t];
    float x4 = h[(size_t)(i + 4) * HOUT + t];
    float x5 = h[(size_t)(i + 5) * HOUT + t];
    float x6 = h[(size_t)(i + 6) * HOUT + t];
    float x7 = h[(size_t)(i + 7) * HOUT + t];
    sum += ((x0 + x1) + (x2 + x3)) + ((x4 + x5) + (x6 + x7));
  }
  for (; i < end; ++i) sum += h[(size_t)i * HOUT + t];
  float cnt = (float)(end - beg);
  float v = (cnt > 0.f) ? sum / cnt : 0.f;
  out[(size_t)g * HOUT + t] = fmaxf(v, 0.f);
}

// ---------------- launcher ----------------

extern "C" void kernel_launch(void* const* d_in, const int* in_sizes, int n_in,
                              void* d_out, int out_size, void* d_ws, size_t ws_size,
                              hipStream_t stream) {
  const float* x   = (const float*)d_in[0];
  const int*   ei  = (const int*)d_in[1];
  const int*   bat = (const int*)d_in[2];
  const float* W1  = (const float*)d_in[3];
  const float* a1s = (const float*)d_in[4];
  const float* a1d = (const float*)d_in[5];
  const float* b1  = (const float*)d_in[6];
  const float* W2  = (const float*)d_in[7];
  const float* a2s = (const float*)d_in[8];
  const float* a2d = (const float*)d_in[9];
  const float* b2  = (const float*)d_in[10];
  float* out = (float*)d_out;

  int N   = in_sizes[2];
  int Fin = in_sizes[0] / N;
  int E   = in_sizes[1] / 2;
  int E2  = E + N;
  int G   = out_size / HOUT;
  int NB  = (N + BNODES - 1) / BNODES;

  char* p = (char*)d_ws;
  auto carve = [&](size_t bytes) -> char* {
    char* r = p;
    p += (bytes + 255) & ~(size_t)255;
    return r;
  };
  int*      offsets   = (int*)carve((size_t)(N + 1) * 4);
  int*      srcs      = (int*)carve((size_t)E2 * 4);
  int*      cnt2d     = (int*)carve((size_t)NBLK * NB * 4);
  int*      base2d    = (int*)carve((size_t)NBLK * NB * 4);
  int*      tot       = (int*)carve((size_t)NB * 4);
  int*      bstart    = (int*)carve((size_t)NB * 4);
  float*    als       = (float*)carve((size_t)N * 4 * 4);
  float*    ald       = (float*)carve((size_t)N * 4 * 4);
  float*    bufB      = (float*)carve((size_t)N * HOUT * 4);
  _Float16* hh        = (_Float16*)carve((size_t)N * HOUT * 2);
  _Float16* hh2       = (_Float16*)carve((size_t)N * HOUT * 2);
  _Float16* W1t       = (_Float16*)carve((size_t)BCOLS * Fin * 2);
  _Float16* W2t       = (_Float16*)carve((size_t)BCOLS * HOUT * 2);
  // ibuf (3.4 MB) aliases bufB (38 MB): ibuf is dead before bufB's first write
  unsigned* ibuf      = (unsigned*)bufB;
  (void)ws_size;

  // --- CSR build (deterministic counting sort, no global atomics) ---
  histA_kernel<<<NBLK, 1024, 0, stream>>>(ei, E, N, NB, cnt2d);
  colscan_kernel<<<NB, 256, 0, stream>>>(cnt2d, base2d, tot, NB);
  tscan_kernel<<<1, 256, 0, stream>>>(tot, bstart, NB, E2, offsets, N);
  scatterA_kernel<<<NBLK, 1024, 0, stream>>>(ei, E, N, NB, base2d, bstart, ibuf);
  bucketB_kernel<<<NB, 256, 0, stream>>>(ibuf, bstart, tot, N, srcs, offsets);
  convw_kernel<<<(198 * Fin + 255) / 256, 256, 0, stream>>>(W1, a1s, a1d, W1t, Fin);
  convw_kernel<<<(198 * HOUT + 255) / 256, 256, 0, stream>>>(W2, a2s, a2d, W2t, HOUT);

  int wave_blocks = (N * 64 + 255) / 256;
  int gemm_blocks = (N + GBM - 1) / GBM;

  // --- layer 1 ---
  gemm_mfma_kernel<float><<<gemm_blocks, 256, 0, stream>>>(x, W1t, hh, als, ald, N, Fin);
  agg_kernel<<<wave_blocks, 256, 0, stream>>>((const __half*)hh, als, ald, offsets, srcs,
                                              b1, nullptr, hh2, N);

  // --- layer 2 ---
  gemm_mfma_kernel<_Float16><<<gemm_blocks, 256, 0, stream>>>(hh2, W2t, hh, als, ald, N, HOUT);
  agg_kernel<<<wave_blocks, 256, 0, stream>>>((const __half*)hh, als, ald, offsets, srcs,
                                              b2, bufB, nullptr, N);

  // --- pool ---
  pool_kernel<<<G, HOUT, 0, stream>>>(bufB, bat, out, N);
}